// Round 11
// baseline (389.205 us; speedup 1.0000x reference)
//
#include <hip/hip_runtime.h>

static __device__ __forceinline__ float lky(float x) { return x > 0.f ? x : 0.01f * x; }

static __device__ __forceinline__ unsigned short f2bf(float x) {
    unsigned int u = __float_as_uint(x);
    unsigned int r = (u + 0x7FFFu + ((u >> 16) & 1u)) >> 16;
    return (unsigned short)r;
}
static __device__ __forceinline__ float bf2f(unsigned short x) {
    return __uint_as_float((unsigned int)x << 16);
}
static __device__ __forceinline__ unsigned int pack2bf(float lo, float hi) {
    return (unsigned int)f2bf(lo) | ((unsigned int)f2bf(hi) << 16);
}

typedef __attribute__((ext_vector_type(8))) short short8;
typedef __attribute__((ext_vector_type(4))) float f32x4;

constexpr int SN  = 50048;   // padded node count (multiple of 64)
constexpr int KLV = 608;     // K(nodes) per split-K chunk (multiple of 32)
constexpr int VCM = 83;      // ceil(SN/KLV)
constexpr int NSCAN = 53248; // 13 * 4096, scan padding
constexpr int NWG_V = 12 * VCM;      // 996
constexpr int NQ_V  = NWG_V / 8;     // 124
constexpr int NR_V  = NWG_V % 8;     // 4

// ---------------- init ----------------
__global__ void k_init(float* t_max, int* cnt, int* cursor, float* colsum, int N, int NP) {
    int i = blockIdx.x * 256 + threadIdx.x;
    if (i < N) { t_max[i] = -1.0f; cursor[i] = 0; }
    if (i < NP) cnt[i] = 0;
    if (i < 224) colsum[i] = 0.0f;
}

// ---------------- weight transpose to bf16: dst[c*K+k] = src[k*C+c] ----------------
__global__ void k_tbf(const float* __restrict__ src, unsigned short* __restrict__ dst,
                      int K, int C) {
    int i = blockIdx.x * 256 + threadIdx.x;
    if (i >= K * C) return;
    int c = i / K, k = i % K;
    dst[i] = f2bf(src[k * C + c]);
}

// ---------------- per-edge t_max / counts ----------------
__global__ void k_tmax_cnt(const int* __restrict__ src, const float* __restrict__ ts,
                           float* t_max, int* cnt, int E) {
    int e = blockIdx.x * 256 + threadIdx.x;
    if (e >= E) return;
    int s = src[e];
    atomicMax((int*)(t_max + s), __float_as_int(ts[e]));   // ts >= 0, int-monotone
    atomicAdd(cnt + s, 1);
}

// ---------------- exclusive scan over counts (single block, 4096/iter) ----------------
__global__ __launch_bounds__(1024) void k_scan(const int* __restrict__ cnt,
                                               int* __restrict__ offsets, int N) {
    __shared__ int wsum[16];
    __shared__ int s_run;
    int t = threadIdx.x;
    int lane = t & 63, wid = t >> 6;
    if (t == 0) s_run = 0;
    __syncthreads();
    int nchunk = (N + 4095) >> 12;
    for (int c = 0; c < nchunk; ++c) {
        int i0 = (c << 12) + t * 4;
        int4 v = *(const int4*)(cnt + i0);     // cnt zero-padded to NSCAN
        int s = v.x + v.y + v.z + v.w;
        int x = s;
        #pragma unroll
        for (int d = 1; d < 64; d <<= 1) {
            int y = __shfl_up(x, d, 64);
            if (lane >= d) x += y;
        }
        if (lane == 63) wsum[wid] = x;
        __syncthreads();
        int wbase = 0;
        #pragma unroll
        for (int w = 0; w < 16; ++w) wbase += (w < wid) ? wsum[w] : 0;
        int run = s_run;
        int base = run + wbase + x - s;
        if (i0 + 3 < N) {
            int4 o;
            o.x = base; o.y = base + v.x; o.z = o.y + v.y; o.w = o.z + v.z;
            *(int4*)(offsets + i0) = o;
        } else {
            int o = base;
            if (i0 < N) offsets[i0] = o;
            o += v.x;
            if (i0 + 1 < N) offsets[i0 + 1] = o;
            o += v.y;
            if (i0 + 2 < N) offsets[i0 + 2] = o;
            o += v.z;
            if (i0 + 3 < N) offsets[i0 + 3] = o;
        }
        __syncthreads();
        if (t == 1023) s_run = run + wbase + x;
        __syncthreads();
    }
    if (t == 0) offsets[N] = s_run;
}

// ---------------- scatter edges into per-node buckets ----------------
__global__ void k_scatter(const int* __restrict__ src, const int* __restrict__ offsets,
                          int* cursor, int* sorted, int E) {
    int e = blockIdx.x * 256 + threadIdx.x;
    if (e >= E) return;
    int s = src[e];
    int pos = offsets[s] + atomicAdd(cursor + s, 1);
    sorted[pos] = e;
}

// ---------------- precompute normalized target embedding, bf16 [N][256] ----------------
__global__ __launch_bounds__(256) void k_prep(
        const float* __restrict__ memory, const float* __restrict__ nodef,
        unsigned int* __restrict__ temb, int N) {
    int wid = threadIdx.x >> 6, lane = threadIdx.x & 63;
    int n = blockIdx.x * 4 + wid;
    if (n >= N) return;
    const float* mrow = memory + (size_t)n * 195;
    float d0 = mrow[64], d1 = mrow[129], d2 = mrow[194];
    int f = 2 * lane;
    float den = (f < 64) ? d0 : d1;
    int offA = (f < 64) ? f : f + 1;
    float va0 = mrow[offA] / den;
    float va1 = mrow[offA + 1] / den;
    float vb0, vb1;
    if (lane < 32) {
        vb0 = mrow[130 + 2 * lane] / d2;
        vb1 = mrow[131 + 2 * lane] / d2;
    } else {
        const float* nf = nodef + (size_t)n * 64 + 2 * (lane - 32);
        vb0 = nf[0]; vb1 = nf[1];
    }
    temb[(size_t)n * 128 + lane]      = pack2bf(va0, va1);
    temb[(size_t)n * 128 + 64 + lane] = pack2bf(vb0, vb1);
}

// ---------------- A_r pass: rowsum, colsum, bf16 Aexp_rm + AexpT (throughput form) ----------------
__global__ __launch_bounds__(256) void k_aexp(
        const float* __restrict__ A_r,
        float* __restrict__ rowsum, float* __restrict__ colsum,
        unsigned short* __restrict__ AexpT, unsigned short* __restrict__ Aexp_rm, int N) {
    __shared__ unsigned short sE[64][228];   // 456B row stride: 8B-aligned, ~2-way banks
    int t = threadIdx.x;
    int n0 = blockIdx.x * 64;
    int maxq = min(64, N - n0) * 56;
    const float4* src = (const float4*)(A_r + (size_t)n0 * 224);
    #pragma unroll
    for (int k = 0; k < 14; ++k) {
        int i = t + k * 256;
        float4 v = (i < maxq) ? src[i] : (float4){-1e30f, -1e30f, -1e30f, -1e30f};
        int row = i / 56, cq = i % 56;
        uint2 pk;
        pk.x = pack2bf(__expf(v.x), __expf(v.y));
        pk.y = pack2bf(__expf(v.z), __expf(v.w));
        *(uint2*)&sE[row][cq * 4] = pk;
    }
    __syncthreads();
    // rowsum: 4 threads per row, 2 shuffles
    {
        int row = t >> 2, q = t & 3;
        const uint2* p = (const uint2*)&sE[row][q * 56];
        float s = 0.f;
        #pragma unroll
        for (int c = 0; c < 7; ++c) {
            uint2 u = p[c];
            s += __uint_as_float(u.x << 16) + __uint_as_float(u.x & 0xffff0000u)
               + __uint_as_float(u.y << 16) + __uint_as_float(u.y & 0xffff0000u);
        }
        s += __shfl_xor(s, 1, 64);
        s += __shfl_xor(s, 2, 64);
        if (q == 0 && n0 + row < N) rowsum[n0 + row] = s;
    }
    // colsum partials
    if (t < 224) {
        float s = 0.f;
        #pragma unroll 8
        for (int r = 0; r < 64; ++r) s += bf2f(sE[r][t]);
        atomicAdd(colsum + t, s);
    }
    // row-major write, packed uints, coalesced
    {
        unsigned int* dst = (unsigned int*)Aexp_rm;
        for (int i = t; i < 64 * 112; i += 256) {
            int n = i / 112, cp = i % 112;
            dst[(size_t)(n0 + n) * 112 + cp] = *(const unsigned int*)&sE[n][2 * cp];
        }
    }
    // transposed write: wave-coalesced 128B runs per r-row
    {
        unsigned int* dst = (unsigned int*)AexpT;
        for (int u = t; u < 224 * 32; u += 256) {
            int r = u >> 5, np = u & 31;
            unsigned int lo = sE[2 * np][r];
            unsigned int hi = sE[2 * np + 1][r];
            dst[(size_t)r * (SN / 2) + (n0 >> 1) + np] = lo | (hi << 16);
        }
    }
}

// ---------------- per-node aggregation: one wave per node, bf16 temb gather ----------------
__global__ __launch_bounds__(256) void k_agg(
        const int* __restrict__ tgt, const float* __restrict__ ts,
        const int* __restrict__ sorted, const int* __restrict__ offsets,
        const float* __restrict__ t_max, const unsigned int* __restrict__ temb,
        const float* __restrict__ lambs,
        unsigned int* __restrict__ aggb, float* __restrict__ cnt3,
        int* __restrict__ has_msg, int N) {
    int wid = threadIdx.x >> 6, lane = threadIdx.x & 63;
    int n = blockIdx.x * 4 + wid;      // n < SN (grid = SN/4)
    size_t rb = (size_t)n * 3;
    if (n >= N) {                       // zero-fill padding rows
        #pragma unroll
        for (int l = 0; l < 3; ++l) {
            unsigned int* row = aggb + (rb + l) * 128;
            row[lane] = 0; row[64 + lane] = 0;
            if (lane == 0) cnt3[rb + l] = 0.f;
        }
        return;
    }
    int beg = offsets[n], end = offsets[n + 1];
    float lb0 = lambs[0], lb1 = lambs[1], lb2 = lambs[2];
    float tm = t_max[n];
    float aa0[3], aa1[3], ab0[3], ab1[3], accc[3];
    #pragma unroll
    for (int l = 0; l < 3; ++l) { aa0[l] = aa1[l] = ab0[l] = ab1[l] = accc[l] = 0.f; }
    for (int idx = beg; idx < end; ++idx) {
        int e = sorted[idx];
        int tt = tgt[e];
        float d = tm - ts[e];
        unsigned int ua = temb[(size_t)tt * 128 + lane];
        unsigned int ub = temb[(size_t)tt * 128 + 64 + lane];
        float a0 = __uint_as_float(ua << 16);
        float a1 = __uint_as_float(ua & 0xffff0000u);
        float b0 = __uint_as_float(ub << 16);
        float b1 = __uint_as_float(ub & 0xffff0000u);
        float w0 = __expf(-lb0 * d), w1 = __expf(-lb1 * d), w2 = __expf(-lb2 * d);
        aa0[0] += w0 * a0; aa1[0] += w0 * a1; ab0[0] += w0 * b0; ab1[0] += w0 * b1; accc[0] += w0;
        aa0[1] += w1 * a0; aa1[1] += w1 * a1; ab0[1] += w1 * b0; ab1[1] += w1 * b1; accc[1] += w1;
        aa0[2] += w2 * a0; aa1[2] += w2 * a1; ab0[2] += w2 * b0; ab1[2] += w2 * b1; accc[2] += w2;
    }
    #pragma unroll
    for (int l = 0; l < 3; ++l) {
        unsigned int* row = aggb + (rb + l) * 128;
        row[lane]      = pack2bf(aa0[l], aa1[l]);
        row[64 + lane] = pack2bf(ab0[l], ab1[l]);
        if (lane == 0) cnt3[rb + l] = accc[l];
    }
    if (lane == 0) has_msg[n] = (end > beg) ? 1 : 0;
}

// ---------------- mf MLP via MFMA: weights-stationary in regs, 128 rows/block ----------------
__global__ __launch_bounds__(256) void k_mf_mfma(
        const unsigned short* __restrict__ aggb,
        const unsigned short* __restrict__ W1T, const float* __restrict__ b1,
        const unsigned short* __restrict__ W2T, const float* __restrict__ b2,
        unsigned short* __restrict__ msg_feat, int NROWS) {
    __shared__ unsigned short As[64 * 264];
    __shared__ unsigned short Hs[64 * 136];
    int t = threadIdx.x, lane = t & 63, w = t >> 6;
    int lr = lane & 15, kg = lane >> 4;
    int row0 = blockIdx.x * 128;
    int n0 = w * 32, c0 = w * 16;
    // preload W into registers (weights-stationary; all indices static)
    short8 bw1[8][2], bw2[4];
    #pragma unroll
    for (int kk = 0; kk < 8; ++kk) {
        bw1[kk][0] = *(const short8*)(W1T + (size_t)(n0 + lr) * 256 + kk * 32 + kg * 8);
        bw1[kk][1] = *(const short8*)(W1T + (size_t)(n0 + 16 + lr) * 256 + kk * 32 + kg * 8);
    }
    #pragma unroll
    for (int kk = 0; kk < 4; ++kk)
        bw2[kk] = *(const short8*)(W2T + (size_t)(c0 + lr) * 128 + kk * 32 + kg * 8);
    // stage tile 0 (rows row0..row0+63): 4 threads/row, 64 shorts (8 uint4) each
    int r = t >> 2, s4 = t & 3;
    uint4* dstA = (uint4*)(As + r * 264 + s4 * 64);
    uint4 pre[8];
    {
        const uint4* g0 = (const uint4*)(aggb + (size_t)(row0 + r) * 256 + s4 * 64);
        #pragma unroll
        for (int u = 0; u < 8; ++u) pre[u] = g0[u];
        #pragma unroll
        for (int u = 0; u < 8; ++u) dstA[u] = pre[u];
    }
    __syncthreads();
    float bb0 = b1[n0 + lr], bb1 = b1[n0 + 16 + lr];
    float b2v = b2[c0 + lr];
    #pragma unroll
    for (int tile = 0; tile < 2; ++tile) {
        if (tile == 0) {   // issue next tile's loads early; write after compute
            const uint4* g1 = (const uint4*)(aggb + (size_t)(row0 + 64 + r) * 256 + s4 * 64);
            #pragma unroll
            for (int u = 0; u < 8; ++u) pre[u] = g1[u];
        }
        // layer 1: 64 rows x 32 cols per wave, zero global loads
        f32x4 acc[4][2];
        #pragma unroll
        for (int m = 0; m < 4; ++m) {
            acc[m][0] = (f32x4){0.f, 0.f, 0.f, 0.f};
            acc[m][1] = (f32x4){0.f, 0.f, 0.f, 0.f};
        }
        #pragma unroll
        for (int kk = 0; kk < 8; ++kk)
            #pragma unroll
            for (int m = 0; m < 4; ++m) {
                short8 af = *(const short8*)(As + (m * 16 + lr) * 264 + kk * 32 + kg * 8);
                acc[m][0] = __builtin_amdgcn_mfma_f32_16x16x32_bf16(af, bw1[kk][0], acc[m][0], 0, 0, 0);
                acc[m][1] = __builtin_amdgcn_mfma_f32_16x16x32_bf16(af, bw1[kk][1], acc[m][1], 0, 0, 0);
            }
        #pragma unroll
        for (int m = 0; m < 4; ++m)
            #pragma unroll
            for (int j = 0; j < 4; ++j) {
                int row = m * 16 + kg * 4 + j;
                Hs[row * 136 + n0 + lr]      = f2bf(fmaxf(acc[m][0][j] + bb0, 0.f));
                Hs[row * 136 + n0 + 16 + lr] = f2bf(fmaxf(acc[m][1][j] + bb1, 0.f));
            }
        __syncthreads();
        // layer 2: 64 rows x 16 cols per wave
        f32x4 a2[4];
        #pragma unroll
        for (int m = 0; m < 4; ++m) a2[m] = (f32x4){0.f, 0.f, 0.f, 0.f};
        #pragma unroll
        for (int kk = 0; kk < 4; ++kk)
            #pragma unroll
            for (int m = 0; m < 4; ++m) {
                short8 af = *(const short8*)(Hs + (m * 16 + lr) * 136 + kk * 32 + kg * 8);
                a2[m] = __builtin_amdgcn_mfma_f32_16x16x32_bf16(af, bw2[kk], a2[m], 0, 0, 0);
            }
        int rbase = row0 + tile * 64;
        #pragma unroll
        for (int m = 0; m < 4; ++m)
            #pragma unroll
            for (int j = 0; j < 4; ++j) {
                int row = rbase + m * 16 + kg * 4 + j;
                if (row < NROWS)
                    msg_feat[(size_t)row * 64 + c0 + lr] = f2bf(fmaxf(a2[m][j] + b2v, 0.f));
            }
        if (tile == 0) {   // all As/Hs reads done -> overwrite As with tile 1
            __syncthreads();
            #pragma unroll
            for (int u = 0; u < 8; ++u) dstA[u] = pre[u];
            __syncthreads();
        }
    }
}

// ---------------- vmid via bf16 MFMA, split-K; XCD-swizzled, B LDS-staged ----------------
__global__ __launch_bounds__(256) void k_vmid_mfma(
        const unsigned short* __restrict__ AexpT, const unsigned short* __restrict__ aggb,
        const float* __restrict__ cnt3, float* __restrict__ vpart) {
    __shared__ unsigned short As[112 * 40];   // 112 rows x 32 shorts (stride 40 = 80B)
    __shared__ unsigned int BsT[128 * 20];    // [col][np-uint] stride 20; np ^= ((col>>3)&3)<<2
    // bijective XCD swizzle: co-locate the 12 tiles of each chunk on one XCD
    int bx = blockIdx.x;
    int xcd = bx & 7, bidx = bx >> 3;
    int virt = (xcd < NR_V) ? xcd * (NQ_V + 1) + bidx
                            : NR_V * (NQ_V + 1) + (xcd - NR_V) * NQ_V + bidx;
    int chunk = virt / 12, tile = virt % 12;
    int r0 = (tile & 1) * 112;
    int ft = tile >> 1;                 // 0..5
    int l = ft >> 1, fo = (ft & 1) * 128;
    int t = threadIdx.x, lane = t & 63, w = t >> 6;
    int lr = lane & 15, kg = lane >> 4;
    int np = t >> 4, sg = t & 15;       // B staging: node-pair, col-segment(8 cols)
    f32x4 acc[7][2];
    #pragma unroll
    for (int q = 0; q < 7; ++q) {
        acc[q][0] = (f32x4){0.f, 0.f, 0.f, 0.f};
        acc[q][1] = (f32x4){0.f, 0.f, 0.f, 0.f};
    }
    int nbeg = chunk * KLV;
    int nsteps = min(KLV, SN - nbeg) >> 5;
    int c0 = w * 32 + lr, c1 = c0 + 16;
    int rb0 = c0 * 20 + (kg ^ ((c0 >> 3) & 3)) * 4;
    int rb1 = c1 * 20 + (kg ^ ((c1 >> 3) & 3)) * 4;
    int swz = np ^ ((sg & 3) << 2);
    for (int s = 0; s < nsteps; ++s) {
        int n0 = nbeg + s * 32;
        if (t < 224) {                   // stage A: 2 threads/row, 32 shorts/row
            int srow = t >> 1, sseg = t & 1;
            const uint4* ap = (const uint4*)(AexpT + (size_t)(r0 + srow) * SN + n0) + sseg * 2;
            uint4 v0 = ap[0];
            uint4 v1 = ap[1];
            *(uint4*)&As[srow * 40 + sseg * 16]     = v0;
            *(uint4*)&As[srow * 40 + sseg * 16 + 8] = v1;
        }
        {   // stage B: nodes (2np, 2np+1) x cols [sg*8, sg*8+8), scaled by 1/den, k-pair packed
            int na = n0 + 2 * np;
            size_t ra = ((size_t)na * 3 + l) * 256 + fo + sg * 8;
            uint4 va = *(const uint4*)(aggb + ra);
            uint4 vb = *(const uint4*)(aggb + ra + 768);
            float da = 1.f / fmaxf(cnt3[(size_t)na * 3 + l], 1e-6f);
            float db = 1.f / fmaxf(cnt3[(size_t)na * 3 + l + 3], 1e-6f);
            const unsigned short* pa = (const unsigned short*)&va;
            const unsigned short* pb = (const unsigned short*)&vb;
            unsigned int* dst = BsT + sg * 160 + swz;
            #pragma unroll
            for (int j = 0; j < 8; ++j)
                dst[j * 20] = pack2bf(bf2f(pa[j]) * da, bf2f(pb[j]) * db);
        }
        __syncthreads();
        short8 b0 = *(const short8*)((const unsigned short*)(BsT + rb0));
        short8 b1 = *(const short8*)((const unsigned short*)(BsT + rb1));
        #pragma unroll
        for (int q = 0; q < 7; ++q) {
            short8 af = *(const short8*)&As[(q * 16 + lr) * 40 + kg * 8];
            acc[q][0] = __builtin_amdgcn_mfma_f32_16x16x32_bf16(af, b0, acc[q][0], 0, 0, 0);
            acc[q][1] = __builtin_amdgcn_mfma_f32_16x16x32_bf16(af, b1, acc[q][1], 0, 0, 0);
        }
        __syncthreads();
    }
    float* outp = vpart + (size_t)chunk * 172032;
    #pragma unroll
    for (int q = 0; q < 7; ++q) {
        int row = r0 + q * 16 + kg * 4;
        #pragma unroll
        for (int p = 0; p < 2; ++p) {
            int col = l * 256 + fo + w * 32 + p * 16 + lr;
            #pragma unroll
            for (int j = 0; j < 4; ++j)
                outp[(size_t)(row + j) * 768 + col] = acc[q][p][j];
        }
    }
}

// ---------------- reduce vpart over chunks, divide by colsum ----------------
__global__ void k_vred(const float* __restrict__ vpart, const float* __restrict__ colsum,
                       float* __restrict__ vmid) {
    int idx = blockIdx.x * 256 + threadIdx.x;
    if (idx >= 224 * 768) return;
    float s = 0.f;
    for (int c = 0; c < VCM; ++c) s += vpart[(long)c * (224 * 768) + idx];
    vmid[idx] = s / colsum[idx / 768];
}

// ---------------- ffr MLP (672 rows) + virtual-memory decay -> vembT (bf16) ----------------
__global__ __launch_bounds__(256) void k_ffr(
        const float* __restrict__ vmid, const float* __restrict__ W1, const float* __restrict__ b1,
        const float* __restrict__ W2, const float* __restrict__ b2,
        const float* __restrict__ vmem, const float* __restrict__ vlast,
        const float* __restrict__ lambs, const float* __restrict__ now_time,
        unsigned short* __restrict__ vembT) {
    __shared__ float sin_[16][260];
    __shared__ float svh[16][260];
    int row0 = blockIdx.x * 16;
    int t = threadIdx.x;
    #pragma unroll
    for (int k = 0; k < 16; ++k) {
        int idx = t + k * 256;
        int r = idx >> 8, f = idx & 255;
        sin_[r][f] = vmid[(long)(row0 + r) * 256 + f];
    }
    __syncthreads();
    {   // layer 1: 16 x 256, 4r x 4c
        int cg = t & 63, rg = t >> 6;
        int c0 = cg * 4, r0 = rg * 4;
        float acc[4][4];
        #pragma unroll
        for (int i = 0; i < 4; ++i)
            #pragma unroll
            for (int j = 0; j < 4; ++j) acc[i][j] = 0.f;
        for (int f0 = 0; f0 < 256; f0 += 4) {
            float4 a[4];
            #pragma unroll
            for (int i = 0; i < 4; ++i) a[i] = *(const float4*)&sin_[r0 + i][f0];
            #pragma unroll
            for (int ff = 0; ff < 4; ++ff) {
                float4 w = *(const float4*)&W1[(long)(f0 + ff) * 256 + c0];
                #pragma unroll
                for (int i = 0; i < 4; ++i) {
                    float av = (&a[i].x)[ff];
                    acc[i][0] += av * w.x; acc[i][1] += av * w.y;
                    acc[i][2] += av * w.z; acc[i][3] += av * w.w;
                }
            }
        }
        #pragma unroll
        for (int i = 0; i < 4; ++i)
            #pragma unroll
            for (int j = 0; j < 4; ++j)
                svh[r0 + i][c0 + j] = lky(acc[i][j] + b1[c0 + j]);
    }
    __syncthreads();
    {   // layer 2: 16 x 64, 2r x 2c + decay epilogue
        int cg = t & 31, rg = t >> 5;
        int c0 = cg * 2, r0 = rg * 2;
        float acc[2][2];
        acc[0][0] = acc[0][1] = acc[1][0] = acc[1][1] = 0.f;
        for (int f0 = 0; f0 < 256; f0 += 4) {
            float4 a[2];
            #pragma unroll
            for (int i = 0; i < 2; ++i) a[i] = *(const float4*)&svh[r0 + i][f0];
            #pragma unroll
            for (int ff = 0; ff < 4; ++ff) {
                float2 w = *(const float2*)&W2[(long)(f0 + ff) * 64 + c0];
                #pragma unroll
                for (int i = 0; i < 2; ++i) {
                    float av = (&a[i].x)[ff];
                    acc[i][0] += av * w.x; acc[i][1] += av * w.y;
                }
            }
        }
        float nowv = now_time[0];
        #pragma unroll
        for (int i = 0; i < 2; ++i) {
            int row = row0 + r0 + i;           // row = rr*3 + l
            int rr = row / 3, l = row % 3;
            float vd = __expf(-lambs[l] * (nowv - vlast[rr]));
            #pragma unroll
            for (int j = 0; j < 2; ++j) {
                float v = lky(acc[i][j] + b2[c0 + j]);
                int m = c0 + j;
                vembT[(size_t)(l * 64 + m) * 224 + rr] =
                    f2bf(vmem[(long)rr * 192 + l * 64 + m] * vd + v);
            }
        }
    }
}

// ---------------- new_mem -> node_emb (bf16) ----------------
__global__ void k_newmem(const float* __restrict__ memory,
        const unsigned short* __restrict__ msg_feat,
        const float* __restrict__ cnt3, const float* __restrict__ t_max,
        const float* __restrict__ last_update, const int* __restrict__ has_msg,
        const float* __restrict__ lambs, unsigned short* __restrict__ node_emb, int N) {
    int n = blockIdx.x;
    int j = threadIdx.x;                 // 0..191
    int l = j >> 6, m = j & 63;
    int has = has_msg[n];
    float dt = has ? (t_max[n] - last_update[n]) : 0.f;
    float decay = __expf(-lambs[l] * dt);
    long mb = (long)n * 195 + l * 65;
    float num = memory[mb + m];
    float den = memory[mb + 64];
    if (has) {
        num = num * decay + bf2f(msg_feat[(size_t)n * 192 + j]);
        den = den * decay + cnt3[(size_t)n * 3 + l];
    }
    node_emb[(size_t)n * 192 + j] = f2bf(num / fmaxf(den, 1e-6f));
}

// ---------------- vnode_emb = row-softmax(A_r) @ v_emb via MFMA (LDS-staged A) ----------------
__global__ __launch_bounds__(256) void k_vnode_mfma(
        const unsigned short* __restrict__ Aexp_rm, const unsigned short* __restrict__ vembT,
        const float* __restrict__ rowsum, unsigned short* __restrict__ vnode_emb, int N) {
    __shared__ unsigned short As[64 * 232];
    __shared__ float sRS[64];
    int t = threadIdx.x, lane = t & 63, w = t >> 6;
    int lr = lane & 15, kg = lane >> 4;
    int row0 = blockIdx.x * 64;
    {
        int r = t >> 2, sg = t & 3;
        const uint4* src = (const uint4*)(Aexp_rm + (size_t)(row0 + r) * 224 + sg * 56);
        uint4* dst = (uint4*)(As + r * 232 + sg * 56);
        #pragma unroll
        for (int u = 0; u < 7; ++u) dst[u] = src[u];
    }
    if (t < 64) sRS[t] = rowsum[min(row0 + t, N - 1)];
    __syncthreads();
    int n0 = w * 48;                      // 192 cols / 4 waves
    f32x4 acc[4][3];
    #pragma unroll
    for (int m = 0; m < 4; ++m)
        #pragma unroll
        for (int nt = 0; nt < 3; ++nt) acc[m][nt] = (f32x4){0.f, 0.f, 0.f, 0.f};
    for (int kk = 0; kk < 7; ++kk) {
        short8 bf[3];
        #pragma unroll
        for (int nt = 0; nt < 3; ++nt)
            bf[nt] = *(const short8*)(vembT + (size_t)(n0 + nt * 16 + lr) * 224 + kk * 32 + kg * 8);
        #pragma unroll
        for (int m = 0; m < 4; ++m) {
            short8 af = *(const short8*)(As + (m * 16 + lr) * 232 + kk * 32 + kg * 8);
            #pragma unroll
            for (int nt = 0; nt < 3; ++nt)
                acc[m][nt] = __builtin_amdgcn_mfma_f32_16x16x32_bf16(af, bf[nt], acc[m][nt], 0, 0, 0);
        }
    }
    #pragma unroll
    for (int m = 0; m < 4; ++m)
        #pragma unroll
        for (int j = 0; j < 4; ++j) {
            int row = row0 + m * 16 + kg * 4 + j;
            if (row < N) {
                float inv = 1.f / sRS[row - row0];
                #pragma unroll
                for (int nt = 0; nt < 3; ++nt)
                    vnode_emb[(size_t)row * 192 + n0 + nt * 16 + lr] = f2bf(acc[m][nt][j] * inv);
            }
        }
}

// ---------------- et + st + output blend via MFMA: 32 rows/block, LDS-staged ----------------
__global__ __launch_bounds__(256) void k_et_st_mfma(
        const unsigned short* __restrict__ ne, const unsigned short* __restrict__ ve,
        const unsigned short* __restrict__ etWT, const float* __restrict__ etb,
        const unsigned short* __restrict__ stWT, const float* __restrict__ stb,
        const float* __restrict__ stat, const float* __restrict__ lamb,
        float* __restrict__ out, int N) {
    __shared__ unsigned short As[64 * 200];    // rows 0-31: node, 32-63: vnode
    __shared__ unsigned short Hs[32 * 136];    // st input [32 rows][128 cols]
    int t = threadIdx.x, lane = t & 63, w = t >> 6;
    int lr = lane & 15, kg = lane >> 4;
    int row0 = blockIdx.x * 32;
    {
        int r = t >> 3, s8 = t & 7;            // 8 threads/row, 48B each
        const uint4* sn = (const uint4*)(ne + (size_t)(row0 + r) * 192 + s8 * 24);
        const uint4* sv = (const uint4*)(ve + (size_t)(row0 + r) * 192 + s8 * 24);
        uint4* dn = (uint4*)(As + (size_t)r * 200 + s8 * 24);
        uint4* dv = (uint4*)(As + (size_t)(32 + r) * 200 + s8 * 24);
        #pragma unroll
        for (int u = 0; u < 3; ++u) { dn[u] = sn[u]; dv[u] = sv[u]; }
    }
    __syncthreads();
    // et layer: wave w -> cols [w*16, w*16+16), both halves; K=192
    int c0 = w * 16;
    f32x4 acc[2][2];
    #pragma unroll
    for (int h = 0; h < 2; ++h)
        #pragma unroll
        for (int m = 0; m < 2; ++m) acc[h][m] = (f32x4){0.f, 0.f, 0.f, 0.f};
    for (int kk = 0; kk < 6; ++kk) {
        short8 bf = *(const short8*)(etWT + (size_t)(c0 + lr) * 192 + kk * 32 + kg * 8);
        #pragma unroll
        for (int h = 0; h < 2; ++h)
            #pragma unroll
            for (int m = 0; m < 2; ++m) {
                short8 af = *(const short8*)(As + (size_t)(h * 32 + m * 16 + lr) * 200 + kk * 32 + kg * 8);
                acc[h][m] = __builtin_amdgcn_mfma_f32_16x16x32_bf16(af, bf, acc[h][m], 0, 0, 0);
            }
    }
    float bb = etb[c0 + lr];
    #pragma unroll
    for (int h = 0; h < 2; ++h)
        #pragma unroll
        for (int m = 0; m < 2; ++m)
            #pragma unroll
            for (int j = 0; j < 4; ++j)
                Hs[(m * 16 + kg * 4 + j) * 136 + h * 64 + c0 + lr] = f2bf(lky(acc[h][m][j] + bb));
    __syncthreads();
    // st layer: wave w -> cols [w*32, w*32+32); K=128
    int c0s = w * 32;
    f32x4 a2[2][2];
    #pragma unroll
    for (int m = 0; m < 2; ++m) { a2[m][0] = (f32x4){0.f,0.f,0.f,0.f}; a2[m][1] = (f32x4){0.f,0.f,0.f,0.f}; }
    for (int kk = 0; kk < 4; ++kk) {
        short8 bf0 = *(const short8*)(stWT + (size_t)(c0s + lr) * 128 + kk * 32 + kg * 8);
        short8 bf1 = *(const short8*)(stWT + (size_t)(c0s + 16 + lr) * 128 + kk * 32 + kg * 8);
        #pragma unroll
        for (int m = 0; m < 2; ++m) {
            short8 af = *(const short8*)(Hs + (m * 16 + lr) * 136 + kk * 32 + kg * 8);
            a2[m][0] = __builtin_amdgcn_mfma_f32_16x16x32_bf16(af, bf0, a2[m][0], 0, 0, 0);
            a2[m][1] = __builtin_amdgcn_mfma_f32_16x16x32_bf16(af, bf1, a2[m][1], 0, 0, 0);
        }
    }
    float lam = lamb[0];
    float sb0 = stb[c0s + lr], sb1 = stb[c0s + 16 + lr];
    #pragma unroll
    for (int m = 0; m < 2; ++m)
        #pragma unroll
        for (int j = 0; j < 4; ++j) {
            int n = row0 + m * 16 + kg * 4 + j;
            if (n < N) {
                int ca = c0s + lr, cb = c0s + 16 + lr;
                float va = lky(a2[m][0][j] + sb0);
                float vb = lky(a2[m][1][j] + sb1);
                out[(size_t)n * 128 + ca] = lam * stat[(size_t)n * 128 + ca] + (1.f - lam) * va;
                out[(size_t)n * 128 + cb] = lam * stat[(size_t)n * 128 + cb] + (1.f - lam) * vb;
            }
        }
}

extern "C" void kernel_launch(void* const* d_in, const int* in_sizes, int n_in,
                              void* d_out, int out_size, void* d_ws, size_t ws_size,
                              hipStream_t stream) {
    const int*   src        = (const int*)d_in[0];
    const int*   tgt        = (const int*)d_in[1];
    const float* ts         = (const float*)d_in[2];
    const float* now_time   = (const float*)d_in[3];
    const float* nodef      = (const float*)d_in[5];
    const float* memory     = (const float*)d_in[6];
    const float* last_upd   = (const float*)d_in[7];
    const float* vmem       = (const float*)d_in[8];
    const float* vlast      = (const float*)d_in[9];
    const float* A_r        = (const float*)d_in[10];
    const float* static_emb = (const float*)d_in[11];
    const float* lamb       = (const float*)d_in[12];
    const float* lambs      = (const float*)d_in[13];
    const float* mf_W1      = (const float*)d_in[14];
    const float* mf_b1      = (const float*)d_in[15];
    const float* mf_W2      = (const float*)d_in[16];
    const float* mf_b2      = (const float*)d_in[17];
    const float* ffr_W1     = (const float*)d_in[18];
    const float* ffr_b1     = (const float*)d_in[19];
    const float* ffr_W2     = (const float*)d_in[20];
    const float* ffr_b2     = (const float*)d_in[21];
    const float* et_W       = (const float*)d_in[22];
    const float* et_b       = (const float*)d_in[23];
    const float* st_W       = (const float*)d_in[24];
    const float* st_b       = (const float*)d_in[25];

    int E = in_sizes[0];
    int N = in_sizes[7];

    float* ws = (float*)d_ws;
    size_t off = 0;
    auto alloc = [&](size_t nf) { float* p = ws + off; off += (nf + 63) & ~(size_t)63; return p; };
    unsigned short* aggb  = (unsigned short*)alloc((size_t)SN * 384);     // SN*3 rows x 256 bf16
    unsigned short* msg_feat = (unsigned short*)alloc((size_t)N * 96);    // bf16
    unsigned short* AexpT   = (unsigned short*)alloc((size_t)224 * SN / 2);
    unsigned short* Aexp_rm = (unsigned short*)alloc((size_t)SN * 224 / 2);
    float* tv_union = alloc((size_t)VCM * 172032);      // temb (N*128) then vpart (VCM*172032)
    float* vmid     = alloc(224 * 768);
    unsigned short* vembT = (unsigned short*)alloc((size_t)192 * 224 / 2 + 64);
    float* t_max    = alloc(N);
    float* rowsum   = alloc(N);
    float* cnt3     = alloc((size_t)SN * 3);
    float* colsum   = alloc(256);
    unsigned short* W1T  = (unsigned short*)alloc(128 * 256 / 2);
    unsigned short* W2T  = (unsigned short*)alloc(64 * 128 / 2);
    unsigned short* etWT = (unsigned short*)alloc(64 * 192 / 2);
    unsigned short* stWT = (unsigned short*)alloc(128 * 128 / 2);
    int*   cnt      = (int*)alloc(NSCAN);               // padded+zeroed for int4 scan
    int*   offsets  = (int*)alloc(N + 1);
    int*   cursor   = (int*)alloc(N);
    int*   sorted   = (int*)alloc(E);
    int*   has_msg  = (int*)alloc(N);
    if (off * sizeof(float) > ws_size) return;   // workspace guard

    unsigned int* temb = (unsigned int*)tv_union;   // live: k_prep..k_agg
    float* vpart = tv_union;                        // live: k_vmid_mfma..k_vred
    // overlays: aggb region is dead after k_mf_mfma + k_vmid_mfma
    unsigned short* node_emb  = (unsigned short*)aggb;
    unsigned short* vnode_emb = node_emb + (size_t)N * 192;

    k_init<<<(NSCAN + 255) / 256, 256, 0, stream>>>(t_max, cnt, cursor, colsum, N, NSCAN);
    k_tbf<<<(256 * 128 + 255) / 256, 256, 0, stream>>>(mf_W1, W1T, 256, 128);
    k_tbf<<<(128 * 64 + 255) / 256, 256, 0, stream>>>(mf_W2, W2T, 128, 64);
    k_tbf<<<(192 * 64 + 255) / 256, 256, 0, stream>>>(et_W, etWT, 192, 64);
    k_tbf<<<(128 * 128 + 255) / 256, 256, 0, stream>>>(st_W, stWT, 128, 128);
    k_tmax_cnt<<<(E + 255) / 256, 256, 0, stream>>>(src, ts, t_max, cnt, E);
    k_scan<<<1, 1024, 0, stream>>>(cnt, offsets, N);
    k_scatter<<<(E + 255) / 256, 256, 0, stream>>>(src, offsets, cursor, sorted, E);
    k_prep<<<(N + 3) / 4, 256, 0, stream>>>(memory, nodef, temb, N);
    k_aexp<<<SN / 64, 256, 0, stream>>>(A_r, rowsum, colsum, AexpT, Aexp_rm, N);
    k_agg<<<SN / 4, 256, 0, stream>>>(tgt, ts, sorted, offsets, t_max, temb,
                                      lambs, (unsigned int*)aggb, cnt3, has_msg, N);
    k_mf_mfma<<<SN * 3 / 128, 256, 0, stream>>>(aggb, W1T, mf_b1, W2T, mf_b2, msg_feat, N * 3);
    k_vmid_mfma<<<NWG_V, 256, 0, stream>>>(AexpT, aggb, cnt3, vpart);
    k_vred<<<(224 * 768 + 255) / 256, 256, 0, stream>>>(vpart, colsum, vmid);
    k_ffr<<<42, 256, 0, stream>>>(vmid, ffr_W1, ffr_b1, ffr_W2, ffr_b2, vmem, vlast,
                                  lambs, now_time, vembT);
    k_newmem<<<N, 192, 0, stream>>>(memory, msg_feat, cnt3, t_max, last_upd, has_msg,
                                    lambs, node_emb, N);
    k_vnode_mfma<<<SN / 64, 256, 0, stream>>>(Aexp_rm, vembT, rowsum, vnode_emb, N);
    k_et_st_mfma<<<SN / 32, 256, 0, stream>>>(node_emb, vnode_emb, etWT, et_b, stWT, st_b,
                                              static_emb, lamb, (float*)d_out, N);
}

// Round 12
// 372.890 us; speedup vs baseline: 1.0438x; 1.0438x over previous
//
#include <hip/hip_runtime.h>

static __device__ __forceinline__ float lky(float x) { return x > 0.f ? x : 0.01f * x; }

static __device__ __forceinline__ unsigned short f2bf(float x) {
    unsigned int u = __float_as_uint(x);
    unsigned int r = (u + 0x7FFFu + ((u >> 16) & 1u)) >> 16;
    return (unsigned short)r;
}
static __device__ __forceinline__ float bf2f(unsigned short x) {
    return __uint_as_float((unsigned int)x << 16);
}
static __device__ __forceinline__ unsigned int pack2bf(float lo, float hi) {
    return (unsigned int)f2bf(lo) | ((unsigned int)f2bf(hi) << 16);
}

typedef __attribute__((ext_vector_type(8))) short short8;
typedef __attribute__((ext_vector_type(4))) float f32x4;

constexpr int SN  = 50048;   // padded node count (multiple of 64)
constexpr int KLV = 608;     // K(nodes) per split-K chunk (multiple of 32)
constexpr int VCM = 83;      // ceil(SN/KLV)
constexpr int NSCAN = 53248; // 13 * 4096, scan padding
constexpr int NWG_V = 12 * VCM;      // 996
constexpr int NQ_V  = NWG_V / 8;     // 124
constexpr int NR_V  = NWG_V % 8;     // 4

// ---------------- init ----------------
__global__ void k_init(float* t_max, int* cnt, int* cursor, float* colsum, int N, int NP) {
    int i = blockIdx.x * 256 + threadIdx.x;
    if (i < N) { t_max[i] = -1.0f; cursor[i] = 0; }
    if (i < NP) cnt[i] = 0;
    if (i < 224) colsum[i] = 0.0f;
}

// ---------------- weight transpose to bf16: dst[c*K+k] = src[k*C+c] ----------------
__global__ void k_tbf(const float* __restrict__ src, unsigned short* __restrict__ dst,
                      int K, int C) {
    int i = blockIdx.x * 256 + threadIdx.x;
    if (i >= K * C) return;
    int c = i / K, k = i % K;
    dst[i] = f2bf(src[k * C + c]);
}

// ---------------- per-edge t_max / counts ----------------
__global__ void k_tmax_cnt(const int* __restrict__ src, const float* __restrict__ ts,
                           float* t_max, int* cnt, int E) {
    int e = blockIdx.x * 256 + threadIdx.x;
    if (e >= E) return;
    int s = src[e];
    atomicMax((int*)(t_max + s), __float_as_int(ts[e]));   // ts >= 0, int-monotone
    atomicAdd(cnt + s, 1);
}

// ---------------- exclusive scan over counts (single block, 4096/iter) ----------------
__global__ __launch_bounds__(1024) void k_scan(const int* __restrict__ cnt,
                                               int* __restrict__ offsets, int N) {
    __shared__ int wsum[16];
    __shared__ int s_run;
    int t = threadIdx.x;
    int lane = t & 63, wid = t >> 6;
    if (t == 0) s_run = 0;
    __syncthreads();
    int nchunk = (N + 4095) >> 12;
    for (int c = 0; c < nchunk; ++c) {
        int i0 = (c << 12) + t * 4;
        int4 v = *(const int4*)(cnt + i0);     // cnt zero-padded to NSCAN
        int s = v.x + v.y + v.z + v.w;
        int x = s;
        #pragma unroll
        for (int d = 1; d < 64; d <<= 1) {
            int y = __shfl_up(x, d, 64);
            if (lane >= d) x += y;
        }
        if (lane == 63) wsum[wid] = x;
        __syncthreads();
        int wbase = 0;
        #pragma unroll
        for (int w = 0; w < 16; ++w) wbase += (w < wid) ? wsum[w] : 0;
        int run = s_run;
        int base = run + wbase + x - s;
        if (i0 + 3 < N) {
            int4 o;
            o.x = base; o.y = base + v.x; o.z = o.y + v.y; o.w = o.z + v.z;
            *(int4*)(offsets + i0) = o;
        } else {
            int o = base;
            if (i0 < N) offsets[i0] = o;
            o += v.x;
            if (i0 + 1 < N) offsets[i0 + 1] = o;
            o += v.y;
            if (i0 + 2 < N) offsets[i0 + 2] = o;
            o += v.z;
            if (i0 + 3 < N) offsets[i0 + 3] = o;
        }
        __syncthreads();
        if (t == 1023) s_run = run + wbase + x;
        __syncthreads();
    }
    if (t == 0) offsets[N] = s_run;
}

// ---------------- scatter edges into per-node buckets ----------------
__global__ void k_scatter(const int* __restrict__ src, const int* __restrict__ offsets,
                          int* cursor, int* sorted, int E) {
    int e = blockIdx.x * 256 + threadIdx.x;
    if (e >= E) return;
    int s = src[e];
    int pos = offsets[s] + atomicAdd(cursor + s, 1);
    sorted[pos] = e;
}

// ---------------- precompute normalized target embedding, bf16 [N][256] ----------------
__global__ __launch_bounds__(256) void k_prep(
        const float* __restrict__ memory, const float* __restrict__ nodef,
        unsigned int* __restrict__ temb, int N) {
    int wid = threadIdx.x >> 6, lane = threadIdx.x & 63;
    int n = blockIdx.x * 4 + wid;
    if (n >= N) return;
    const float* mrow = memory + (size_t)n * 195;
    float d0 = mrow[64], d1 = mrow[129], d2 = mrow[194];
    int f = 2 * lane;
    float den = (f < 64) ? d0 : d1;
    int offA = (f < 64) ? f : f + 1;
    float va0 = mrow[offA] / den;
    float va1 = mrow[offA + 1] / den;
    float vb0, vb1;
    if (lane < 32) {
        vb0 = mrow[130 + 2 * lane] / d2;
        vb1 = mrow[131 + 2 * lane] / d2;
    } else {
        const float* nf = nodef + (size_t)n * 64 + 2 * (lane - 32);
        vb0 = nf[0]; vb1 = nf[1];
    }
    temb[(size_t)n * 128 + lane]      = pack2bf(va0, va1);
    temb[(size_t)n * 128 + 64 + lane] = pack2bf(vb0, vb1);
}

// ---------------- A_r pass: rowsum, colsum, bf16 Aexp_rm + AexpT (throughput form) ----------------
__global__ __launch_bounds__(256) void k_aexp(
        const float* __restrict__ A_r,
        float* __restrict__ rowsum, float* __restrict__ colsum,
        unsigned short* __restrict__ AexpT, unsigned short* __restrict__ Aexp_rm, int N) {
    __shared__ unsigned short sE[64][228];   // 456B row stride: 8B-aligned, ~2-way banks
    int t = threadIdx.x;
    int n0 = blockIdx.x * 64;
    int maxq = min(64, N - n0) * 56;
    const float4* src = (const float4*)(A_r + (size_t)n0 * 224);
    #pragma unroll
    for (int k = 0; k < 14; ++k) {
        int i = t + k * 256;
        float4 v = (i < maxq) ? src[i] : (float4){-1e30f, -1e30f, -1e30f, -1e30f};
        int row = i / 56, cq = i % 56;
        uint2 pk;
        pk.x = pack2bf(__expf(v.x), __expf(v.y));
        pk.y = pack2bf(__expf(v.z), __expf(v.w));
        *(uint2*)&sE[row][cq * 4] = pk;
    }
    __syncthreads();
    // rowsum: 4 threads per row, 2 shuffles
    {
        int row = t >> 2, q = t & 3;
        const uint2* p = (const uint2*)&sE[row][q * 56];
        float s = 0.f;
        #pragma unroll
        for (int c = 0; c < 7; ++c) {
            uint2 u = p[c];
            s += __uint_as_float(u.x << 16) + __uint_as_float(u.x & 0xffff0000u)
               + __uint_as_float(u.y << 16) + __uint_as_float(u.y & 0xffff0000u);
        }
        s += __shfl_xor(s, 1, 64);
        s += __shfl_xor(s, 2, 64);
        if (q == 0 && n0 + row < N) rowsum[n0 + row] = s;
    }
    // colsum partials
    if (t < 224) {
        float s = 0.f;
        #pragma unroll 8
        for (int r = 0; r < 64; ++r) s += bf2f(sE[r][t]);
        atomicAdd(colsum + t, s);
    }
    // row-major write, packed uints, coalesced
    {
        unsigned int* dst = (unsigned int*)Aexp_rm;
        for (int i = t; i < 64 * 112; i += 256) {
            int n = i / 112, cp = i % 112;
            dst[(size_t)(n0 + n) * 112 + cp] = *(const unsigned int*)&sE[n][2 * cp];
        }
    }
    // transposed write: wave-coalesced 128B runs per r-row
    {
        unsigned int* dst = (unsigned int*)AexpT;
        for (int u = t; u < 224 * 32; u += 256) {
            int r = u >> 5, np = u & 31;
            unsigned int lo = sE[2 * np][r];
            unsigned int hi = sE[2 * np + 1][r];
            dst[(size_t)r * (SN / 2) + (n0 >> 1) + np] = lo | (hi << 16);
        }
    }
}

// ---------------- per-node aggregation: one wave per node, bf16 temb gather ----------------
__global__ __launch_bounds__(256) void k_agg(
        const int* __restrict__ tgt, const float* __restrict__ ts,
        const int* __restrict__ sorted, const int* __restrict__ offsets,
        const float* __restrict__ t_max, const unsigned int* __restrict__ temb,
        const float* __restrict__ lambs,
        unsigned int* __restrict__ aggb, float* __restrict__ cnt3,
        int* __restrict__ has_msg, int N) {
    int wid = threadIdx.x >> 6, lane = threadIdx.x & 63;
    int n = blockIdx.x * 4 + wid;      // n < SN (grid = SN/4)
    size_t rb = (size_t)n * 3;
    if (n >= N) {                       // zero-fill padding rows
        #pragma unroll
        for (int l = 0; l < 3; ++l) {
            unsigned int* row = aggb + (rb + l) * 128;
            row[lane] = 0; row[64 + lane] = 0;
            if (lane == 0) cnt3[rb + l] = 0.f;
        }
        return;
    }
    int beg = offsets[n], end = offsets[n + 1];
    float lb0 = lambs[0], lb1 = lambs[1], lb2 = lambs[2];
    float tm = t_max[n];
    float aa0[3], aa1[3], ab0[3], ab1[3], accc[3];
    #pragma unroll
    for (int l = 0; l < 3; ++l) { aa0[l] = aa1[l] = ab0[l] = ab1[l] = accc[l] = 0.f; }
    for (int idx = beg; idx < end; ++idx) {
        int e = sorted[idx];
        int tt = tgt[e];
        float d = tm - ts[e];
        unsigned int ua = temb[(size_t)tt * 128 + lane];
        unsigned int ub = temb[(size_t)tt * 128 + 64 + lane];
        float a0 = __uint_as_float(ua << 16);
        float a1 = __uint_as_float(ua & 0xffff0000u);
        float b0 = __uint_as_float(ub << 16);
        float b1 = __uint_as_float(ub & 0xffff0000u);
        float w0 = __expf(-lb0 * d), w1 = __expf(-lb1 * d), w2 = __expf(-lb2 * d);
        aa0[0] += w0 * a0; aa1[0] += w0 * a1; ab0[0] += w0 * b0; ab1[0] += w0 * b1; accc[0] += w0;
        aa0[1] += w1 * a0; aa1[1] += w1 * a1; ab0[1] += w1 * b0; ab1[1] += w1 * b1; accc[1] += w1;
        aa0[2] += w2 * a0; aa1[2] += w2 * a1; ab0[2] += w2 * b0; ab1[2] += w2 * b1; accc[2] += w2;
    }
    #pragma unroll
    for (int l = 0; l < 3; ++l) {
        unsigned int* row = aggb + (rb + l) * 128;
        row[lane]      = pack2bf(aa0[l], aa1[l]);
        row[64 + lane] = pack2bf(ab0[l], ab1[l]);
        if (lane == 0) cnt3[rb + l] = accc[l];
    }
    if (lane == 0) has_msg[n] = (end > beg) ? 1 : 0;
}

// ---------------- mf MLP via MFMA (round-7 measured-best): 64 rows/block, LDS-staged ----------------
__global__ __launch_bounds__(256) void k_mf_mfma(
        const unsigned short* __restrict__ aggb,
        const unsigned short* __restrict__ W1T, const float* __restrict__ b1,
        const unsigned short* __restrict__ W2T, const float* __restrict__ b2,
        unsigned short* __restrict__ msg_feat, int NROWS) {
    __shared__ unsigned short As[64 * 264];
    __shared__ unsigned short Hs[64 * 136];
    int t = threadIdx.x, lane = t & 63, w = t >> 6;
    int lr = lane & 15, kg = lane >> 4;
    int row0 = blockIdx.x * 64;
    {   // stage A: 64 rows x 256 bf16, 4 threads/row
        int r = t >> 2, s4 = t & 3;
        const uint4* src = (const uint4*)(aggb + (size_t)(row0 + r) * 256 + s4 * 64);
        uint4* dst = (uint4*)(As + r * 264 + s4 * 64);
        #pragma unroll
        for (int u = 0; u < 8; ++u) dst[u] = src[u];
    }
    __syncthreads();
    // layer 1: wave w -> cols [w*32, w*32+32)
    int n0 = w * 32;
    f32x4 acc[4][2];
    #pragma unroll
    for (int m = 0; m < 4; ++m) {
        acc[m][0] = (f32x4){0.f, 0.f, 0.f, 0.f};
        acc[m][1] = (f32x4){0.f, 0.f, 0.f, 0.f};
    }
    for (int kk = 0; kk < 8; ++kk) {
        short8 bf0 = *(const short8*)(W1T + (size_t)(n0 + lr) * 256 + kk * 32 + kg * 8);
        short8 bf1 = *(const short8*)(W1T + (size_t)(n0 + 16 + lr) * 256 + kk * 32 + kg * 8);
        #pragma unroll
        for (int m = 0; m < 4; ++m) {
            short8 af = *(const short8*)(As + (m * 16 + lr) * 264 + kk * 32 + kg * 8);
            acc[m][0] = __builtin_amdgcn_mfma_f32_16x16x32_bf16(af, bf0, acc[m][0], 0, 0, 0);
            acc[m][1] = __builtin_amdgcn_mfma_f32_16x16x32_bf16(af, bf1, acc[m][1], 0, 0, 0);
        }
    }
    float bb0 = b1[n0 + lr], bb1 = b1[n0 + 16 + lr];
    #pragma unroll
    for (int m = 0; m < 4; ++m)
        #pragma unroll
        for (int j = 0; j < 4; ++j) {
            int row = m * 16 + kg * 4 + j;
            Hs[row * 136 + n0 + lr]      = f2bf(fmaxf(acc[m][0][j] + bb0, 0.f));
            Hs[row * 136 + n0 + 16 + lr] = f2bf(fmaxf(acc[m][1][j] + bb1, 0.f));
        }
    __syncthreads();
    // layer 2: wave w -> cols [w*16, w*16+16)
    int c0 = w * 16;
    f32x4 a2[4];
    #pragma unroll
    for (int m = 0; m < 4; ++m) a2[m] = (f32x4){0.f, 0.f, 0.f, 0.f};
    for (int kk = 0; kk < 4; ++kk) {
        short8 bf = *(const short8*)(W2T + (size_t)(c0 + lr) * 128 + kk * 32 + kg * 8);
        #pragma unroll
        for (int m = 0; m < 4; ++m) {
            short8 af = *(const short8*)(Hs + (m * 16 + lr) * 136 + kk * 32 + kg * 8);
            a2[m] = __builtin_amdgcn_mfma_f32_16x16x32_bf16(af, bf, a2[m], 0, 0, 0);
        }
    }
    float b2v = b2[c0 + lr];
    #pragma unroll
    for (int m = 0; m < 4; ++m)
        #pragma unroll
        for (int j = 0; j < 4; ++j) {
            int row = row0 + m * 16 + kg * 4 + j;
            if (row < NROWS)
                msg_feat[(size_t)row * 64 + c0 + lr] = f2bf(fmaxf(a2[m][j] + b2v, 0.f));
        }
}

// ---------------- vmid via bf16 MFMA, split-K; XCD-swizzled, B LDS-staged ----------------
__global__ __launch_bounds__(256) void k_vmid_mfma(
        const unsigned short* __restrict__ AexpT, const unsigned short* __restrict__ aggb,
        const float* __restrict__ cnt3, float* __restrict__ vpart) {
    __shared__ unsigned short As[112 * 40];   // 112 rows x 32 shorts (stride 40 = 80B)
    __shared__ unsigned int BsT[128 * 20];    // [col][np-uint] stride 20; np ^= ((col>>3)&3)<<2
    // bijective XCD swizzle: co-locate the 12 tiles of each chunk on one XCD
    int bx = blockIdx.x;
    int xcd = bx & 7, bidx = bx >> 3;
    int virt = (xcd < NR_V) ? xcd * (NQ_V + 1) + bidx
                            : NR_V * (NQ_V + 1) + (xcd - NR_V) * NQ_V + bidx;
    int chunk = virt / 12, tile = virt % 12;
    int r0 = (tile & 1) * 112;
    int ft = tile >> 1;                 // 0..5
    int l = ft >> 1, fo = (ft & 1) * 128;
    int t = threadIdx.x, lane = t & 63, w = t >> 6;
    int lr = lane & 15, kg = lane >> 4;
    int np = t >> 4, sg = t & 15;       // B staging: node-pair, col-segment(8 cols)
    f32x4 acc[7][2];
    #pragma unroll
    for (int q = 0; q < 7; ++q) {
        acc[q][0] = (f32x4){0.f, 0.f, 0.f, 0.f};
        acc[q][1] = (f32x4){0.f, 0.f, 0.f, 0.f};
    }
    int nbeg = chunk * KLV;
    int nsteps = min(KLV, SN - nbeg) >> 5;
    int c0 = w * 32 + lr, c1 = c0 + 16;
    int rb0 = c0 * 20 + (kg ^ ((c0 >> 3) & 3)) * 4;
    int rb1 = c1 * 20 + (kg ^ ((c1 >> 3) & 3)) * 4;
    int swz = np ^ ((sg & 3) << 2);
    for (int s = 0; s < nsteps; ++s) {
        int n0 = nbeg + s * 32;
        if (t < 224) {                   // stage A: 2 threads/row, 32 shorts/row
            int srow = t >> 1, sseg = t & 1;
            const uint4* ap = (const uint4*)(AexpT + (size_t)(r0 + srow) * SN + n0) + sseg * 2;
            uint4 v0 = ap[0];
            uint4 v1 = ap[1];
            *(uint4*)&As[srow * 40 + sseg * 16]     = v0;
            *(uint4*)&As[srow * 40 + sseg * 16 + 8] = v1;
        }
        {   // stage B: nodes (2np, 2np+1) x cols [sg*8, sg*8+8), scaled by 1/den, k-pair packed
            int na = n0 + 2 * np;
            size_t ra = ((size_t)na * 3 + l) * 256 + fo + sg * 8;
            uint4 va = *(const uint4*)(aggb + ra);
            uint4 vb = *(const uint4*)(aggb + ra + 768);
            float da = 1.f / fmaxf(cnt3[(size_t)na * 3 + l], 1e-6f);
            float db = 1.f / fmaxf(cnt3[(size_t)na * 3 + l + 3], 1e-6f);
            const unsigned short* pa = (const unsigned short*)&va;
            const unsigned short* pb = (const unsigned short*)&vb;
            unsigned int* dst = BsT + sg * 160 + swz;
            #pragma unroll
            for (int j = 0; j < 8; ++j)
                dst[j * 20] = pack2bf(bf2f(pa[j]) * da, bf2f(pb[j]) * db);
        }
        __syncthreads();
        short8 b0 = *(const short8*)((const unsigned short*)(BsT + rb0));
        short8 b1 = *(const short8*)((const unsigned short*)(BsT + rb1));
        #pragma unroll
        for (int q = 0; q < 7; ++q) {
            short8 af = *(const short8*)&As[(q * 16 + lr) * 40 + kg * 8];
            acc[q][0] = __builtin_amdgcn_mfma_f32_16x16x32_bf16(af, b0, acc[q][0], 0, 0, 0);
            acc[q][1] = __builtin_amdgcn_mfma_f32_16x16x32_bf16(af, b1, acc[q][1], 0, 0, 0);
        }
        __syncthreads();
    }
    float* outp = vpart + (size_t)chunk * 172032;
    #pragma unroll
    for (int q = 0; q < 7; ++q) {
        int row = r0 + q * 16 + kg * 4;
        #pragma unroll
        for (int p = 0; p < 2; ++p) {
            int col = l * 256 + fo + w * 32 + p * 16 + lr;
            #pragma unroll
            for (int j = 0; j < 4; ++j)
                outp[(size_t)(row + j) * 768 + col] = acc[q][p][j];
        }
    }
}

// ---------------- reduce vpart over chunks, divide by colsum ----------------
__global__ void k_vred(const float* __restrict__ vpart, const float* __restrict__ colsum,
                       float* __restrict__ vmid) {
    int idx = blockIdx.x * 256 + threadIdx.x;
    if (idx >= 224 * 768) return;
    float s = 0.f;
    for (int c = 0; c < VCM; ++c) s += vpart[(long)c * (224 * 768) + idx];
    vmid[idx] = s / colsum[idx / 768];
}

// ---------------- ffr MLP (672 rows) + virtual-memory decay -> vembT (bf16) ----------------
__global__ __launch_bounds__(256) void k_ffr(
        const float* __restrict__ vmid, const float* __restrict__ W1, const float* __restrict__ b1,
        const float* __restrict__ W2, const float* __restrict__ b2,
        const float* __restrict__ vmem, const float* __restrict__ vlast,
        const float* __restrict__ lambs, const float* __restrict__ now_time,
        unsigned short* __restrict__ vembT) {
    __shared__ float sin_[16][260];
    __shared__ float svh[16][260];
    int row0 = blockIdx.x * 16;
    int t = threadIdx.x;
    #pragma unroll
    for (int k = 0; k < 16; ++k) {
        int idx = t + k * 256;
        int r = idx >> 8, f = idx & 255;
        sin_[r][f] = vmid[(long)(row0 + r) * 256 + f];
    }
    __syncthreads();
    {   // layer 1: 16 x 256, 4r x 4c
        int cg = t & 63, rg = t >> 6;
        int c0 = cg * 4, r0 = rg * 4;
        float acc[4][4];
        #pragma unroll
        for (int i = 0; i < 4; ++i)
            #pragma unroll
            for (int j = 0; j < 4; ++j) acc[i][j] = 0.f;
        for (int f0 = 0; f0 < 256; f0 += 4) {
            float4 a[4];
            #pragma unroll
            for (int i = 0; i < 4; ++i) a[i] = *(const float4*)&sin_[r0 + i][f0];
            #pragma unroll
            for (int ff = 0; ff < 4; ++ff) {
                float4 w = *(const float4*)&W1[(long)(f0 + ff) * 256 + c0];
                #pragma unroll
                for (int i = 0; i < 4; ++i) {
                    float av = (&a[i].x)[ff];
                    acc[i][0] += av * w.x; acc[i][1] += av * w.y;
                    acc[i][2] += av * w.z; acc[i][3] += av * w.w;
                }
            }
        }
        #pragma unroll
        for (int i = 0; i < 4; ++i)
            #pragma unroll
            for (int j = 0; j < 4; ++j)
                svh[r0 + i][c0 + j] = lky(acc[i][j] + b1[c0 + j]);
    }
    __syncthreads();
    {   // layer 2: 16 x 64, 2r x 2c + decay epilogue
        int cg = t & 31, rg = t >> 5;
        int c0 = cg * 2, r0 = rg * 2;
        float acc[2][2];
        acc[0][0] = acc[0][1] = acc[1][0] = acc[1][1] = 0.f;
        for (int f0 = 0; f0 < 256; f0 += 4) {
            float4 a[2];
            #pragma unroll
            for (int i = 0; i < 2; ++i) a[i] = *(const float4*)&svh[r0 + i][f0];
            #pragma unroll
            for (int ff = 0; ff < 4; ++ff) {
                float2 w = *(const float2*)&W2[(long)(f0 + ff) * 64 + c0];
                #pragma unroll
                for (int i = 0; i < 2; ++i) {
                    float av = (&a[i].x)[ff];
                    acc[i][0] += av * w.x; acc[i][1] += av * w.y;
                }
            }
        }
        float nowv = now_time[0];
        #pragma unroll
        for (int i = 0; i < 2; ++i) {
            int row = row0 + r0 + i;           // row = rr*3 + l
            int rr = row / 3, l = row % 3;
            float vd = __expf(-lambs[l] * (nowv - vlast[rr]));
            #pragma unroll
            for (int j = 0; j < 2; ++j) {
                float v = lky(acc[i][j] + b2[c0 + j]);
                int m = c0 + j;
                vembT[(size_t)(l * 64 + m) * 224 + rr] =
                    f2bf(vmem[(long)rr * 192 + l * 64 + m] * vd + v);
            }
        }
    }
}

// ---------------- new_mem -> node_emb (bf16) ----------------
__global__ void k_newmem(const float* __restrict__ memory,
        const unsigned short* __restrict__ msg_feat,
        const float* __restrict__ cnt3, const float* __restrict__ t_max,
        const float* __restrict__ last_update, const int* __restrict__ has_msg,
        const float* __restrict__ lambs, unsigned short* __restrict__ node_emb, int N) {
    int n = blockIdx.x;
    int j = threadIdx.x;                 // 0..191
    int l = j >> 6, m = j & 63;
    int has = has_msg[n];
    float dt = has ? (t_max[n] - last_update[n]) : 0.f;
    float decay = __expf(-lambs[l] * dt);
    long mb = (long)n * 195 + l * 65;
    float num = memory[mb + m];
    float den = memory[mb + 64];
    if (has) {
        num = num * decay + bf2f(msg_feat[(size_t)n * 192 + j]);
        den = den * decay + cnt3[(size_t)n * 3 + l];
    }
    node_emb[(size_t)n * 192 + j] = f2bf(num / fmaxf(den, 1e-6f));
}

// ---------------- vnode_emb = row-softmax(A_r) @ v_emb via MFMA (LDS-staged A) ----------------
__global__ __launch_bounds__(256) void k_vnode_mfma(
        const unsigned short* __restrict__ Aexp_rm, const unsigned short* __restrict__ vembT,
        const float* __restrict__ rowsum, unsigned short* __restrict__ vnode_emb, int N) {
    __shared__ unsigned short As[64 * 232];
    __shared__ float sRS[64];
    int t = threadIdx.x, lane = t & 63, w = t >> 6;
    int lr = lane & 15, kg = lane >> 4;
    int row0 = blockIdx.x * 64;
    {
        int r = t >> 2, sg = t & 3;
        const uint4* src = (const uint4*)(Aexp_rm + (size_t)(row0 + r) * 224 + sg * 56);
        uint4* dst = (uint4*)(As + r * 232 + sg * 56);
        #pragma unroll
        for (int u = 0; u < 7; ++u) dst[u] = src[u];
    }
    if (t < 64) sRS[t] = rowsum[min(row0 + t, N - 1)];
    __syncthreads();
    int n0 = w * 48;                      // 192 cols / 4 waves
    f32x4 acc[4][3];
    #pragma unroll
    for (int m = 0; m < 4; ++m)
        #pragma unroll
        for (int nt = 0; nt < 3; ++nt) acc[m][nt] = (f32x4){0.f, 0.f, 0.f, 0.f};
    for (int kk = 0; kk < 7; ++kk) {
        short8 bf[3];
        #pragma unroll
        for (int nt = 0; nt < 3; ++nt)
            bf[nt] = *(const short8*)(vembT + (size_t)(n0 + nt * 16 + lr) * 224 + kk * 32 + kg * 8);
        #pragma unroll
        for (int m = 0; m < 4; ++m) {
            short8 af = *(const short8*)(As + (m * 16 + lr) * 232 + kk * 32 + kg * 8);
            #pragma unroll
            for (int nt = 0; nt < 3; ++nt)
                acc[m][nt] = __builtin_amdgcn_mfma_f32_16x16x32_bf16(af, bf[nt], acc[m][nt], 0, 0, 0);
        }
    }
    #pragma unroll
    for (int m = 0; m < 4; ++m)
        #pragma unroll
        for (int j = 0; j < 4; ++j) {
            int row = row0 + m * 16 + kg * 4 + j;
            if (row < N) {
                float inv = 1.f / sRS[row - row0];
                #pragma unroll
                for (int nt = 0; nt < 3; ++nt)
                    vnode_emb[(size_t)row * 192 + n0 + nt * 16 + lr] = f2bf(acc[m][nt][j] * inv);
            }
        }
}

// ---------------- et + st + output blend via MFMA: 32 rows/block, LDS-staged ----------------
__global__ __launch_bounds__(256) void k_et_st_mfma(
        const unsigned short* __restrict__ ne, const unsigned short* __restrict__ ve,
        const unsigned short* __restrict__ etWT, const float* __restrict__ etb,
        const unsigned short* __restrict__ stWT, const float* __restrict__ stb,
        const float* __restrict__ stat, const float* __restrict__ lamb,
        float* __restrict__ out, int N) {
    __shared__ unsigned short As[64 * 200];    // rows 0-31: node, 32-63: vnode
    __shared__ unsigned short Hs[32 * 136];    // st input [32 rows][128 cols]
    int t = threadIdx.x, lane = t & 63, w = t >> 6;
    int lr = lane & 15, kg = lane >> 4;
    int row0 = blockIdx.x * 32;
    {
        int r = t >> 3, s8 = t & 7;            // 8 threads/row, 48B each
        const uint4* sn = (const uint4*)(ne + (size_t)(row0 + r) * 192 + s8 * 24);
        const uint4* sv = (const uint4*)(ve + (size_t)(row0 + r) * 192 + s8 * 24);
        uint4* dn = (uint4*)(As + (size_t)r * 200 + s8 * 24);
        uint4* dv = (uint4*)(As + (size_t)(32 + r) * 200 + s8 * 24);
        #pragma unroll
        for (int u = 0; u < 3; ++u) { dn[u] = sn[u]; dv[u] = sv[u]; }
    }
    __syncthreads();
    // et layer: wave w -> cols [w*16, w*16+16), both halves; K=192
    int c0 = w * 16;
    f32x4 acc[2][2];
    #pragma unroll
    for (int h = 0; h < 2; ++h)
        #pragma unroll
        for (int m = 0; m < 2; ++m) acc[h][m] = (f32x4){0.f, 0.f, 0.f, 0.f};
    for (int kk = 0; kk < 6; ++kk) {
        short8 bf = *(const short8*)(etWT + (size_t)(c0 + lr) * 192 + kk * 32 + kg * 8);
        #pragma unroll
        for (int h = 0; h < 2; ++h)
            #pragma unroll
            for (int m = 0; m < 2; ++m) {
                short8 af = *(const short8*)(As + (size_t)(h * 32 + m * 16 + lr) * 200 + kk * 32 + kg * 8);
                acc[h][m] = __builtin_amdgcn_mfma_f32_16x16x32_bf16(af, bf, acc[h][m], 0, 0, 0);
            }
    }
    float bb = etb[c0 + lr];
    #pragma unroll
    for (int h = 0; h < 2; ++h)
        #pragma unroll
        for (int m = 0; m < 2; ++m)
            #pragma unroll
            for (int j = 0; j < 4; ++j)
                Hs[(m * 16 + kg * 4 + j) * 136 + h * 64 + c0 + lr] = f2bf(lky(acc[h][m][j] + bb));
    __syncthreads();
    // st layer: wave w -> cols [w*32, w*32+32); K=128
    int c0s = w * 32;
    f32x4 a2[2][2];
    #pragma unroll
    for (int m = 0; m < 2; ++m) { a2[m][0] = (f32x4){0.f,0.f,0.f,0.f}; a2[m][1] = (f32x4){0.f,0.f,0.f,0.f}; }
    for (int kk = 0; kk < 4; ++kk) {
        short8 bf0 = *(const short8*)(stWT + (size_t)(c0s + lr) * 128 + kk * 32 + kg * 8);
        short8 bf1 = *(const short8*)(stWT + (size_t)(c0s + 16 + lr) * 128 + kk * 32 + kg * 8);
        #pragma unroll
        for (int m = 0; m < 2; ++m) {
            short8 af = *(const short8*)(Hs + (m * 16 + lr) * 136 + kk * 32 + kg * 8);
            a2[m][0] = __builtin_amdgcn_mfma_f32_16x16x32_bf16(af, bf0, a2[m][0], 0, 0, 0);
            a2[m][1] = __builtin_amdgcn_mfma_f32_16x16x32_bf16(af, bf1, a2[m][1], 0, 0, 0);
        }
    }
    float lam = lamb[0];
    float sb0 = stb[c0s + lr], sb1 = stb[c0s + 16 + lr];
    #pragma unroll
    for (int m = 0; m < 2; ++m)
        #pragma unroll
        for (int j = 0; j < 4; ++j) {
            int n = row0 + m * 16 + kg * 4 + j;
            if (n < N) {
                int ca = c0s + lr, cb = c0s + 16 + lr;
                float va = lky(a2[m][0][j] + sb0);
                float vb = lky(a2[m][1][j] + sb1);
                out[(size_t)n * 128 + ca] = lam * stat[(size_t)n * 128 + ca] + (1.f - lam) * va;
                out[(size_t)n * 128 + cb] = lam * stat[(size_t)n * 128 + cb] + (1.f - lam) * vb;
            }
        }
}

extern "C" void kernel_launch(void* const* d_in, const int* in_sizes, int n_in,
                              void* d_out, int out_size, void* d_ws, size_t ws_size,
                              hipStream_t stream) {
    const int*   src        = (const int*)d_in[0];
    const int*   tgt        = (const int*)d_in[1];
    const float* ts         = (const float*)d_in[2];
    const float* now_time   = (const float*)d_in[3];
    const float* nodef      = (const float*)d_in[5];
    const float* memory     = (const float*)d_in[6];
    const float* last_upd   = (const float*)d_in[7];
    const float* vmem       = (const float*)d_in[8];
    const float* vlast      = (const float*)d_in[9];
    const float* A_r        = (const float*)d_in[10];
    const float* static_emb = (const float*)d_in[11];
    const float* lamb       = (const float*)d_in[12];
    const float* lambs      = (const float*)d_in[13];
    const float* mf_W1      = (const float*)d_in[14];
    const float* mf_b1      = (const float*)d_in[15];
    const float* mf_W2      = (const float*)d_in[16];
    const float* mf_b2      = (const float*)d_in[17];
    const float* ffr_W1     = (const float*)d_in[18];
    const float* ffr_b1     = (const float*)d_in[19];
    const float* ffr_W2     = (const float*)d_in[20];
    const float* ffr_b2     = (const float*)d_in[21];
    const float* et_W       = (const float*)d_in[22];
    const float* et_b       = (const float*)d_in[23];
    const float* st_W       = (const float*)d_in[24];
    const float* st_b       = (const float*)d_in[25];

    int E = in_sizes[0];
    int N = in_sizes[7];

    float* ws = (float*)d_ws;
    size_t off = 0;
    auto alloc = [&](size_t nf) { float* p = ws + off; off += (nf + 63) & ~(size_t)63; return p; };
    unsigned short* aggb  = (unsigned short*)alloc((size_t)SN * 384);     // SN*3 rows x 256 bf16
    unsigned short* msg_feat = (unsigned short*)alloc((size_t)N * 96);    // bf16
    unsigned short* AexpT   = (unsigned short*)alloc((size_t)224 * SN / 2);
    unsigned short* Aexp_rm = (unsigned short*)alloc((size_t)SN * 224 / 2);
    float* tv_union = alloc((size_t)VCM * 172032);      // temb (N*128) then vpart (VCM*172032)
    float* vmid     = alloc(224 * 768);
    unsigned short* vembT = (unsigned short*)alloc((size_t)192 * 224 / 2 + 64);
    float* t_max    = alloc(N);
    float* rowsum   = alloc(N);
    float* cnt3     = alloc((size_t)SN * 3);
    float* colsum   = alloc(256);
    unsigned short* W1T  = (unsigned short*)alloc(128 * 256 / 2);
    unsigned short* W2T  = (unsigned short*)alloc(64 * 128 / 2);
    unsigned short* etWT = (unsigned short*)alloc(64 * 192 / 2);
    unsigned short* stWT = (unsigned short*)alloc(128 * 128 / 2);
    int*   cnt      = (int*)alloc(NSCAN);               // padded+zeroed for int4 scan
    int*   offsets  = (int*)alloc(N + 1);
    int*   cursor   = (int*)alloc(N);
    int*   sorted   = (int*)alloc(E);
    int*   has_msg  = (int*)alloc(N);
    if (off * sizeof(float) > ws_size) return;   // workspace guard

    unsigned int* temb = (unsigned int*)tv_union;   // live: k_prep..k_agg
    float* vpart = tv_union;                        // live: k_vmid_mfma..k_vred
    // overlays: aggb region is dead after k_mf_mfma + k_vmid_mfma
    unsigned short* node_emb  = (unsigned short*)aggb;
    unsigned short* vnode_emb = node_emb + (size_t)N * 192;

    k_init<<<(NSCAN + 255) / 256, 256, 0, stream>>>(t_max, cnt, cursor, colsum, N, NSCAN);
    k_tbf<<<(256 * 128 + 255) / 256, 256, 0, stream>>>(mf_W1, W1T, 256, 128);
    k_tbf<<<(128 * 64 + 255) / 256, 256, 0, stream>>>(mf_W2, W2T, 128, 64);
    k_tbf<<<(192 * 64 + 255) / 256, 256, 0, stream>>>(et_W, etWT, 192, 64);
    k_tbf<<<(128 * 128 + 255) / 256, 256, 0, stream>>>(st_W, stWT, 128, 128);
    k_tmax_cnt<<<(E + 255) / 256, 256, 0, stream>>>(src, ts, t_max, cnt, E);
    k_scan<<<1, 1024, 0, stream>>>(cnt, offsets, N);
    k_scatter<<<(E + 255) / 256, 256, 0, stream>>>(src, offsets, cursor, sorted, E);
    k_prep<<<(N + 3) / 4, 256, 0, stream>>>(memory, nodef, temb, N);
    k_aexp<<<SN / 64, 256, 0, stream>>>(A_r, rowsum, colsum, AexpT, Aexp_rm, N);
    k_agg<<<SN / 4, 256, 0, stream>>>(tgt, ts, sorted, offsets, t_max, temb,
                                      lambs, (unsigned int*)aggb, cnt3, has_msg, N);
    k_mf_mfma<<<SN * 3 / 64, 256, 0, stream>>>(aggb, W1T, mf_b1, W2T, mf_b2, msg_feat, N * 3);
    k_vmid_mfma<<<NWG_V, 256, 0, stream>>>(AexpT, aggb, cnt3, vpart);
    k_vred<<<(224 * 768 + 255) / 256, 256, 0, stream>>>(vpart, colsum, vmid);
    k_ffr<<<42, 256, 0, stream>>>(vmid, ffr_W1, ffr_b1, ffr_W2, ffr_b2, vmem, vlast,
                                  lambs, now_time, vembT);
    k_newmem<<<N, 192, 0, stream>>>(memory, msg_feat, cnt3, t_max, last_upd, has_msg,
                                    lambs, node_emb, N);
    k_vnode_mfma<<<SN / 64, 256, 0, stream>>>(Aexp_rm, vembT, rowsum, vnode_emb, N);
    k_et_st_mfma<<<SN / 32, 256, 0, stream>>>(node_emb, vnode_emb, etWT, et_b, stWT, st_b,
                                              static_emb, lamb, (float*)d_out, N);
}

// Round 13
// 372.061 us; speedup vs baseline: 1.0461x; 1.0022x over previous
//
#include <hip/hip_runtime.h>

static __device__ __forceinline__ float lky(float x) { return x > 0.f ? x : 0.01f * x; }

static __device__ __forceinline__ unsigned short f2bf(float x) {
    unsigned int u = __float_as_uint(x);
    unsigned int r = (u + 0x7FFFu + ((u >> 16) & 1u)) >> 16;
    return (unsigned short)r;
}
static __device__ __forceinline__ float bf2f(unsigned short x) {
    return __uint_as_float((unsigned int)x << 16);
}
static __device__ __forceinline__ unsigned int pack2bf(float lo, float hi) {
    return (unsigned int)f2bf(lo) | ((unsigned int)f2bf(hi) << 16);
}

typedef __attribute__((ext_vector_type(8))) short short8;
typedef __attribute__((ext_vector_type(4))) float f32x4;

constexpr int SN  = 50048;   // padded node count (multiple of 64)
constexpr int KLV = 608;     // K(nodes) per split-K chunk (multiple of 32)
constexpr int VCM = 83;      // ceil(SN/KLV)
constexpr int NSCAN = 53248; // 13 * 4096, scan padding
constexpr int NWG_V = 12 * VCM;      // 996
constexpr int NQ_V  = NWG_V / 8;     // 124
constexpr int NR_V  = NWG_V % 8;     // 4
constexpr int AGG_BLOCKS = 2048;     // persistent k_agg blocks
constexpr int AGG_WAVES  = AGG_BLOCKS * 4;

// ---------------- init ----------------
__global__ void k_init(float* t_max, int* cnt, int* cursor, float* colsum, int N, int NP) {
    int i = blockIdx.x * 256 + threadIdx.x;
    if (i < N) { t_max[i] = -1.0f; cursor[i] = 0; }
    if (i < NP) cnt[i] = 0;
    if (i < 224) colsum[i] = 0.0f;
}

// ---------------- weight transpose to bf16: dst[c*K+k] = src[k*C+c] ----------------
__global__ void k_tbf(const float* __restrict__ src, unsigned short* __restrict__ dst,
                      int K, int C) {
    int i = blockIdx.x * 256 + threadIdx.x;
    if (i >= K * C) return;
    int c = i / K, k = i % K;
    dst[i] = f2bf(src[k * C + c]);
}

// ---------------- per-edge t_max / counts ----------------
__global__ void k_tmax_cnt(const int* __restrict__ src, const float* __restrict__ ts,
                           float* t_max, int* cnt, int E) {
    int e = blockIdx.x * 256 + threadIdx.x;
    if (e >= E) return;
    int s = src[e];
    atomicMax((int*)(t_max + s), __float_as_int(ts[e]));   // ts >= 0, int-monotone
    atomicAdd(cnt + s, 1);
}

// ---------------- exclusive scan over counts (single block, 4096/iter) ----------------
__global__ __launch_bounds__(1024) void k_scan(const int* __restrict__ cnt,
                                               int* __restrict__ offsets, int N) {
    __shared__ int wsum[16];
    __shared__ int s_run;
    int t = threadIdx.x;
    int lane = t & 63, wid = t >> 6;
    if (t == 0) s_run = 0;
    __syncthreads();
    int nchunk = (N + 4095) >> 12;
    for (int c = 0; c < nchunk; ++c) {
        int i0 = (c << 12) + t * 4;
        int4 v = *(const int4*)(cnt + i0);     // cnt zero-padded to NSCAN
        int s = v.x + v.y + v.z + v.w;
        int x = s;
        #pragma unroll
        for (int d = 1; d < 64; d <<= 1) {
            int y = __shfl_up(x, d, 64);
            if (lane >= d) x += y;
        }
        if (lane == 63) wsum[wid] = x;
        __syncthreads();
        int wbase = 0;
        #pragma unroll
        for (int w = 0; w < 16; ++w) wbase += (w < wid) ? wsum[w] : 0;
        int run = s_run;
        int base = run + wbase + x - s;
        if (i0 + 3 < N) {
            int4 o;
            o.x = base; o.y = base + v.x; o.z = o.y + v.y; o.w = o.z + v.z;
            *(int4*)(offsets + i0) = o;
        } else {
            int o = base;
            if (i0 < N) offsets[i0] = o;
            o += v.x;
            if (i0 + 1 < N) offsets[i0 + 1] = o;
            o += v.y;
            if (i0 + 2 < N) offsets[i0 + 2] = o;
            o += v.z;
            if (i0 + 3 < N) offsets[i0 + 3] = o;
        }
        __syncthreads();
        if (t == 1023) s_run = run + wbase + x;
        __syncthreads();
    }
    if (t == 0) offsets[N] = s_run;
}

// ---------------- scatter edges into per-node buckets ----------------
__global__ void k_scatter(const int* __restrict__ src, const int* __restrict__ offsets,
                          int* cursor, int* sorted, int E) {
    int e = blockIdx.x * 256 + threadIdx.x;
    if (e >= E) return;
    int s = src[e];
    int pos = offsets[s] + atomicAdd(cursor + s, 1);
    sorted[pos] = e;
}

// ---------------- precompute normalized target embedding, bf16 [N][256] ----------------
__global__ __launch_bounds__(256) void k_prep(
        const float* __restrict__ memory, const float* __restrict__ nodef,
        unsigned int* __restrict__ temb, int N) {
    int wid = threadIdx.x >> 6, lane = threadIdx.x & 63;
    int n = blockIdx.x * 4 + wid;
    if (n >= N) return;
    const float* mrow = memory + (size_t)n * 195;
    float d0 = mrow[64], d1 = mrow[129], d2 = mrow[194];
    int f = 2 * lane;
    float den = (f < 64) ? d0 : d1;
    int offA = (f < 64) ? f : f + 1;
    float va0 = mrow[offA] / den;
    float va1 = mrow[offA + 1] / den;
    float vb0, vb1;
    if (lane < 32) {
        vb0 = mrow[130 + 2 * lane] / d2;
        vb1 = mrow[131 + 2 * lane] / d2;
    } else {
        const float* nf = nodef + (size_t)n * 64 + 2 * (lane - 32);
        vb0 = nf[0]; vb1 = nf[1];
    }
    temb[(size_t)n * 128 + lane]      = pack2bf(va0, va1);
    temb[(size_t)n * 128 + 64 + lane] = pack2bf(vb0, vb1);
}

// ---------------- A_r pass: rowsum, colsum, bf16 Aexp_rm + AexpT (throughput form) ----------------
__global__ __launch_bounds__(256) void k_aexp(
        const float* __restrict__ A_r,
        float* __restrict__ rowsum, float* __restrict__ colsum,
        unsigned short* __restrict__ AexpT, unsigned short* __restrict__ Aexp_rm, int N) {
    __shared__ unsigned short sE[64][228];   // 456B row stride: 8B-aligned, ~2-way banks
    int t = threadIdx.x;
    int n0 = blockIdx.x * 64;
    int maxq = min(64, N - n0) * 56;
    const float4* src = (const float4*)(A_r + (size_t)n0 * 224);
    #pragma unroll
    for (int k = 0; k < 14; ++k) {
        int i = t + k * 256;
        float4 v = (i < maxq) ? src[i] : (float4){-1e30f, -1e30f, -1e30f, -1e30f};
        int row = i / 56, cq = i % 56;
        uint2 pk;
        pk.x = pack2bf(__expf(v.x), __expf(v.y));
        pk.y = pack2bf(__expf(v.z), __expf(v.w));
        *(uint2*)&sE[row][cq * 4] = pk;
    }
    __syncthreads();
    // rowsum: 4 threads per row, 2 shuffles
    {
        int row = t >> 2, q = t & 3;
        const uint2* p = (const uint2*)&sE[row][q * 56];
        float s = 0.f;
        #pragma unroll
        for (int c = 0; c < 7; ++c) {
            uint2 u = p[c];
            s += __uint_as_float(u.x << 16) + __uint_as_float(u.x & 0xffff0000u)
               + __uint_as_float(u.y << 16) + __uint_as_float(u.y & 0xffff0000u);
        }
        s += __shfl_xor(s, 1, 64);
        s += __shfl_xor(s, 2, 64);
        if (q == 0 && n0 + row < N) rowsum[n0 + row] = s;
    }
    // colsum partials
    if (t < 224) {
        float s = 0.f;
        #pragma unroll 8
        for (int r = 0; r < 64; ++r) s += bf2f(sE[r][t]);
        atomicAdd(colsum + t, s);
    }
    // row-major write, packed uints, coalesced
    {
        unsigned int* dst = (unsigned int*)Aexp_rm;
        for (int i = t; i < 64 * 112; i += 256) {
            int n = i / 112, cp = i % 112;
            dst[(size_t)(n0 + n) * 112 + cp] = *(const unsigned int*)&sE[n][2 * cp];
        }
    }
    // transposed write: wave-coalesced 128B runs per r-row
    {
        unsigned int* dst = (unsigned int*)AexpT;
        for (int u = t; u < 224 * 32; u += 256) {
            int r = u >> 5, np = u & 31;
            unsigned int lo = sE[2 * np][r];
            unsigned int hi = sE[2 * np + 1][r];
            dst[(size_t)r * (SN / 2) + (n0 >> 1) + np] = lo | (hi << 16);
        }
    }
}

// ---------------- per-node aggregation: persistent strided waves ----------------
__global__ __launch_bounds__(256) void k_agg(
        const int* __restrict__ tgt, const float* __restrict__ ts,
        const int* __restrict__ sorted, const int* __restrict__ offsets,
        const float* __restrict__ t_max, const unsigned int* __restrict__ temb,
        const float* __restrict__ lambs,
        unsigned int* __restrict__ aggb, float* __restrict__ cnt3,
        int* __restrict__ has_msg, int N) {
    int gw = blockIdx.x * 4 + (threadIdx.x >> 6);   // global wave id
    int lane = threadIdx.x & 63;
    float lb0 = lambs[0], lb1 = lambs[1], lb2 = lambs[2];
    for (int n = gw; n < SN; n += AGG_WAVES) {
        size_t rb = (size_t)n * 3;
        if (n >= N) {                       // zero-fill padding rows
            #pragma unroll
            for (int l = 0; l < 3; ++l) {
                unsigned int* row = aggb + (rb + l) * 128;
                row[lane] = 0; row[64 + lane] = 0;
                if (lane == 0) cnt3[rb + l] = 0.f;
            }
            continue;
        }
        int beg = offsets[n], end = offsets[n + 1];
        float tm = t_max[n];
        float aa0[3], aa1[3], ab0[3], ab1[3], accc[3];
        #pragma unroll
        for (int l = 0; l < 3; ++l) { aa0[l] = aa1[l] = ab0[l] = ab1[l] = accc[l] = 0.f; }
        for (int idx = beg; idx < end; ++idx) {
            int e = sorted[idx];
            int tt = tgt[e];
            float d = tm - ts[e];
            unsigned int ua = temb[(size_t)tt * 128 + lane];
            unsigned int ub = temb[(size_t)tt * 128 + 64 + lane];
            float a0 = __uint_as_float(ua << 16);
            float a1 = __uint_as_float(ua & 0xffff0000u);
            float b0 = __uint_as_float(ub << 16);
            float b1 = __uint_as_float(ub & 0xffff0000u);
            float w0 = __expf(-lb0 * d), w1 = __expf(-lb1 * d), w2 = __expf(-lb2 * d);
            aa0[0] += w0 * a0; aa1[0] += w0 * a1; ab0[0] += w0 * b0; ab1[0] += w0 * b1; accc[0] += w0;
            aa0[1] += w1 * a0; aa1[1] += w1 * a1; ab0[1] += w1 * b0; ab1[1] += w1 * b1; accc[1] += w1;
            aa0[2] += w2 * a0; aa1[2] += w2 * a1; ab0[2] += w2 * b0; ab1[2] += w2 * b1; accc[2] += w2;
        }
        #pragma unroll
        for (int l = 0; l < 3; ++l) {
            unsigned int* row = aggb + (rb + l) * 128;
            row[lane]      = pack2bf(aa0[l], aa1[l]);
            row[64 + lane] = pack2bf(ab0[l], ab1[l]);
            if (lane == 0) cnt3[rb + l] = accc[l];
        }
        if (lane == 0) has_msg[n] = (end > beg) ? 1 : 0;
    }
}

// ---------------- mf MLP via MFMA: 64 rows/block, LDS-staged, VGPR budget for 3 w/SIMD ----------------
__global__ __launch_bounds__(256, 3) void k_mf_mfma(
        const unsigned short* __restrict__ aggb,
        const unsigned short* __restrict__ W1T, const float* __restrict__ b1,
        const unsigned short* __restrict__ W2T, const float* __restrict__ b2,
        unsigned short* __restrict__ msg_feat, int NROWS) {
    __shared__ unsigned short As[64 * 264];
    __shared__ unsigned short Hs[64 * 136];
    int t = threadIdx.x, lane = t & 63, w = t >> 6;
    int lr = lane & 15, kg = lane >> 4;
    int row0 = blockIdx.x * 64;
    {   // stage A: 64 rows x 256 bf16, 4 threads/row
        int r = t >> 2, s4 = t & 3;
        const uint4* src = (const uint4*)(aggb + (size_t)(row0 + r) * 256 + s4 * 64);
        uint4* dst = (uint4*)(As + r * 264 + s4 * 64);
        #pragma unroll
        for (int u = 0; u < 8; ++u) dst[u] = src[u];
    }
    __syncthreads();
    // layer 1: wave w -> cols [w*32, w*32+32)
    int n0 = w * 32;
    f32x4 acc[4][2];
    #pragma unroll
    for (int m = 0; m < 4; ++m) {
        acc[m][0] = (f32x4){0.f, 0.f, 0.f, 0.f};
        acc[m][1] = (f32x4){0.f, 0.f, 0.f, 0.f};
    }
    #pragma unroll
    for (int kk = 0; kk < 8; ++kk) {
        short8 bf0 = *(const short8*)(W1T + (size_t)(n0 + lr) * 256 + kk * 32 + kg * 8);
        short8 bf1 = *(const short8*)(W1T + (size_t)(n0 + 16 + lr) * 256 + kk * 32 + kg * 8);
        #pragma unroll
        for (int m = 0; m < 4; ++m) {
            short8 af = *(const short8*)(As + (m * 16 + lr) * 264 + kk * 32 + kg * 8);
            acc[m][0] = __builtin_amdgcn_mfma_f32_16x16x32_bf16(af, bf0, acc[m][0], 0, 0, 0);
            acc[m][1] = __builtin_amdgcn_mfma_f32_16x16x32_bf16(af, bf1, acc[m][1], 0, 0, 0);
        }
    }
    float bb0 = b1[n0 + lr], bb1 = b1[n0 + 16 + lr];
    #pragma unroll
    for (int m = 0; m < 4; ++m)
        #pragma unroll
        for (int j = 0; j < 4; ++j) {
            int row = m * 16 + kg * 4 + j;
            Hs[row * 136 + n0 + lr]      = f2bf(fmaxf(acc[m][0][j] + bb0, 0.f));
            Hs[row * 136 + n0 + 16 + lr] = f2bf(fmaxf(acc[m][1][j] + bb1, 0.f));
        }
    __syncthreads();
    // layer 2: wave w -> cols [w*16, w*16+16)
    int c0 = w * 16;
    f32x4 a2[4];
    #pragma unroll
    for (int m = 0; m < 4; ++m) a2[m] = (f32x4){0.f, 0.f, 0.f, 0.f};
    #pragma unroll
    for (int kk = 0; kk < 4; ++kk) {
        short8 bf = *(const short8*)(W2T + (size_t)(c0 + lr) * 128 + kk * 32 + kg * 8);
        #pragma unroll
        for (int m = 0; m < 4; ++m) {
            short8 af = *(const short8*)(Hs + (m * 16 + lr) * 136 + kk * 32 + kg * 8);
            a2[m] = __builtin_amdgcn_mfma_f32_16x16x32_bf16(af, bf, a2[m], 0, 0, 0);
        }
    }
    float b2v = b2[c0 + lr];
    #pragma unroll
    for (int m = 0; m < 4; ++m)
        #pragma unroll
        for (int j = 0; j < 4; ++j) {
            int row = row0 + m * 16 + kg * 4 + j;
            if (row < NROWS)
                msg_feat[(size_t)row * 64 + c0 + lr] = f2bf(fmaxf(a2[m][j] + b2v, 0.f));
        }
}

// ---------------- vmid via bf16 MFMA, split-K; XCD-swizzled, B LDS-staged ----------------
__global__ __launch_bounds__(256, 4) void k_vmid_mfma(
        const unsigned short* __restrict__ AexpT, const unsigned short* __restrict__ aggb,
        const float* __restrict__ cnt3, float* __restrict__ vpart) {
    __shared__ unsigned short As[112 * 40];   // 112 rows x 32 shorts (stride 40 = 80B)
    __shared__ unsigned int BsT[128 * 20];    // [col][np-uint] stride 20; np ^= ((col>>3)&3)<<2
    // bijective XCD swizzle: co-locate the 12 tiles of each chunk on one XCD
    int bx = blockIdx.x;
    int xcd = bx & 7, bidx = bx >> 3;
    int virt = (xcd < NR_V) ? xcd * (NQ_V + 1) + bidx
                            : NR_V * (NQ_V + 1) + (xcd - NR_V) * NQ_V + bidx;
    int chunk = virt / 12, tile = virt % 12;
    int r0 = (tile & 1) * 112;
    int ft = tile >> 1;                 // 0..5
    int l = ft >> 1, fo = (ft & 1) * 128;
    int t = threadIdx.x, lane = t & 63, w = t >> 6;
    int lr = lane & 15, kg = lane >> 4;
    int np = t >> 4, sg = t & 15;       // B staging: node-pair, col-segment(8 cols)
    f32x4 acc[7][2];
    #pragma unroll
    for (int q = 0; q < 7; ++q) {
        acc[q][0] = (f32x4){0.f, 0.f, 0.f, 0.f};
        acc[q][1] = (f32x4){0.f, 0.f, 0.f, 0.f};
    }
    int nbeg = chunk * KLV;
    int nsteps = min(KLV, SN - nbeg) >> 5;
    int c0 = w * 32 + lr, c1 = c0 + 16;
    int rb0 = c0 * 20 + (kg ^ ((c0 >> 3) & 3)) * 4;
    int rb1 = c1 * 20 + (kg ^ ((c1 >> 3) & 3)) * 4;
    int swz = np ^ ((sg & 3) << 2);
    for (int s = 0; s < nsteps; ++s) {
        int n0 = nbeg + s * 32;
        if (t < 224) {                   // stage A: 2 threads/row, 32 shorts/row
            int srow = t >> 1, sseg = t & 1;
            const uint4* ap = (const uint4*)(AexpT + (size_t)(r0 + srow) * SN + n0) + sseg * 2;
            uint4 v0 = ap[0];
            uint4 v1 = ap[1];
            *(uint4*)&As[srow * 40 + sseg * 16]     = v0;
            *(uint4*)&As[srow * 40 + sseg * 16 + 8] = v1;
        }
        {   // stage B: nodes (2np, 2np+1) x cols [sg*8, sg*8+8), scaled by 1/den, k-pair packed
            int na = n0 + 2 * np;
            size_t ra = ((size_t)na * 3 + l) * 256 + fo + sg * 8;
            uint4 va = *(const uint4*)(aggb + ra);
            uint4 vb = *(const uint4*)(aggb + ra + 768);
            float da = 1.f / fmaxf(cnt3[(size_t)na * 3 + l], 1e-6f);
            float db = 1.f / fmaxf(cnt3[(size_t)na * 3 + l + 3], 1e-6f);
            const unsigned short* pa = (const unsigned short*)&va;
            const unsigned short* pb = (const unsigned short*)&vb;
            unsigned int* dst = BsT + sg * 160 + swz;
            #pragma unroll
            for (int j = 0; j < 8; ++j)
                dst[j * 20] = pack2bf(bf2f(pa[j]) * da, bf2f(pb[j]) * db);
        }
        __syncthreads();
        short8 b0 = *(const short8*)((const unsigned short*)(BsT + rb0));
        short8 b1 = *(const short8*)((const unsigned short*)(BsT + rb1));
        #pragma unroll
        for (int q = 0; q < 7; ++q) {
            short8 af = *(const short8*)&As[(q * 16 + lr) * 40 + kg * 8];
            acc[q][0] = __builtin_amdgcn_mfma_f32_16x16x32_bf16(af, b0, acc[q][0], 0, 0, 0);
            acc[q][1] = __builtin_amdgcn_mfma_f32_16x16x32_bf16(af, b1, acc[q][1], 0, 0, 0);
        }
        __syncthreads();
    }
    float* outp = vpart + (size_t)chunk * 172032;
    #pragma unroll
    for (int q = 0; q < 7; ++q) {
        int row = r0 + q * 16 + kg * 4;
        #pragma unroll
        for (int p = 0; p < 2; ++p) {
            int col = l * 256 + fo + w * 32 + p * 16 + lr;
            #pragma unroll
            for (int j = 0; j < 4; ++j)
                outp[(size_t)(row + j) * 768 + col] = acc[q][p][j];
        }
    }
}

// ---------------- reduce vpart over chunks, divide by colsum ----------------
__global__ void k_vred(const float* __restrict__ vpart, const float* __restrict__ colsum,
                       float* __restrict__ vmid) {
    int idx = blockIdx.x * 256 + threadIdx.x;
    if (idx >= 224 * 768) return;
    float s = 0.f;
    for (int c = 0; c < VCM; ++c) s += vpart[(long)c * (224 * 768) + idx];
    vmid[idx] = s / colsum[idx / 768];
}

// ---------------- ffr MLP (672 rows) + virtual-memory decay -> vembT (bf16) ----------------
__global__ __launch_bounds__(256) void k_ffr(
        const float* __restrict__ vmid, const float* __restrict__ W1, const float* __restrict__ b1,
        const float* __restrict__ W2, const float* __restrict__ b2,
        const float* __restrict__ vmem, const float* __restrict__ vlast,
        const float* __restrict__ lambs, const float* __restrict__ now_time,
        unsigned short* __restrict__ vembT) {
    __shared__ float sin_[16][260];
    __shared__ float svh[16][260];
    int row0 = blockIdx.x * 16;
    int t = threadIdx.x;
    #pragma unroll
    for (int k = 0; k < 16; ++k) {
        int idx = t + k * 256;
        int r = idx >> 8, f = idx & 255;
        sin_[r][f] = vmid[(long)(row0 + r) * 256 + f];
    }
    __syncthreads();
    {   // layer 1: 16 x 256, 4r x 4c
        int cg = t & 63, rg = t >> 6;
        int c0 = cg * 4, r0 = rg * 4;
        float acc[4][4];
        #pragma unroll
        for (int i = 0; i < 4; ++i)
            #pragma unroll
            for (int j = 0; j < 4; ++j) acc[i][j] = 0.f;
        for (int f0 = 0; f0 < 256; f0 += 4) {
            float4 a[4];
            #pragma unroll
            for (int i = 0; i < 4; ++i) a[i] = *(const float4*)&sin_[r0 + i][f0];
            #pragma unroll
            for (int ff = 0; ff < 4; ++ff) {
                float4 w = *(const float4*)&W1[(long)(f0 + ff) * 256 + c0];
                #pragma unroll
                for (int i = 0; i < 4; ++i) {
                    float av = (&a[i].x)[ff];
                    acc[i][0] += av * w.x; acc[i][1] += av * w.y;
                    acc[i][2] += av * w.z; acc[i][3] += av * w.w;
                }
            }
        }
        #pragma unroll
        for (int i = 0; i < 4; ++i)
            #pragma unroll
            for (int j = 0; j < 4; ++j)
                svh[r0 + i][c0 + j] = lky(acc[i][j] + b1[c0 + j]);
    }
    __syncthreads();
    {   // layer 2: 16 x 64, 2r x 2c + decay epilogue
        int cg = t & 31, rg = t >> 5;
        int c0 = cg * 2, r0 = rg * 2;
        float acc[2][2];
        acc[0][0] = acc[0][1] = acc[1][0] = acc[1][1] = 0.f;
        for (int f0 = 0; f0 < 256; f0 += 4) {
            float4 a[2];
            #pragma unroll
            for (int i = 0; i < 2; ++i) a[i] = *(const float4*)&svh[r0 + i][f0];
            #pragma unroll
            for (int ff = 0; ff < 4; ++ff) {
                float2 w = *(const float2*)&W2[(long)(f0 + ff) * 64 + c0];
                #pragma unroll
                for (int i = 0; i < 2; ++i) {
                    float av = (&a[i].x)[ff];
                    acc[i][0] += av * w.x; acc[i][1] += av * w.y;
                }
            }
        }
        float nowv = now_time[0];
        #pragma unroll
        for (int i = 0; i < 2; ++i) {
            int row = row0 + r0 + i;           // row = rr*3 + l
            int rr = row / 3, l = row % 3;
            float vd = __expf(-lambs[l] * (nowv - vlast[rr]));
            #pragma unroll
            for (int j = 0; j < 2; ++j) {
                float v = lky(acc[i][j] + b2[c0 + j]);
                int m = c0 + j;
                vembT[(size_t)(l * 64 + m) * 224 + rr] =
                    f2bf(vmem[(long)rr * 192 + l * 64 + m] * vd + v);
            }
        }
    }
}

// ---------------- new_mem -> node_emb (bf16) ----------------
__global__ void k_newmem(const float* __restrict__ memory,
        const unsigned short* __restrict__ msg_feat,
        const float* __restrict__ cnt3, const float* __restrict__ t_max,
        const float* __restrict__ last_update, const int* __restrict__ has_msg,
        const float* __restrict__ lambs, unsigned short* __restrict__ node_emb, int N) {
    int n = blockIdx.x;
    int j = threadIdx.x;                 // 0..191
    int l = j >> 6, m = j & 63;
    int has = has_msg[n];
    float dt = has ? (t_max[n] - last_update[n]) : 0.f;
    float decay = __expf(-lambs[l] * dt);
    long mb = (long)n * 195 + l * 65;
    float num = memory[mb + m];
    float den = memory[mb + 64];
    if (has) {
        num = num * decay + bf2f(msg_feat[(size_t)n * 192 + j]);
        den = den * decay + cnt3[(size_t)n * 3 + l];
    }
    node_emb[(size_t)n * 192 + j] = f2bf(num / fmaxf(den, 1e-6f));
}

// ---------------- vnode_emb = row-softmax(A_r) @ v_emb via MFMA (LDS-staged A) ----------------
__global__ __launch_bounds__(256, 4) void k_vnode_mfma(
        const unsigned short* __restrict__ Aexp_rm, const unsigned short* __restrict__ vembT,
        const float* __restrict__ rowsum, unsigned short* __restrict__ vnode_emb, int N) {
    __shared__ unsigned short As[64 * 232];
    __shared__ float sRS[64];
    int t = threadIdx.x, lane = t & 63, w = t >> 6;
    int lr = lane & 15, kg = lane >> 4;
    int row0 = blockIdx.x * 64;
    {
        int r = t >> 2, sg = t & 3;
        const uint4* src = (const uint4*)(Aexp_rm + (size_t)(row0 + r) * 224 + sg * 56);
        uint4* dst = (uint4*)(As + r * 232 + sg * 56);
        #pragma unroll
        for (int u = 0; u < 7; ++u) dst[u] = src[u];
    }
    if (t < 64) sRS[t] = rowsum[min(row0 + t, N - 1)];
    __syncthreads();
    int n0 = w * 48;                      // 192 cols / 4 waves
    f32x4 acc[4][3];
    #pragma unroll
    for (int m = 0; m < 4; ++m)
        #pragma unroll
        for (int nt = 0; nt < 3; ++nt) acc[m][nt] = (f32x4){0.f, 0.f, 0.f, 0.f};
    #pragma unroll
    for (int kk = 0; kk < 7; ++kk) {
        short8 bf[3];
        #pragma unroll
        for (int nt = 0; nt < 3; ++nt)
            bf[nt] = *(const short8*)(vembT + (size_t)(n0 + nt * 16 + lr) * 224 + kk * 32 + kg * 8);
        #pragma unroll
        for (int m = 0; m < 4; ++m) {
            short8 af = *(const short8*)(As + (m * 16 + lr) * 232 + kk * 32 + kg * 8);
            #pragma unroll
            for (int nt = 0; nt < 3; ++nt)
                acc[m][nt] = __builtin_amdgcn_mfma_f32_16x16x32_bf16(af, bf[nt], acc[m][nt], 0, 0, 0);
        }
    }
    #pragma unroll
    for (int m = 0; m < 4; ++m)
        #pragma unroll
        for (int j = 0; j < 4; ++j) {
            int row = row0 + m * 16 + kg * 4 + j;
            if (row < N) {
                float inv = 1.f / sRS[row - row0];
                #pragma unroll
                for (int nt = 0; nt < 3; ++nt)
                    vnode_emb[(size_t)row * 192 + n0 + nt * 16 + lr] = f2bf(acc[m][nt][j] * inv);
            }
        }
}

// ---------------- et + st + output blend via MFMA: 32 rows/block, LDS-staged ----------------
__global__ __launch_bounds__(256, 4) void k_et_st_mfma(
        const unsigned short* __restrict__ ne, const unsigned short* __restrict__ ve,
        const unsigned short* __restrict__ etWT, const float* __restrict__ etb,
        const unsigned short* __restrict__ stWT, const float* __restrict__ stb,
        const float* __restrict__ stat, const float* __restrict__ lamb,
        float* __restrict__ out, int N) {
    __shared__ unsigned short As[64 * 200];    // rows 0-31: node, 32-63: vnode
    __shared__ unsigned short Hs[32 * 136];    // st input [32 rows][128 cols]
    int t = threadIdx.x, lane = t & 63, w = t >> 6;
    int lr = lane & 15, kg = lane >> 4;
    int row0 = blockIdx.x * 32;
    {
        int r = t >> 3, s8 = t & 7;            // 8 threads/row, 48B each
        const uint4* sn = (const uint4*)(ne + (size_t)(row0 + r) * 192 + s8 * 24);
        const uint4* sv = (const uint4*)(ve + (size_t)(row0 + r) * 192 + s8 * 24);
        uint4* dn = (uint4*)(As + (size_t)r * 200 + s8 * 24);
        uint4* dv = (uint4*)(As + (size_t)(32 + r) * 200 + s8 * 24);
        #pragma unroll
        for (int u = 0; u < 3; ++u) { dn[u] = sn[u]; dv[u] = sv[u]; }
    }
    __syncthreads();
    // et layer: wave w -> cols [w*16, w*16+16), both halves; K=192
    int c0 = w * 16;
    f32x4 acc[2][2];
    #pragma unroll
    for (int h = 0; h < 2; ++h)
        #pragma unroll
        for (int m = 0; m < 2; ++m) acc[h][m] = (f32x4){0.f, 0.f, 0.f, 0.f};
    #pragma unroll
    for (int kk = 0; kk < 6; ++kk) {
        short8 bf = *(const short8*)(etWT + (size_t)(c0 + lr) * 192 + kk * 32 + kg * 8);
        #pragma unroll
        for (int h = 0; h < 2; ++h)
            #pragma unroll
            for (int m = 0; m < 2; ++m) {
                short8 af = *(const short8*)(As + (size_t)(h * 32 + m * 16 + lr) * 200 + kk * 32 + kg * 8);
                acc[h][m] = __builtin_amdgcn_mfma_f32_16x16x32_bf16(af, bf, acc[h][m], 0, 0, 0);
            }
    }
    float bb = etb[c0 + lr];
    #pragma unroll
    for (int h = 0; h < 2; ++h)
        #pragma unroll
        for (int m = 0; m < 2; ++m)
            #pragma unroll
            for (int j = 0; j < 4; ++j)
                Hs[(m * 16 + kg * 4 + j) * 136 + h * 64 + c0 + lr] = f2bf(lky(acc[h][m][j] + bb));
    __syncthreads();
    // st layer: wave w -> cols [w*32, w*32+32); K=128
    int c0s = w * 32;
    f32x4 a2[2][2];
    #pragma unroll
    for (int m = 0; m < 2; ++m) { a2[m][0] = (f32x4){0.f,0.f,0.f,0.f}; a2[m][1] = (f32x4){0.f,0.f,0.f,0.f}; }
    #pragma unroll
    for (int kk = 0; kk < 4; ++kk) {
        short8 bf0 = *(const short8*)(stWT + (size_t)(c0s + lr) * 128 + kk * 32 + kg * 8);
        short8 bf1 = *(const short8*)(stWT + (size_t)(c0s + 16 + lr) * 128 + kk * 32 + kg * 8);
        #pragma unroll
        for (int m = 0; m < 2; ++m) {
            short8 af = *(const short8*)(Hs + (m * 16 + lr) * 136 + kk * 32 + kg * 8);
            a2[m][0] = __builtin_amdgcn_mfma_f32_16x16x32_bf16(af, bf0, a2[m][0], 0, 0, 0);
            a2[m][1] = __builtin_amdgcn_mfma_f32_16x16x32_bf16(af, bf1, a2[m][1], 0, 0, 0);
        }
    }
    float lam = lamb[0];
    float sb0 = stb[c0s + lr], sb1 = stb[c0s + 16 + lr];
    #pragma unroll
    for (int m = 0; m < 2; ++m)
        #pragma unroll
        for (int j = 0; j < 4; ++j) {
            int n = row0 + m * 16 + kg * 4 + j;
            if (n < N) {
                int ca = c0s + lr, cb = c0s + 16 + lr;
                float va = lky(a2[m][0][j] + sb0);
                float vb = lky(a2[m][1][j] + sb1);
                out[(size_t)n * 128 + ca] = lam * stat[(size_t)n * 128 + ca] + (1.f - lam) * va;
                out[(size_t)n * 128 + cb] = lam * stat[(size_t)n * 128 + cb] + (1.f - lam) * vb;
            }
        }
}

extern "C" void kernel_launch(void* const* d_in, const int* in_sizes, int n_in,
                              void* d_out, int out_size, void* d_ws, size_t ws_size,
                              hipStream_t stream) {
    const int*   src        = (const int*)d_in[0];
    const int*   tgt        = (const int*)d_in[1];
    const float* ts         = (const float*)d_in[2];
    const float* now_time   = (const float*)d_in[3];
    const float* nodef      = (const float*)d_in[5];
    const float* memory     = (const float*)d_in[6];
    const float* last_upd   = (const float*)d_in[7];
    const float* vmem       = (const float*)d_in[8];
    const float* vlast      = (const float*)d_in[9];
    const float* A_r        = (const float*)d_in[10];
    const float* static_emb = (const float*)d_in[11];
    const float* lamb       = (const float*)d_in[12];
    const float* lambs      = (const float*)d_in[13];
    const float* mf_W1      = (const float*)d_in[14];
    const float* mf_b1      = (const float*)d_in[15];
    const float* mf_W2      = (const float*)d_in[16];
    const float* mf_b2      = (const float*)d_in[17];
    const float* ffr_W1     = (const float*)d_in[18];
    const float* ffr_b1     = (const float*)d_in[19];
    const float* ffr_W2     = (const float*)d_in[20];
    const float* ffr_b2     = (const float*)d_in[21];
    const float* et_W       = (const float*)d_in[22];
    const float* et_b       = (const float*)d_in[23];
    const float* st_W       = (const float*)d_in[24];
    const float* st_b       = (const float*)d_in[25];

    int E = in_sizes[0];
    int N = in_sizes[7];

    float* ws = (float*)d_ws;
    size_t off = 0;
    auto alloc = [&](size_t nf) { float* p = ws + off; off += (nf + 63) & ~(size_t)63; return p; };
    unsigned short* aggb  = (unsigned short*)alloc((size_t)SN * 384);     // SN*3 rows x 256 bf16
    unsigned short* msg_feat = (unsigned short*)alloc((size_t)N * 96);    // bf16
    unsigned short* AexpT   = (unsigned short*)alloc((size_t)224 * SN / 2);
    unsigned short* Aexp_rm = (unsigned short*)alloc((size_t)SN * 224 / 2);
    float* tv_union = alloc((size_t)VCM * 172032);      // temb (N*128) then vpart (VCM*172032)
    float* vmid     = alloc(224 * 768);
    unsigned short* vembT = (unsigned short*)alloc((size_t)192 * 224 / 2 + 64);
    float* t_max    = alloc(N);
    float* rowsum   = alloc(N);
    float* cnt3     = alloc((size_t)SN * 3);
    float* colsum   = alloc(256);
    unsigned short* W1T  = (unsigned short*)alloc(128 * 256 / 2);
    unsigned short* W2T  = (unsigned short*)alloc(64 * 128 / 2);
    unsigned short* etWT = (unsigned short*)alloc(64 * 192 / 2);
    unsigned short* stWT = (unsigned short*)alloc(128 * 128 / 2);
    int*   cnt      = (int*)alloc(NSCAN);               // padded+zeroed for int4 scan
    int*   offsets  = (int*)alloc(N + 1);
    int*   cursor   = (int*)alloc(N);
    int*   sorted   = (int*)alloc(E);
    int*   has_msg  = (int*)alloc(N);
    if (off * sizeof(float) > ws_size) return;   // workspace guard

    unsigned int* temb = (unsigned int*)tv_union;   // live: k_prep..k_agg
    float* vpart = tv_union;                        // live: k_vmid_mfma..k_vred
    // overlays: aggb region is dead after k_mf_mfma + k_vmid_mfma
    unsigned short* node_emb  = (unsigned short*)aggb;
    unsigned short* vnode_emb = node_emb + (size_t)N * 192;

    k_init<<<(NSCAN + 255) / 256, 256, 0, stream>>>(t_max, cnt, cursor, colsum, N, NSCAN);
    k_tbf<<<(256 * 128 + 255) / 256, 256, 0, stream>>>(mf_W1, W1T, 256, 128);
    k_tbf<<<(128 * 64 + 255) / 256, 256, 0, stream>>>(mf_W2, W2T, 128, 64);
    k_tbf<<<(192 * 64 + 255) / 256, 256, 0, stream>>>(et_W, etWT, 192, 64);
    k_tbf<<<(128 * 128 + 255) / 256, 256, 0, stream>>>(st_W, stWT, 128, 128);
    k_tmax_cnt<<<(E + 255) / 256, 256, 0, stream>>>(src, ts, t_max, cnt, E);
    k_scan<<<1, 1024, 0, stream>>>(cnt, offsets, N);
    k_scatter<<<(E + 255) / 256, 256, 0, stream>>>(src, offsets, cursor, sorted, E);
    k_prep<<<(N + 3) / 4, 256, 0, stream>>>(memory, nodef, temb, N);
    k_aexp<<<SN / 64, 256, 0, stream>>>(A_r, rowsum, colsum, AexpT, Aexp_rm, N);
    k_agg<<<AGG_BLOCKS, 256, 0, stream>>>(tgt, ts, sorted, offsets, t_max, temb,
                                          lambs, (unsigned int*)aggb, cnt3, has_msg, N);
    k_mf_mfma<<<SN * 3 / 64, 256, 0, stream>>>(aggb, W1T, mf_b1, W2T, mf_b2, msg_feat, N * 3);
    k_vmid_mfma<<<NWG_V, 256, 0, stream>>>(AexpT, aggb, cnt3, vpart);
    k_vred<<<(224 * 768 + 255) / 256, 256, 0, stream>>>(vpart, colsum, vmid);
    k_ffr<<<42, 256, 0, stream>>>(vmid, ffr_W1, ffr_b1, ffr_W2, ffr_b2, vmem, vlast,
                                  lambs, now_time, vembT);
    k_newmem<<<N, 192, 0, stream>>>(memory, msg_feat, cnt3, t_max, last_upd, has_msg,
                                    lambs, node_emb, N);
    k_vnode_mfma<<<SN / 64, 256, 0, stream>>>(Aexp_rm, vembT, rowsum, vnode_emb, N);
    k_et_st_mfma<<<SN / 32, 256, 0, stream>>>(node_emb, vnode_emb, etWT, et_b, stWT, st_b,
                                              static_emb, lamb, (float*)d_out, N);
}

// Round 14
// 370.766 us; speedup vs baseline: 1.0497x; 1.0035x over previous
//
#include <hip/hip_runtime.h>

static __device__ __forceinline__ float lky(float x) { return x > 0.f ? x : 0.01f * x; }

static __device__ __forceinline__ unsigned short f2bf(float x) {
    unsigned int u = __float_as_uint(x);
    unsigned int r = (u + 0x7FFFu + ((u >> 16) & 1u)) >> 16;
    return (unsigned short)r;
}
static __device__ __forceinline__ float bf2f(unsigned short x) {
    return __uint_as_float((unsigned int)x << 16);
}
static __device__ __forceinline__ unsigned int pack2bf(float lo, float hi) {
    return (unsigned int)f2bf(lo) | ((unsigned int)f2bf(hi) << 16);
}

typedef __attribute__((ext_vector_type(8))) short short8;
typedef __attribute__((ext_vector_type(4))) float f32x4;

constexpr int SN  = 50048;   // padded node count (multiple of 64)
constexpr int KLV = 608;     // K(nodes) per split-K chunk (multiple of 32)
constexpr int VCM = 83;      // ceil(SN/KLV)
constexpr int NSCAN = 53248; // 13 * 4096, scan padding
constexpr int NWG_V = 12 * VCM;      // 996
constexpr int NQ_V  = NWG_V / 8;     // 124
constexpr int NR_V  = NWG_V % 8;     // 4
constexpr int AGG_BLOCKS = 2048;     // persistent k_agg blocks
constexpr int AGG_WAVES  = AGG_BLOCKS * 4;

// ---------------- init ----------------
__global__ void k_init(float* t_max, int* cnt, int* cursor, float* colsum, int N, int NP) {
    int i = blockIdx.x * 256 + threadIdx.x;
    if (i < N) { t_max[i] = -1.0f; cursor[i] = 0; }
    if (i < NP) cnt[i] = 0;
    if (i < 224) colsum[i] = 0.0f;
}

// ---------------- weight transpose to bf16: dst[c*K+k] = src[k*C+c] ----------------
__global__ void k_tbf(const float* __restrict__ src, unsigned short* __restrict__ dst,
                      int K, int C) {
    int i = blockIdx.x * 256 + threadIdx.x;
    if (i >= K * C) return;
    int c = i / K, k = i % K;
    dst[i] = f2bf(src[k * C + c]);
}

// ---------------- per-edge t_max / counts ----------------
__global__ void k_tmax_cnt(const int* __restrict__ src, const float* __restrict__ ts,
                           float* t_max, int* cnt, int E) {
    int e = blockIdx.x * 256 + threadIdx.x;
    if (e >= E) return;
    int s = src[e];
    atomicMax((int*)(t_max + s), __float_as_int(ts[e]));   // ts >= 0, int-monotone
    atomicAdd(cnt + s, 1);
}

// ---------------- exclusive scan over counts (single block, 4096/iter) ----------------
__global__ __launch_bounds__(1024) void k_scan(const int* __restrict__ cnt,
                                               int* __restrict__ offsets, int N) {
    __shared__ int wsum[16];
    __shared__ int s_run;
    int t = threadIdx.x;
    int lane = t & 63, wid = t >> 6;
    if (t == 0) s_run = 0;
    __syncthreads();
    int nchunk = (N + 4095) >> 12;
    for (int c = 0; c < nchunk; ++c) {
        int i0 = (c << 12) + t * 4;
        int4 v = *(const int4*)(cnt + i0);     // cnt zero-padded to NSCAN
        int s = v.x + v.y + v.z + v.w;
        int x = s;
        #pragma unroll
        for (int d = 1; d < 64; d <<= 1) {
            int y = __shfl_up(x, d, 64);
            if (lane >= d) x += y;
        }
        if (lane == 63) wsum[wid] = x;
        __syncthreads();
        int wbase = 0;
        #pragma unroll
        for (int w = 0; w < 16; ++w) wbase += (w < wid) ? wsum[w] : 0;
        int run = s_run;
        int base = run + wbase + x - s;
        if (i0 + 3 < N) {
            int4 o;
            o.x = base; o.y = base + v.x; o.z = o.y + v.y; o.w = o.z + v.z;
            *(int4*)(offsets + i0) = o;
        } else {
            int o = base;
            if (i0 < N) offsets[i0] = o;
            o += v.x;
            if (i0 + 1 < N) offsets[i0 + 1] = o;
            o += v.y;
            if (i0 + 2 < N) offsets[i0 + 2] = o;
            o += v.z;
            if (i0 + 3 < N) offsets[i0 + 3] = o;
        }
        __syncthreads();
        if (t == 1023) s_run = run + wbase + x;
        __syncthreads();
    }
    if (t == 0) offsets[N] = s_run;
}

// ---------------- scatter edges into per-node buckets ----------------
__global__ void k_scatter(const int* __restrict__ src, const int* __restrict__ offsets,
                          int* cursor, int* sorted, int E) {
    int e = blockIdx.x * 256 + threadIdx.x;
    if (e >= E) return;
    int s = src[e];
    int pos = offsets[s] + atomicAdd(cursor + s, 1);
    sorted[pos] = e;
}

// ---------------- precompute normalized target embedding, bf16 [N][256] ----------------
__global__ __launch_bounds__(256) void k_prep(
        const float* __restrict__ memory, const float* __restrict__ nodef,
        unsigned int* __restrict__ temb, int N) {
    int wid = threadIdx.x >> 6, lane = threadIdx.x & 63;
    int n = blockIdx.x * 4 + wid;
    if (n >= N) return;
    const float* mrow = memory + (size_t)n * 195;
    float d0 = mrow[64], d1 = mrow[129], d2 = mrow[194];
    int f = 2 * lane;
    float den = (f < 64) ? d0 : d1;
    int offA = (f < 64) ? f : f + 1;
    float va0 = mrow[offA] / den;
    float va1 = mrow[offA + 1] / den;
    float vb0, vb1;
    if (lane < 32) {
        vb0 = mrow[130 + 2 * lane] / d2;
        vb1 = mrow[131 + 2 * lane] / d2;
    } else {
        const float* nf = nodef + (size_t)n * 64 + 2 * (lane - 32);
        vb0 = nf[0]; vb1 = nf[1];
    }
    temb[(size_t)n * 128 + lane]      = pack2bf(va0, va1);
    temb[(size_t)n * 128 + 64 + lane] = pack2bf(vb0, vb1);
}

// ---------------- A_r pass: rowsum, colsum, bf16 Aexp_rm + AexpT (throughput form) ----------------
__global__ __launch_bounds__(256) void k_aexp(
        const float* __restrict__ A_r,
        float* __restrict__ rowsum, float* __restrict__ colsum,
        unsigned short* __restrict__ AexpT, unsigned short* __restrict__ Aexp_rm, int N) {
    __shared__ unsigned short sE[64][228];   // 456B row stride: 8B-aligned, ~2-way banks
    int t = threadIdx.x;
    int n0 = blockIdx.x * 64;
    int maxq = min(64, N - n0) * 56;
    const float4* src = (const float4*)(A_r + (size_t)n0 * 224);
    #pragma unroll
    for (int k = 0; k < 14; ++k) {
        int i = t + k * 256;
        float4 v = (i < maxq) ? src[i] : (float4){-1e30f, -1e30f, -1e30f, -1e30f};
        int row = i / 56, cq = i % 56;
        uint2 pk;
        pk.x = pack2bf(__expf(v.x), __expf(v.y));
        pk.y = pack2bf(__expf(v.z), __expf(v.w));
        *(uint2*)&sE[row][cq * 4] = pk;
    }
    __syncthreads();
    // rowsum: 4 threads per row, 2 shuffles
    {
        int row = t >> 2, q = t & 3;
        const uint2* p = (const uint2*)&sE[row][q * 56];
        float s = 0.f;
        #pragma unroll
        for (int c = 0; c < 7; ++c) {
            uint2 u = p[c];
            s += __uint_as_float(u.x << 16) + __uint_as_float(u.x & 0xffff0000u)
               + __uint_as_float(u.y << 16) + __uint_as_float(u.y & 0xffff0000u);
        }
        s += __shfl_xor(s, 1, 64);
        s += __shfl_xor(s, 2, 64);
        if (q == 0 && n0 + row < N) rowsum[n0 + row] = s;
    }
    // colsum partials
    if (t < 224) {
        float s = 0.f;
        #pragma unroll 8
        for (int r = 0; r < 64; ++r) s += bf2f(sE[r][t]);
        atomicAdd(colsum + t, s);
    }
    // row-major write, packed uints, coalesced
    {
        unsigned int* dst = (unsigned int*)Aexp_rm;
        for (int i = t; i < 64 * 112; i += 256) {
            int n = i / 112, cp = i % 112;
            dst[(size_t)(n0 + n) * 112 + cp] = *(const unsigned int*)&sE[n][2 * cp];
        }
    }
    // transposed write: wave-coalesced 128B runs per r-row
    {
        unsigned int* dst = (unsigned int*)AexpT;
        for (int u = t; u < 224 * 32; u += 256) {
            int r = u >> 5, np = u & 31;
            unsigned int lo = sE[2 * np][r];
            unsigned int hi = sE[2 * np + 1][r];
            dst[(size_t)r * (SN / 2) + (n0 >> 1) + np] = lo | (hi << 16);
        }
    }
}

// ---------------- per-node aggregation: persistent strided waves ----------------
__global__ __launch_bounds__(256) void k_agg(
        const int* __restrict__ tgt, const float* __restrict__ ts,
        const int* __restrict__ sorted, const int* __restrict__ offsets,
        const float* __restrict__ t_max, const unsigned int* __restrict__ temb,
        const float* __restrict__ lambs,
        unsigned int* __restrict__ aggb, float* __restrict__ cnt3,
        int* __restrict__ has_msg, int N) {
    int gw = blockIdx.x * 4 + (threadIdx.x >> 6);   // global wave id
    int lane = threadIdx.x & 63;
    float lb0 = lambs[0], lb1 = lambs[1], lb2 = lambs[2];
    for (int n = gw; n < SN; n += AGG_WAVES) {
        size_t rb = (size_t)n * 3;
        if (n >= N) {                       // zero-fill padding rows
            #pragma unroll
            for (int l = 0; l < 3; ++l) {
                unsigned int* row = aggb + (rb + l) * 128;
                row[lane] = 0; row[64 + lane] = 0;
                if (lane == 0) cnt3[rb + l] = 0.f;
            }
            continue;
        }
        int beg = offsets[n], end = offsets[n + 1];
        float tm = t_max[n];
        float aa0[3], aa1[3], ab0[3], ab1[3], accc[3];
        #pragma unroll
        for (int l = 0; l < 3; ++l) { aa0[l] = aa1[l] = ab0[l] = ab1[l] = accc[l] = 0.f; }
        for (int idx = beg; idx < end; ++idx) {
            int e = sorted[idx];
            int tt = tgt[e];
            float d = tm - ts[e];
            unsigned int ua = temb[(size_t)tt * 128 + lane];
            unsigned int ub = temb[(size_t)tt * 128 + 64 + lane];
            float a0 = __uint_as_float(ua << 16);
            float a1 = __uint_as_float(ua & 0xffff0000u);
            float b0 = __uint_as_float(ub << 16);
            float b1 = __uint_as_float(ub & 0xffff0000u);
            float w0 = __expf(-lb0 * d), w1 = __expf(-lb1 * d), w2 = __expf(-lb2 * d);
            aa0[0] += w0 * a0; aa1[0] += w0 * a1; ab0[0] += w0 * b0; ab1[0] += w0 * b1; accc[0] += w0;
            aa0[1] += w1 * a0; aa1[1] += w1 * a1; ab0[1] += w1 * b0; ab1[1] += w1 * b1; accc[1] += w1;
            aa0[2] += w2 * a0; aa1[2] += w2 * a1; ab0[2] += w2 * b0; ab1[2] += w2 * b1; accc[2] += w2;
        }
        #pragma unroll
        for (int l = 0; l < 3; ++l) {
            unsigned int* row = aggb + (rb + l) * 128;
            row[lane]      = pack2bf(aa0[l], aa1[l]);
            row[64 + lane] = pack2bf(ab0[l], ab1[l]);
            if (lane == 0) cnt3[rb + l] = accc[l];
        }
        if (lane == 0) has_msg[n] = (end > beg) ? 1 : 0;
    }
}

// ---------------- mf MLP via MFMA: 512 threads (8 waves), 64 rows/block, W-prefetch ----------------
__global__ __launch_bounds__(512, 3) void k_mf_mfma(
        const unsigned short* __restrict__ aggb,
        const unsigned short* __restrict__ W1T, const float* __restrict__ b1,
        const unsigned short* __restrict__ W2T, const float* __restrict__ b2,
        unsigned short* __restrict__ msg_feat, int NROWS) {
    __shared__ unsigned short As[64 * 264];
    __shared__ unsigned short Hs[64 * 136];
    int t = threadIdx.x, lane = t & 63, w = t >> 6;   // w in 0..7
    int lr = lane & 15, kg = lane >> 4;
    int row0 = blockIdx.x * 64;
    {   // stage A: 64 rows x 256 bf16, 8 threads/row (32 shorts each)
        int r = t >> 3, s8 = t & 7;
        const uint4* src = (const uint4*)(aggb + (size_t)(row0 + r) * 256 + s8 * 32);
        uint4* dst = (uint4*)(As + r * 264 + s8 * 32);
        #pragma unroll
        for (int u = 0; u < 4; ++u) dst[u] = src[u];
    }
    __syncthreads();
    // layer 1: wave w -> cols [w*16, w*16+16); 64 rows
    int n0 = w * 16;
    f32x4 acc[4];
    #pragma unroll
    for (int m = 0; m < 4; ++m) acc[m] = (f32x4){0.f, 0.f, 0.f, 0.f};
    short8 bfc = *(const short8*)(W1T + (size_t)(n0 + lr) * 256 + kg * 8);
    #pragma unroll
    for (int kk = 0; kk < 8; ++kk) {
        short8 bfn;
        if (kk < 7)
            bfn = *(const short8*)(W1T + (size_t)(n0 + lr) * 256 + (kk + 1) * 32 + kg * 8);
        #pragma unroll
        for (int m = 0; m < 4; ++m) {
            short8 af = *(const short8*)(As + (m * 16 + lr) * 264 + kk * 32 + kg * 8);
            acc[m] = __builtin_amdgcn_mfma_f32_16x16x32_bf16(af, bfc, acc[m], 0, 0, 0);
        }
        bfc = bfn;
    }
    float bb0 = b1[n0 + lr];
    #pragma unroll
    for (int m = 0; m < 4; ++m)
        #pragma unroll
        for (int j = 0; j < 4; ++j) {
            int row = m * 16 + kg * 4 + j;
            Hs[row * 136 + n0 + lr] = f2bf(fmaxf(acc[m][j] + bb0, 0.f));
        }
    __syncthreads();
    // layer 2: wave w -> rows [(w>>2)*32, +32), cols [(w&3)*16, +16); K=128
    int rh = (w >> 2) * 32;
    int c0 = (w & 3) * 16;
    f32x4 a2[2];
    a2[0] = (f32x4){0.f, 0.f, 0.f, 0.f};
    a2[1] = (f32x4){0.f, 0.f, 0.f, 0.f};
    short8 b2c = *(const short8*)(W2T + (size_t)(c0 + lr) * 128 + kg * 8);
    #pragma unroll
    for (int kk = 0; kk < 4; ++kk) {
        short8 b2n;
        if (kk < 3)
            b2n = *(const short8*)(W2T + (size_t)(c0 + lr) * 128 + (kk + 1) * 32 + kg * 8);
        #pragma unroll
        for (int m = 0; m < 2; ++m) {
            short8 af = *(const short8*)(Hs + (rh + m * 16 + lr) * 136 + kk * 32 + kg * 8);
            a2[m] = __builtin_amdgcn_mfma_f32_16x16x32_bf16(af, b2c, a2[m], 0, 0, 0);
        }
        b2c = b2n;
    }
    float b2v = b2[c0 + lr];
    #pragma unroll
    for (int m = 0; m < 2; ++m)
        #pragma unroll
        for (int j = 0; j < 4; ++j) {
            int row = row0 + rh + m * 16 + kg * 4 + j;
            if (row < NROWS)
                msg_feat[(size_t)row * 64 + c0 + lr] = f2bf(fmaxf(a2[m][j] + b2v, 0.f));
        }
}

// ---------------- vmid via bf16 MFMA, split-K; XCD-swizzled, B LDS-staged ----------------
__global__ __launch_bounds__(256, 4) void k_vmid_mfma(
        const unsigned short* __restrict__ AexpT, const unsigned short* __restrict__ aggb,
        const float* __restrict__ cnt3, float* __restrict__ vpart) {
    __shared__ unsigned short As[112 * 40];   // 112 rows x 32 shorts (stride 40 = 80B)
    __shared__ unsigned int BsT[128 * 20];    // [col][np-uint] stride 20; np ^= ((col>>3)&3)<<2
    // bijective XCD swizzle: co-locate the 12 tiles of each chunk on one XCD
    int bx = blockIdx.x;
    int xcd = bx & 7, bidx = bx >> 3;
    int virt = (xcd < NR_V) ? xcd * (NQ_V + 1) + bidx
                            : NR_V * (NQ_V + 1) + (xcd - NR_V) * NQ_V + bidx;
    int chunk = virt / 12, tile = virt % 12;
    int r0 = (tile & 1) * 112;
    int ft = tile >> 1;                 // 0..5
    int l = ft >> 1, fo = (ft & 1) * 128;
    int t = threadIdx.x, lane = t & 63, w = t >> 6;
    int lr = lane & 15, kg = lane >> 4;
    int np = t >> 4, sg = t & 15;       // B staging: node-pair, col-segment(8 cols)
    f32x4 acc[7][2];
    #pragma unroll
    for (int q = 0; q < 7; ++q) {
        acc[q][0] = (f32x4){0.f, 0.f, 0.f, 0.f};
        acc[q][1] = (f32x4){0.f, 0.f, 0.f, 0.f};
    }
    int nbeg = chunk * KLV;
    int nsteps = min(KLV, SN - nbeg) >> 5;
    int c0 = w * 32 + lr, c1 = c0 + 16;
    int rb0 = c0 * 20 + (kg ^ ((c0 >> 3) & 3)) * 4;
    int rb1 = c1 * 20 + (kg ^ ((c1 >> 3) & 3)) * 4;
    int swz = np ^ ((sg & 3) << 2);
    for (int s = 0; s < nsteps; ++s) {
        int n0 = nbeg + s * 32;
        if (t < 224) {                   // stage A: 2 threads/row, 32 shorts/row
            int srow = t >> 1, sseg = t & 1;
            const uint4* ap = (const uint4*)(AexpT + (size_t)(r0 + srow) * SN + n0) + sseg * 2;
            uint4 v0 = ap[0];
            uint4 v1 = ap[1];
            *(uint4*)&As[srow * 40 + sseg * 16]     = v0;
            *(uint4*)&As[srow * 40 + sseg * 16 + 8] = v1;
        }
        {   // stage B: nodes (2np, 2np+1) x cols [sg*8, sg*8+8), scaled by 1/den, k-pair packed
            int na = n0 + 2 * np;
            size_t ra = ((size_t)na * 3 + l) * 256 + fo + sg * 8;
            uint4 va = *(const uint4*)(aggb + ra);
            uint4 vb = *(const uint4*)(aggb + ra + 768);
            float da = 1.f / fmaxf(cnt3[(size_t)na * 3 + l], 1e-6f);
            float db = 1.f / fmaxf(cnt3[(size_t)na * 3 + l + 3], 1e-6f);
            const unsigned short* pa = (const unsigned short*)&va;
            const unsigned short* pb = (const unsigned short*)&vb;
            unsigned int* dst = BsT + sg * 160 + swz;
            #pragma unroll
            for (int j = 0; j < 8; ++j)
                dst[j * 20] = pack2bf(bf2f(pa[j]) * da, bf2f(pb[j]) * db);
        }
        __syncthreads();
        short8 b0 = *(const short8*)((const unsigned short*)(BsT + rb0));
        short8 b1 = *(const short8*)((const unsigned short*)(BsT + rb1));
        #pragma unroll
        for (int q = 0; q < 7; ++q) {
            short8 af = *(const short8*)&As[(q * 16 + lr) * 40 + kg * 8];
            acc[q][0] = __builtin_amdgcn_mfma_f32_16x16x32_bf16(af, b0, acc[q][0], 0, 0, 0);
            acc[q][1] = __builtin_amdgcn_mfma_f32_16x16x32_bf16(af, b1, acc[q][1], 0, 0, 0);
        }
        __syncthreads();
    }
    float* outp = vpart + (size_t)chunk * 172032;
    #pragma unroll
    for (int q = 0; q < 7; ++q) {
        int row = r0 + q * 16 + kg * 4;
        #pragma unroll
        for (int p = 0; p < 2; ++p) {
            int col = l * 256 + fo + w * 32 + p * 16 + lr;
            #pragma unroll
            for (int j = 0; j < 4; ++j)
                outp[(size_t)(row + j) * 768 + col] = acc[q][p][j];
        }
    }
}

// ---------------- reduce vpart over chunks, divide by colsum ----------------
__global__ void k_vred(const float* __restrict__ vpart, const float* __restrict__ colsum,
                       float* __restrict__ vmid) {
    int idx = blockIdx.x * 256 + threadIdx.x;
    if (idx >= 224 * 768) return;
    float s = 0.f;
    for (int c = 0; c < VCM; ++c) s += vpart[(long)c * (224 * 768) + idx];
    vmid[idx] = s / colsum[idx / 768];
}

// ---------------- ffr MLP (672 rows) + virtual-memory decay -> vembT (bf16) ----------------
__global__ __launch_bounds__(256) void k_ffr(
        const float* __restrict__ vmid, const float* __restrict__ W1, const float* __restrict__ b1,
        const float* __restrict__ W2, const float* __restrict__ b2,
        const float* __restrict__ vmem, const float* __restrict__ vlast,
        const float* __restrict__ lambs, const float* __restrict__ now_time,
        unsigned short* __restrict__ vembT) {
    __shared__ float sin_[16][260];
    __shared__ float svh[16][260];
    int row0 = blockIdx.x * 16;
    int t = threadIdx.x;
    #pragma unroll
    for (int k = 0; k < 16; ++k) {
        int idx = t + k * 256;
        int r = idx >> 8, f = idx & 255;
        sin_[r][f] = vmid[(long)(row0 + r) * 256 + f];
    }
    __syncthreads();
    {   // layer 1: 16 x 256, 4r x 4c
        int cg = t & 63, rg = t >> 6;
        int c0 = cg * 4, r0 = rg * 4;
        float acc[4][4];
        #pragma unroll
        for (int i = 0; i < 4; ++i)
            #pragma unroll
            for (int j = 0; j < 4; ++j) acc[i][j] = 0.f;
        for (int f0 = 0; f0 < 256; f0 += 4) {
            float4 a[4];
            #pragma unroll
            for (int i = 0; i < 4; ++i) a[i] = *(const float4*)&sin_[r0 + i][f0];
            #pragma unroll
            for (int ff = 0; ff < 4; ++ff) {
                float4 w = *(const float4*)&W1[(long)(f0 + ff) * 256 + c0];
                #pragma unroll
                for (int i = 0; i < 4; ++i) {
                    float av = (&a[i].x)[ff];
                    acc[i][0] += av * w.x; acc[i][1] += av * w.y;
                    acc[i][2] += av * w.z; acc[i][3] += av * w.w;
                }
            }
        }
        #pragma unroll
        for (int i = 0; i < 4; ++i)
            #pragma unroll
            for (int j = 0; j < 4; ++j)
                svh[r0 + i][c0 + j] = lky(acc[i][j] + b1[c0 + j]);
    }
    __syncthreads();
    {   // layer 2: 16 x 64, 2r x 2c + decay epilogue
        int cg = t & 31, rg = t >> 5;
        int c0 = cg * 2, r0 = rg * 2;
        float acc[2][2];
        acc[0][0] = acc[0][1] = acc[1][0] = acc[1][1] = 0.f;
        for (int f0 = 0; f0 < 256; f0 += 4) {
            float4 a[2];
            #pragma unroll
            for (int i = 0; i < 2; ++i) a[i] = *(const float4*)&svh[r0 + i][f0];
            #pragma unroll
            for (int ff = 0; ff < 4; ++ff) {
                float2 w = *(const float2*)&W2[(long)(f0 + ff) * 64 + c0];
                #pragma unroll
                for (int i = 0; i < 2; ++i) {
                    float av = (&a[i].x)[ff];
                    acc[i][0] += av * w.x; acc[i][1] += av * w.y;
                }
            }
        }
        float nowv = now_time[0];
        #pragma unroll
        for (int i = 0; i < 2; ++i) {
            int row = row0 + r0 + i;           // row = rr*3 + l
            int rr = row / 3, l = row % 3;
            float vd = __expf(-lambs[l] * (nowv - vlast[rr]));
            #pragma unroll
            for (int j = 0; j < 2; ++j) {
                float v = lky(acc[i][j] + b2[c0 + j]);
                int m = c0 + j;
                vembT[(size_t)(l * 64 + m) * 224 + rr] =
                    f2bf(vmem[(long)rr * 192 + l * 64 + m] * vd + v);
            }
        }
    }
}

// ---------------- new_mem -> node_emb (bf16) ----------------
__global__ void k_newmem(const float* __restrict__ memory,
        const unsigned short* __restrict__ msg_feat,
        const float* __restrict__ cnt3, const float* __restrict__ t_max,
        const float* __restrict__ last_update, const int* __restrict__ has_msg,
        const float* __restrict__ lambs, unsigned short* __restrict__ node_emb, int N) {
    int n = blockIdx.x;
    int j = threadIdx.x;                 // 0..191
    int l = j >> 6, m = j & 63;
    int has = has_msg[n];
    float dt = has ? (t_max[n] - last_update[n]) : 0.f;
    float decay = __expf(-lambs[l] * dt);
    long mb = (long)n * 195 + l * 65;
    float num = memory[mb + m];
    float den = memory[mb + 64];
    if (has) {
        num = num * decay + bf2f(msg_feat[(size_t)n * 192 + j]);
        den = den * decay + cnt3[(size_t)n * 3 + l];
    }
    node_emb[(size_t)n * 192 + j] = f2bf(num / fmaxf(den, 1e-6f));
}

// ---------------- vnode_emb = row-softmax(A_r) @ v_emb via MFMA (LDS-staged A) ----------------
__global__ __launch_bounds__(256, 4) void k_vnode_mfma(
        const unsigned short* __restrict__ Aexp_rm, const unsigned short* __restrict__ vembT,
        const float* __restrict__ rowsum, unsigned short* __restrict__ vnode_emb, int N) {
    __shared__ unsigned short As[64 * 232];
    __shared__ float sRS[64];
    int t = threadIdx.x, lane = t & 63, w = t >> 6;
    int lr = lane & 15, kg = lane >> 4;
    int row0 = blockIdx.x * 64;
    {
        int r = t >> 2, sg = t & 3;
        const uint4* src = (const uint4*)(Aexp_rm + (size_t)(row0 + r) * 224 + sg * 56);
        uint4* dst = (uint4*)(As + r * 232 + sg * 56);
        #pragma unroll
        for (int u = 0; u < 7; ++u) dst[u] = src[u];
    }
    if (t < 64) sRS[t] = rowsum[min(row0 + t, N - 1)];
    __syncthreads();
    int n0 = w * 48;                      // 192 cols / 4 waves
    f32x4 acc[4][3];
    #pragma unroll
    for (int m = 0; m < 4; ++m)
        #pragma unroll
        for (int nt = 0; nt < 3; ++nt) acc[m][nt] = (f32x4){0.f, 0.f, 0.f, 0.f};
    #pragma unroll
    for (int kk = 0; kk < 7; ++kk) {
        short8 bf[3];
        #pragma unroll
        for (int nt = 0; nt < 3; ++nt)
            bf[nt] = *(const short8*)(vembT + (size_t)(n0 + nt * 16 + lr) * 224 + kk * 32 + kg * 8);
        #pragma unroll
        for (int m = 0; m < 4; ++m) {
            short8 af = *(const short8*)(As + (m * 16 + lr) * 232 + kk * 32 + kg * 8);
            #pragma unroll
            for (int nt = 0; nt < 3; ++nt)
                acc[m][nt] = __builtin_amdgcn_mfma_f32_16x16x32_bf16(af, bf[nt], acc[m][nt], 0, 0, 0);
        }
    }
    #pragma unroll
    for (int m = 0; m < 4; ++m)
        #pragma unroll
        for (int j = 0; j < 4; ++j) {
            int row = row0 + m * 16 + kg * 4 + j;
            if (row < N) {
                float inv = 1.f / sRS[row - row0];
                #pragma unroll
                for (int nt = 0; nt < 3; ++nt)
                    vnode_emb[(size_t)row * 192 + n0 + nt * 16 + lr] = f2bf(acc[m][nt][j] * inv);
            }
        }
}

// ---------------- et + st + output blend via MFMA: 32 rows/block, LDS-staged ----------------
__global__ __launch_bounds__(256, 4) void k_et_st_mfma(
        const unsigned short* __restrict__ ne, const unsigned short* __restrict__ ve,
        const unsigned short* __restrict__ etWT, const float* __restrict__ etb,
        const unsigned short* __restrict__ stWT, const float* __restrict__ stb,
        const float* __restrict__ stat, const float* __restrict__ lamb,
        float* __restrict__ out, int N) {
    __shared__ unsigned short As[64 * 200];    // rows 0-31: node, 32-63: vnode
    __shared__ unsigned short Hs[32 * 136];    // st input [32 rows][128 cols]
    int t = threadIdx.x, lane = t & 63, w = t >> 6;
    int lr = lane & 15, kg = lane >> 4;
    int row0 = blockIdx.x * 32;
    {
        int r = t >> 3, s8 = t & 7;            // 8 threads/row, 48B each
        const uint4* sn = (const uint4*)(ne + (size_t)(row0 + r) * 192 + s8 * 24);
        const uint4* sv = (const uint4*)(ve + (size_t)(row0 + r) * 192 + s8 * 24);
        uint4* dn = (uint4*)(As + (size_t)r * 200 + s8 * 24);
        uint4* dv = (uint4*)(As + (size_t)(32 + r) * 200 + s8 * 24);
        #pragma unroll
        for (int u = 0; u < 3; ++u) { dn[u] = sn[u]; dv[u] = sv[u]; }
    }
    __syncthreads();
    // et layer: wave w -> cols [w*16, w*16+16), both halves; K=192
    int c0 = w * 16;
    f32x4 acc[2][2];
    #pragma unroll
    for (int h = 0; h < 2; ++h)
        #pragma unroll
        for (int m = 0; m < 2; ++m) acc[h][m] = (f32x4){0.f, 0.f, 0.f, 0.f};
    #pragma unroll
    for (int kk = 0; kk < 6; ++kk) {
        short8 bf = *(const short8*)(etWT + (size_t)(c0 + lr) * 192 + kk * 32 + kg * 8);
        #pragma unroll
        for (int h = 0; h < 2; ++h)
            #pragma unroll
            for (int m = 0; m < 2; ++m) {
                short8 af = *(const short8*)(As + (size_t)(h * 32 + m * 16 + lr) * 200 + kk * 32 + kg * 8);
                acc[h][m] = __builtin_amdgcn_mfma_f32_16x16x32_bf16(af, bf, acc[h][m], 0, 0, 0);
            }
    }
    float bb = etb[c0 + lr];
    #pragma unroll
    for (int h = 0; h < 2; ++h)
        #pragma unroll
        for (int m = 0; m < 2; ++m)
            #pragma unroll
            for (int j = 0; j < 4; ++j)
                Hs[(m * 16 + kg * 4 + j) * 136 + h * 64 + c0 + lr] = f2bf(lky(acc[h][m][j] + bb));
    __syncthreads();
    // st layer: wave w -> cols [w*32, w*32+32); K=128
    int c0s = w * 32;
    f32x4 a2[2][2];
    #pragma unroll
    for (int m = 0; m < 2; ++m) { a2[m][0] = (f32x4){0.f,0.f,0.f,0.f}; a2[m][1] = (f32x4){0.f,0.f,0.f,0.f}; }
    #pragma unroll
    for (int kk = 0; kk < 4; ++kk) {
        short8 bf0 = *(const short8*)(stWT + (size_t)(c0s + lr) * 128 + kk * 32 + kg * 8);
        short8 bf1 = *(const short8*)(stWT + (size_t)(c0s + 16 + lr) * 128 + kk * 32 + kg * 8);
        #pragma unroll
        for (int m = 0; m < 2; ++m) {
            short8 af = *(const short8*)(Hs + (m * 16 + lr) * 136 + kk * 32 + kg * 8);
            a2[m][0] = __builtin_amdgcn_mfma_f32_16x16x32_bf16(af, bf0, a2[m][0], 0, 0, 0);
            a2[m][1] = __builtin_amdgcn_mfma_f32_16x16x32_bf16(af, bf1, a2[m][1], 0, 0, 0);
        }
    }
    float lam = lamb[0];
    float sb0 = stb[c0s + lr], sb1 = stb[c0s + 16 + lr];
    #pragma unroll
    for (int m = 0; m < 2; ++m)
        #pragma unroll
        for (int j = 0; j < 4; ++j) {
            int n = row0 + m * 16 + kg * 4 + j;
            if (n < N) {
                int ca = c0s + lr, cb = c0s + 16 + lr;
                float va = lky(a2[m][0][j] + sb0);
                float vb = lky(a2[m][1][j] + sb1);
                out[(size_t)n * 128 + ca] = lam * stat[(size_t)n * 128 + ca] + (1.f - lam) * va;
                out[(size_t)n * 128 + cb] = lam * stat[(size_t)n * 128 + cb] + (1.f - lam) * vb;
            }
        }
}

extern "C" void kernel_launch(void* const* d_in, const int* in_sizes, int n_in,
                              void* d_out, int out_size, void* d_ws, size_t ws_size,
                              hipStream_t stream) {
    const int*   src        = (const int*)d_in[0];
    const int*   tgt        = (const int*)d_in[1];
    const float* ts         = (const float*)d_in[2];
    const float* now_time   = (const float*)d_in[3];
    const float* nodef      = (const float*)d_in[5];
    const float* memory     = (const float*)d_in[6];
    const float* last_upd   = (const float*)d_in[7];
    const float* vmem       = (const float*)d_in[8];
    const float* vlast      = (const float*)d_in[9];
    const float* A_r        = (const float*)d_in[10];
    const float* static_emb = (const float*)d_in[11];
    const float* lamb       = (const float*)d_in[12];
    const float* lambs      = (const float*)d_in[13];
    const float* mf_W1      = (const float*)d_in[14];
    const float* mf_b1      = (const float*)d_in[15];
    const float* mf_W2      = (const float*)d_in[16];
    const float* mf_b2      = (const float*)d_in[17];
    const float* ffr_W1     = (const float*)d_in[18];
    const float* ffr_b1     = (const float*)d_in[19];
    const float* ffr_W2     = (const float*)d_in[20];
    const float* ffr_b2     = (const float*)d_in[21];
    const float* et_W       = (const float*)d_in[22];
    const float* et_b       = (const float*)d_in[23];
    const float* st_W       = (const float*)d_in[24];
    const float* st_b       = (const float*)d_in[25];

    int E = in_sizes[0];
    int N = in_sizes[7];

    float* ws = (float*)d_ws;
    size_t off = 0;
    auto alloc = [&](size_t nf) { float* p = ws + off; off += (nf + 63) & ~(size_t)63; return p; };
    unsigned short* aggb  = (unsigned short*)alloc((size_t)SN * 384);     // SN*3 rows x 256 bf16
    unsigned short* msg_feat = (unsigned short*)alloc((size_t)N * 96);    // bf16
    unsigned short* AexpT   = (unsigned short*)alloc((size_t)224 * SN / 2);
    unsigned short* Aexp_rm = (unsigned short*)alloc((size_t)SN * 224 / 2);
    float* tv_union = alloc((size_t)VCM * 172032);      // temb (N*128) then vpart (VCM*172032)
    float* vmid     = alloc(224 * 768);
    unsigned short* vembT = (unsigned short*)alloc((size_t)192 * 224 / 2 + 64);
    float* t_max    = alloc(N);
    float* rowsum   = alloc(N);
    float* cnt3     = alloc((size_t)SN * 3);
    float* colsum   = alloc(256);
    unsigned short* W1T  = (unsigned short*)alloc(128 * 256 / 2);
    unsigned short* W2T  = (unsigned short*)alloc(64 * 128 / 2);
    unsigned short* etWT = (unsigned short*)alloc(64 * 192 / 2);
    unsigned short* stWT = (unsigned short*)alloc(128 * 128 / 2);
    int*   cnt      = (int*)alloc(NSCAN);               // padded+zeroed for int4 scan
    int*   offsets  = (int*)alloc(N + 1);
    int*   cursor   = (int*)alloc(N);
    int*   sorted   = (int*)alloc(E);
    int*   has_msg  = (int*)alloc(N);
    if (off * sizeof(float) > ws_size) return;   // workspace guard

    unsigned int* temb = (unsigned int*)tv_union;   // live: k_prep..k_agg
    float* vpart = tv_union;                        // live: k_vmid_mfma..k_vred
    // overlays: aggb region is dead after k_mf_mfma + k_vmid_mfma
    unsigned short* node_emb  = (unsigned short*)aggb;
    unsigned short* vnode_emb = node_emb + (size_t)N * 192;

    k_init<<<(NSCAN + 255) / 256, 256, 0, stream>>>(t_max, cnt, cursor, colsum, N, NSCAN);
    k_tbf<<<(256 * 128 + 255) / 256, 256, 0, stream>>>(mf_W1, W1T, 256, 128);
    k_tbf<<<(128 * 64 + 255) / 256, 256, 0, stream>>>(mf_W2, W2T, 128, 64);
    k_tbf<<<(192 * 64 + 255) / 256, 256, 0, stream>>>(et_W, etWT, 192, 64);
    k_tbf<<<(128 * 128 + 255) / 256, 256, 0, stream>>>(st_W, stWT, 128, 128);
    k_tmax_cnt<<<(E + 255) / 256, 256, 0, stream>>>(src, ts, t_max, cnt, E);
    k_scan<<<1, 1024, 0, stream>>>(cnt, offsets, N);
    k_scatter<<<(E + 255) / 256, 256, 0, stream>>>(src, offsets, cursor, sorted, E);
    k_prep<<<(N + 3) / 4, 256, 0, stream>>>(memory, nodef, temb, N);
    k_aexp<<<SN / 64, 256, 0, stream>>>(A_r, rowsum, colsum, AexpT, Aexp_rm, N);
    k_agg<<<AGG_BLOCKS, 256, 0, stream>>>(tgt, ts, sorted, offsets, t_max, temb,
                                          lambs, (unsigned int*)aggb, cnt3, has_msg, N);
    k_mf_mfma<<<SN * 3 / 64, 512, 0, stream>>>(aggb, W1T, mf_b1, W2T, mf_b2, msg_feat, N * 3);
    k_vmid_mfma<<<NWG_V, 256, 0, stream>>>(AexpT, aggb, cnt3, vpart);
    k_vred<<<(224 * 768 + 255) / 256, 256, 0, stream>>>(vpart, colsum, vmid);
    k_ffr<<<42, 256, 0, stream>>>(vmid, ffr_W1, ffr_b1, ffr_W2, ffr_b2, vmem, vlast,
                                  lambs, now_time, vembT);
    k_newmem<<<N, 192, 0, stream>>>(memory, msg_feat, cnt3, t_max, last_upd, has_msg,
                                    lambs, node_emb, N);
    k_vnode_mfma<<<SN / 64, 256, 0, stream>>>(Aexp_rm, vembT, rowsum, vnode_emb, N);
    k_et_st_mfma<<<SN / 32, 256, 0, stream>>>(node_emb, vnode_emb, etWT, et_b, stWT, st_b,
                                              static_emb, lamb, (float*)d_out, N);
}

// Round 15
// 356.292 us; speedup vs baseline: 1.0924x; 1.0406x over previous
//
#include <hip/hip_runtime.h>

static __device__ __forceinline__ float lky(float x) { return x > 0.f ? x : 0.01f * x; }

static __device__ __forceinline__ unsigned short f2bf(float x) {
    unsigned int u = __float_as_uint(x);
    unsigned int r = (u + 0x7FFFu + ((u >> 16) & 1u)) >> 16;
    return (unsigned short)r;
}
static __device__ __forceinline__ float bf2f(unsigned short x) {
    return __uint_as_float((unsigned int)x << 16);
}
static __device__ __forceinline__ unsigned int pack2bf(float lo, float hi) {
    return (unsigned int)f2bf(lo) | ((unsigned int)f2bf(hi) << 16);
}

typedef __attribute__((ext_vector_type(8))) short short8;
typedef __attribute__((ext_vector_type(4))) float f32x4;

constexpr int SN  = 50048;   // padded node count (multiple of 64)
constexpr int KLV = 608;     // K(nodes) per split-K chunk (multiple of 32)
constexpr int VCM = 83;      // ceil(SN/KLV)
constexpr int NSCAN = 53248; // 13 * 4096, scan padding
constexpr int NWG_V = 12 * VCM;      // 996
constexpr int NQ_V  = NWG_V / 8;     // 124
constexpr int NR_V  = NWG_V % 8;     // 4
constexpr int AGG_BLOCKS = 2048;     // persistent k_agg blocks
constexpr int AGG_WAVES  = AGG_BLOCKS * 4;
constexpr int SETUP_BLOCKS = 2048;
constexpr int SETUP_WAVES  = SETUP_BLOCKS * 4;

// ---------------- fused setup: init + 4 weight transposes + temb prep ----------------
__global__ __launch_bounds__(256) void k_setup(
        float* t_max, int* cnt, int* cursor, float* colsum,
        const float* __restrict__ mf_W1, unsigned short* __restrict__ W1T,
        const float* __restrict__ mf_W2, unsigned short* __restrict__ W2T,
        const float* __restrict__ et_W,  unsigned short* __restrict__ etWT,
        const float* __restrict__ st_W,  unsigned short* __restrict__ stWT,
        const float* __restrict__ memory, const float* __restrict__ nodef,
        unsigned int* __restrict__ temb, int N, int NP) {
    int gid = blockIdx.x * 256 + threadIdx.x;
    // init
    if (gid < N) { t_max[gid] = -1.0f; cursor[gid] = 0; }
    if (gid < NP) cnt[gid] = 0;
    if (gid < 224) colsum[gid] = 0.0f;
    // weight transposes (disjoint gid ranges; dst[c*K+k] = src[k*C+c])
    if (gid < 128 * 256) {                       // W1T: K=256, C=128
        int c = gid / 256, k = gid % 256;
        W1T[gid] = f2bf(mf_W1[k * 128 + c]);
    } else if (gid < 128 * 256 + 64 * 128) {     // W2T: K=128, C=64
        int i = gid - 128 * 256;
        int c = i / 128, k = i % 128;
        W2T[i] = f2bf(mf_W2[k * 64 + c]);
    } else if (gid < 128 * 256 + 64 * 128 + 64 * 192) {   // etWT: K=192, C=64
        int i = gid - (128 * 256 + 64 * 128);
        int c = i / 192, k = i % 192;
        etWT[i] = f2bf(et_W[k * 64 + c]);
    } else if (gid < 128 * 256 + 64 * 128 + 64 * 192 + 128 * 128) {  // stWT: K=128, C=128
        int i = gid - (128 * 256 + 64 * 128 + 64 * 192);
        int c = i / 128, k = i % 128;
        stWT[i] = f2bf(st_W[k * 128 + c]);
    }
    // temb prep: wave-stride over nodes
    int gw = blockIdx.x * 4 + (threadIdx.x >> 6);
    int lane = threadIdx.x & 63;
    for (int n = gw; n < N; n += SETUP_WAVES) {
        const float* mrow = memory + (size_t)n * 195;
        float d0 = mrow[64], d1 = mrow[129], d2 = mrow[194];
        int f = 2 * lane;
        float den = (f < 64) ? d0 : d1;
        int offA = (f < 64) ? f : f + 1;
        float va0 = mrow[offA] / den;
        float va1 = mrow[offA + 1] / den;
        float vb0, vb1;
        if (lane < 32) {
            vb0 = mrow[130 + 2 * lane] / d2;
            vb1 = mrow[131 + 2 * lane] / d2;
        } else {
            const float* nf = nodef + (size_t)n * 64 + 2 * (lane - 32);
            vb0 = nf[0]; vb1 = nf[1];
        }
        temb[(size_t)n * 128 + lane]      = pack2bf(va0, va1);
        temb[(size_t)n * 128 + 64 + lane] = pack2bf(vb0, vb1);
    }
}

// ---------------- per-edge t_max / counts ----------------
__global__ void k_tmax_cnt(const int* __restrict__ src, const float* __restrict__ ts,
                           float* t_max, int* cnt, int E) {
    int e = blockIdx.x * 256 + threadIdx.x;
    if (e >= E) return;
    int s = src[e];
    atomicMax((int*)(t_max + s), __float_as_int(ts[e]));   // ts >= 0, int-monotone
    atomicAdd(cnt + s, 1);
}

// ---------------- exclusive scan over counts (single block, 4096/iter) ----------------
__global__ __launch_bounds__(1024) void k_scan(const int* __restrict__ cnt,
                                               int* __restrict__ offsets, int N) {
    __shared__ int wsum[16];
    __shared__ int s_run;
    int t = threadIdx.x;
    int lane = t & 63, wid = t >> 6;
    if (t == 0) s_run = 0;
    __syncthreads();
    int nchunk = (N + 4095) >> 12;
    for (int c = 0; c < nchunk; ++c) {
        int i0 = (c << 12) + t * 4;
        int4 v = *(const int4*)(cnt + i0);     // cnt zero-padded to NSCAN
        int s = v.x + v.y + v.z + v.w;
        int x = s;
        #pragma unroll
        for (int d = 1; d < 64; d <<= 1) {
            int y = __shfl_up(x, d, 64);
            if (lane >= d) x += y;
        }
        if (lane == 63) wsum[wid] = x;
        __syncthreads();
        int wbase = 0;
        #pragma unroll
        for (int w = 0; w < 16; ++w) wbase += (w < wid) ? wsum[w] : 0;
        int run = s_run;
        int base = run + wbase + x - s;
        if (i0 + 3 < N) {
            int4 o;
            o.x = base; o.y = base + v.x; o.z = o.y + v.y; o.w = o.z + v.z;
            *(int4*)(offsets + i0) = o;
        } else {
            int o = base;
            if (i0 < N) offsets[i0] = o;
            o += v.x;
            if (i0 + 1 < N) offsets[i0 + 1] = o;
            o += v.y;
            if (i0 + 2 < N) offsets[i0 + 2] = o;
            o += v.z;
            if (i0 + 3 < N) offsets[i0 + 3] = o;
        }
        __syncthreads();
        if (t == 1023) s_run = run + wbase + x;
        __syncthreads();
    }
    if (t == 0) offsets[N] = s_run;
}

// ---------------- scatter edges into per-node buckets ----------------
__global__ void k_scatter(const int* __restrict__ src, const int* __restrict__ offsets,
                          int* cursor, int* sorted, int E) {
    int e = blockIdx.x * 256 + threadIdx.x;
    if (e >= E) return;
    int s = src[e];
    int pos = offsets[s] + atomicAdd(cursor + s, 1);
    sorted[pos] = e;
}

// ---------------- A_r pass: rowsum, colsum, bf16 Aexp_rm + AexpT (throughput form) ----------------
__global__ __launch_bounds__(256) void k_aexp(
        const float* __restrict__ A_r,
        float* __restrict__ rowsum, float* __restrict__ colsum,
        unsigned short* __restrict__ AexpT, unsigned short* __restrict__ Aexp_rm, int N) {
    __shared__ unsigned short sE[64][228];   // 456B row stride: 8B-aligned, ~2-way banks
    int t = threadIdx.x;
    int n0 = blockIdx.x * 64;
    int maxq = min(64, N - n0) * 56;
    const float4* src = (const float4*)(A_r + (size_t)n0 * 224);
    #pragma unroll
    for (int k = 0; k < 14; ++k) {
        int i = t + k * 256;
        float4 v = (i < maxq) ? src[i] : (float4){-1e30f, -1e30f, -1e30f, -1e30f};
        int row = i / 56, cq = i % 56;
        uint2 pk;
        pk.x = pack2bf(__expf(v.x), __expf(v.y));
        pk.y = pack2bf(__expf(v.z), __expf(v.w));
        *(uint2*)&sE[row][cq * 4] = pk;
    }
    __syncthreads();
    // rowsum: 4 threads per row, 2 shuffles
    {
        int row = t >> 2, q = t & 3;
        const uint2* p = (const uint2*)&sE[row][q * 56];
        float s = 0.f;
        #pragma unroll
        for (int c = 0; c < 7; ++c) {
            uint2 u = p[c];
            s += __uint_as_float(u.x << 16) + __uint_as_float(u.x & 0xffff0000u)
               + __uint_as_float(u.y << 16) + __uint_as_float(u.y & 0xffff0000u);
        }
        s += __shfl_xor(s, 1, 64);
        s += __shfl_xor(s, 2, 64);
        if (q == 0 && n0 + row < N) rowsum[n0 + row] = s;
    }
    // colsum partials
    if (t < 224) {
        float s = 0.f;
        #pragma unroll 8
        for (int r = 0; r < 64; ++r) s += bf2f(sE[r][t]);
        atomicAdd(colsum + t, s);
    }
    // row-major write, packed uints, coalesced
    {
        unsigned int* dst = (unsigned int*)Aexp_rm;
        for (int i = t; i < 64 * 112; i += 256) {
            int n = i / 112, cp = i % 112;
            dst[(size_t)(n0 + n) * 112 + cp] = *(const unsigned int*)&sE[n][2 * cp];
        }
    }
    // transposed write: wave-coalesced 128B runs per r-row
    {
        unsigned int* dst = (unsigned int*)AexpT;
        for (int u = t; u < 224 * 32; u += 256) {
            int r = u >> 5, np = u & 31;
            unsigned int lo = sE[2 * np][r];
            unsigned int hi = sE[2 * np + 1][r];
            dst[(size_t)r * (SN / 2) + (n0 >> 1) + np] = lo | (hi << 16);
        }
    }
}

// ---------------- per-node aggregation: persistent strided waves ----------------
__global__ __launch_bounds__(256) void k_agg(
        const int* __restrict__ tgt, const float* __restrict__ ts,
        const int* __restrict__ sorted, const int* __restrict__ offsets,
        const float* __restrict__ t_max, const unsigned int* __restrict__ temb,
        const float* __restrict__ lambs,
        unsigned int* __restrict__ aggb, float* __restrict__ cnt3,
        int* __restrict__ has_msg, int N) {
    int gw = blockIdx.x * 4 + (threadIdx.x >> 6);   // global wave id
    int lane = threadIdx.x & 63;
    float lb0 = lambs[0], lb1 = lambs[1], lb2 = lambs[2];
    for (int n = gw; n < SN; n += AGG_WAVES) {
        size_t rb = (size_t)n * 3;
        if (n >= N) {                       // zero-fill padding rows
            #pragma unroll
            for (int l = 0; l < 3; ++l) {
                unsigned int* row = aggb + (rb + l) * 128;
                row[lane] = 0; row[64 + lane] = 0;
                if (lane == 0) cnt3[rb + l] = 0.f;
            }
            continue;
        }
        int beg = offsets[n], end = offsets[n + 1];
        float tm = t_max[n];
        float aa0[3], aa1[3], ab0[3], ab1[3], accc[3];
        #pragma unroll
        for (int l = 0; l < 3; ++l) { aa0[l] = aa1[l] = ab0[l] = ab1[l] = accc[l] = 0.f; }
        for (int idx = beg; idx < end; ++idx) {
            int e = sorted[idx];
            int tt = tgt[e];
            float d = tm - ts[e];
            unsigned int ua = temb[(size_t)tt * 128 + lane];
            unsigned int ub = temb[(size_t)tt * 128 + 64 + lane];
            float a0 = __uint_as_float(ua << 16);
            float a1 = __uint_as_float(ua & 0xffff0000u);
            float b0 = __uint_as_float(ub << 16);
            float b1 = __uint_as_float(ub & 0xffff0000u);
            float w0 = __expf(-lb0 * d), w1 = __expf(-lb1 * d), w2 = __expf(-lb2 * d);
            aa0[0] += w0 * a0; aa1[0] += w0 * a1; ab0[0] += w0 * b0; ab1[0] += w0 * b1; accc[0] += w0;
            aa0[1] += w1 * a0; aa1[1] += w1 * a1; ab0[1] += w1 * b0; ab1[1] += w1 * b1; accc[1] += w1;
            aa0[2] += w2 * a0; aa1[2] += w2 * a1; ab0[2] += w2 * b0; ab1[2] += w2 * b1; accc[2] += w2;
        }
        #pragma unroll
        for (int l = 0; l < 3; ++l) {
            unsigned int* row = aggb + (rb + l) * 128;
            row[lane]      = pack2bf(aa0[l], aa1[l]);
            row[64 + lane] = pack2bf(ab0[l], ab1[l]);
            if (lane == 0) cnt3[rb + l] = accc[l];
        }
        if (lane == 0) has_msg[n] = (end > beg) ? 1 : 0;
    }
}

// ---------------- mf MLP via MFMA: 512 threads (8 waves), 64 rows/block, W-prefetch ----------------
__global__ __launch_bounds__(512, 3) void k_mf_mfma(
        const unsigned short* __restrict__ aggb,
        const unsigned short* __restrict__ W1T, const float* __restrict__ b1,
        const unsigned short* __restrict__ W2T, const float* __restrict__ b2,
        unsigned short* __restrict__ msg_feat, int NROWS) {
    __shared__ unsigned short As[64 * 264];
    __shared__ unsigned short Hs[64 * 136];
    int t = threadIdx.x, lane = t & 63, w = t >> 6;   // w in 0..7
    int lr = lane & 15, kg = lane >> 4;
    int row0 = blockIdx.x * 64;
    {   // stage A: 64 rows x 256 bf16, 8 threads/row (32 shorts each)
        int r = t >> 3, s8 = t & 7;
        const uint4* src = (const uint4*)(aggb + (size_t)(row0 + r) * 256 + s8 * 32);
        uint4* dst = (uint4*)(As + r * 264 + s8 * 32);
        #pragma unroll
        for (int u = 0; u < 4; ++u) dst[u] = src[u];
    }
    __syncthreads();
    // layer 1: wave w -> cols [w*16, w*16+16); 64 rows
    int n0 = w * 16;
    f32x4 acc[4];
    #pragma unroll
    for (int m = 0; m < 4; ++m) acc[m] = (f32x4){0.f, 0.f, 0.f, 0.f};
    short8 bfc = *(const short8*)(W1T + (size_t)(n0 + lr) * 256 + kg * 8);
    #pragma unroll
    for (int kk = 0; kk < 8; ++kk) {
        short8 bfn;
        if (kk < 7)
            bfn = *(const short8*)(W1T + (size_t)(n0 + lr) * 256 + (kk + 1) * 32 + kg * 8);
        #pragma unroll
        for (int m = 0; m < 4; ++m) {
            short8 af = *(const short8*)(As + (m * 16 + lr) * 264 + kk * 32 + kg * 8);
            acc[m] = __builtin_amdgcn_mfma_f32_16x16x32_bf16(af, bfc, acc[m], 0, 0, 0);
        }
        bfc = bfn;
    }
    float bb0 = b1[n0 + lr];
    #pragma unroll
    for (int m = 0; m < 4; ++m)
        #pragma unroll
        for (int j = 0; j < 4; ++j) {
            int row = m * 16 + kg * 4 + j;
            Hs[row * 136 + n0 + lr] = f2bf(fmaxf(acc[m][j] + bb0, 0.f));
        }
    __syncthreads();
    // layer 2: wave w -> rows [(w>>2)*32, +32), cols [(w&3)*16, +16); K=128
    int rh = (w >> 2) * 32;
    int c0 = (w & 3) * 16;
    f32x4 a2[2];
    a2[0] = (f32x4){0.f, 0.f, 0.f, 0.f};
    a2[1] = (f32x4){0.f, 0.f, 0.f, 0.f};
    short8 b2c = *(const short8*)(W2T + (size_t)(c0 + lr) * 128 + kg * 8);
    #pragma unroll
    for (int kk = 0; kk < 4; ++kk) {
        short8 b2n;
        if (kk < 3)
            b2n = *(const short8*)(W2T + (size_t)(c0 + lr) * 128 + (kk + 1) * 32 + kg * 8);
        #pragma unroll
        for (int m = 0; m < 2; ++m) {
            short8 af = *(const short8*)(Hs + (rh + m * 16 + lr) * 136 + kk * 32 + kg * 8);
            a2[m] = __builtin_amdgcn_mfma_f32_16x16x32_bf16(af, b2c, a2[m], 0, 0, 0);
        }
        b2c = b2n;
    }
    float b2v = b2[c0 + lr];
    #pragma unroll
    for (int m = 0; m < 2; ++m)
        #pragma unroll
        for (int j = 0; j < 4; ++j) {
            int row = row0 + rh + m * 16 + kg * 4 + j;
            if (row < NROWS)
                msg_feat[(size_t)row * 64 + c0 + lr] = f2bf(fmaxf(a2[m][j] + b2v, 0.f));
        }
}

// ---------------- vmid via bf16 MFMA, split-K; XCD-swizzled, B LDS-staged ----------------
__global__ __launch_bounds__(256, 4) void k_vmid_mfma(
        const unsigned short* __restrict__ AexpT, const unsigned short* __restrict__ aggb,
        const float* __restrict__ cnt3, float* __restrict__ vpart) {
    __shared__ unsigned short As[112 * 40];   // 112 rows x 32 shorts (stride 40 = 80B)
    __shared__ unsigned int BsT[128 * 20];    // [col][np-uint] stride 20; np ^= ((col>>3)&3)<<2
    // bijective XCD swizzle: co-locate the 12 tiles of each chunk on one XCD
    int bx = blockIdx.x;
    int xcd = bx & 7, bidx = bx >> 3;
    int virt = (xcd < NR_V) ? xcd * (NQ_V + 1) + bidx
                            : NR_V * (NQ_V + 1) + (xcd - NR_V) * NQ_V + bidx;
    int chunk = virt / 12, tile = virt % 12;
    int r0 = (tile & 1) * 112;
    int ft = tile >> 1;                 // 0..5
    int l = ft >> 1, fo = (ft & 1) * 128;
    int t = threadIdx.x, lane = t & 63, w = t >> 6;
    int lr = lane & 15, kg = lane >> 4;
    int np = t >> 4, sg = t & 15;       // B staging: node-pair, col-segment(8 cols)
    f32x4 acc[7][2];
    #pragma unroll
    for (int q = 0; q < 7; ++q) {
        acc[q][0] = (f32x4){0.f, 0.f, 0.f, 0.f};
        acc[q][1] = (f32x4){0.f, 0.f, 0.f, 0.f};
    }
    int nbeg = chunk * KLV;
    int nsteps = min(KLV, SN - nbeg) >> 5;
    int c0 = w * 32 + lr, c1 = c0 + 16;
    int rb0 = c0 * 20 + (kg ^ ((c0 >> 3) & 3)) * 4;
    int rb1 = c1 * 20 + (kg ^ ((c1 >> 3) & 3)) * 4;
    int swz = np ^ ((sg & 3) << 2);
    for (int s = 0; s < nsteps; ++s) {
        int n0 = nbeg + s * 32;
        if (t < 224) {                   // stage A: 2 threads/row, 32 shorts/row
            int srow = t >> 1, sseg = t & 1;
            const uint4* ap = (const uint4*)(AexpT + (size_t)(r0 + srow) * SN + n0) + sseg * 2;
            uint4 v0 = ap[0];
            uint4 v1 = ap[1];
            *(uint4*)&As[srow * 40 + sseg * 16]     = v0;
            *(uint4*)&As[srow * 40 + sseg * 16 + 8] = v1;
        }
        {   // stage B: nodes (2np, 2np+1) x cols [sg*8, sg*8+8), scaled by 1/den, k-pair packed
            int na = n0 + 2 * np;
            size_t ra = ((size_t)na * 3 + l) * 256 + fo + sg * 8;
            uint4 va = *(const uint4*)(aggb + ra);
            uint4 vb = *(const uint4*)(aggb + ra + 768);
            float da = 1.f / fmaxf(cnt3[(size_t)na * 3 + l], 1e-6f);
            float db = 1.f / fmaxf(cnt3[(size_t)na * 3 + l + 3], 1e-6f);
            const unsigned short* pa = (const unsigned short*)&va;
            const unsigned short* pb = (const unsigned short*)&vb;
            unsigned int* dst = BsT + sg * 160 + swz;
            #pragma unroll
            for (int j = 0; j < 8; ++j)
                dst[j * 20] = pack2bf(bf2f(pa[j]) * da, bf2f(pb[j]) * db);
        }
        __syncthreads();
        short8 b0 = *(const short8*)((const unsigned short*)(BsT + rb0));
        short8 b1 = *(const short8*)((const unsigned short*)(BsT + rb1));
        #pragma unroll
        for (int q = 0; q < 7; ++q) {
            short8 af = *(const short8*)&As[(q * 16 + lr) * 40 + kg * 8];
            acc[q][0] = __builtin_amdgcn_mfma_f32_16x16x32_bf16(af, b0, acc[q][0], 0, 0, 0);
            acc[q][1] = __builtin_amdgcn_mfma_f32_16x16x32_bf16(af, b1, acc[q][1], 0, 0, 0);
        }
        __syncthreads();
    }
    float* outp = vpart + (size_t)chunk * 172032;
    #pragma unroll
    for (int q = 0; q < 7; ++q) {
        int row = r0 + q * 16 + kg * 4;
        #pragma unroll
        for (int p = 0; p < 2; ++p) {
            int col = l * 256 + fo + w * 32 + p * 16 + lr;
            #pragma unroll
            for (int j = 0; j < 4; ++j)
                outp[(size_t)(row + j) * 768 + col] = acc[q][p][j];
        }
    }
}

// ---------------- reduce vpart over chunks, divide by colsum ----------------
__global__ void k_vred(const float* __restrict__ vpart, const float* __restrict__ colsum,
                       float* __restrict__ vmid) {
    int idx = blockIdx.x * 256 + threadIdx.x;
    if (idx >= 224 * 768) return;
    float s = 0.f;
    for (int c = 0; c < VCM; ++c) s += vpart[(long)c * (224 * 768) + idx];
    vmid[idx] = s / colsum[idx / 768];
}

// ---------------- ffr MLP (672 rows) + virtual-memory decay -> vembT (bf16) ----------------
__global__ __launch_bounds__(256) void k_ffr(
        const float* __restrict__ vmid, const float* __restrict__ W1, const float* __restrict__ b1,
        const float* __restrict__ W2, const float* __restrict__ b2,
        const float* __restrict__ vmem, const float* __restrict__ vlast,
        const float* __restrict__ lambs, const float* __restrict__ now_time,
        unsigned short* __restrict__ vembT) {
    __shared__ float sin_[16][260];
    __shared__ float svh[16][260];
    int row0 = blockIdx.x * 16;
    int t = threadIdx.x;
    #pragma unroll
    for (int k = 0; k < 16; ++k) {
        int idx = t + k * 256;
        int r = idx >> 8, f = idx & 255;
        sin_[r][f] = vmid[(long)(row0 + r) * 256 + f];
    }
    __syncthreads();
    {   // layer 1: 16 x 256, 4r x 4c
        int cg = t & 63, rg = t >> 6;
        int c0 = cg * 4, r0 = rg * 4;
        float acc[4][4];
        #pragma unroll
        for (int i = 0; i < 4; ++i)
            #pragma unroll
            for (int j = 0; j < 4; ++j) acc[i][j] = 0.f;
        for (int f0 = 0; f0 < 256; f0 += 4) {
            float4 a[4];
            #pragma unroll
            for (int i = 0; i < 4; ++i) a[i] = *(const float4*)&sin_[r0 + i][f0];
            #pragma unroll
            for (int ff = 0; ff < 4; ++ff) {
                float4 w = *(const float4*)&W1[(long)(f0 + ff) * 256 + c0];
                #pragma unroll
                for (int i = 0; i < 4; ++i) {
                    float av = (&a[i].x)[ff];
                    acc[i][0] += av * w.x; acc[i][1] += av * w.y;
                    acc[i][2] += av * w.z; acc[i][3] += av * w.w;
                }
            }
        }
        #pragma unroll
        for (int i = 0; i < 4; ++i)
            #pragma unroll
            for (int j = 0; j < 4; ++j)
                svh[r0 + i][c0 + j] = lky(acc[i][j] + b1[c0 + j]);
    }
    __syncthreads();
    {   // layer 2: 16 x 64, 2r x 2c + decay epilogue
        int cg = t & 31, rg = t >> 5;
        int c0 = cg * 2, r0 = rg * 2;
        float acc[2][2];
        acc[0][0] = acc[0][1] = acc[1][0] = acc[1][1] = 0.f;
        for (int f0 = 0; f0 < 256; f0 += 4) {
            float4 a[2];
            #pragma unroll
            for (int i = 0; i < 2; ++i) a[i] = *(const float4*)&svh[r0 + i][f0];
            #pragma unroll
            for (int ff = 0; ff < 4; ++ff) {
                float2 w = *(const float2*)&W2[(long)(f0 + ff) * 64 + c0];
                #pragma unroll
                for (int i = 0; i < 2; ++i) {
                    float av = (&a[i].x)[ff];
                    acc[i][0] += av * w.x; acc[i][1] += av * w.y;
                }
            }
        }
        float nowv = now_time[0];
        #pragma unroll
        for (int i = 0; i < 2; ++i) {
            int row = row0 + r0 + i;           // row = rr*3 + l
            int rr = row / 3, l = row % 3;
            float vd = __expf(-lambs[l] * (nowv - vlast[rr]));
            #pragma unroll
            for (int j = 0; j < 2; ++j) {
                float v = lky(acc[i][j] + b2[c0 + j]);
                int m = c0 + j;
                vembT[(size_t)(l * 64 + m) * 224 + rr] =
                    f2bf(vmem[(long)rr * 192 + l * 64 + m] * vd + v);
            }
        }
    }
}

// ---------------- new_mem -> node_emb (bf16) ----------------
__global__ void k_newmem(const float* __restrict__ memory,
        const unsigned short* __restrict__ msg_feat,
        const float* __restrict__ cnt3, const float* __restrict__ t_max,
        const float* __restrict__ last_update, const int* __restrict__ has_msg,
        const float* __restrict__ lambs, unsigned short* __restrict__ node_emb, int N) {
    int n = blockIdx.x;
    int j = threadIdx.x;                 // 0..191
    int l = j >> 6, m = j & 63;
    int has = has_msg[n];
    float dt = has ? (t_max[n] - last_update[n]) : 0.f;
    float decay = __expf(-lambs[l] * dt);
    long mb = (long)n * 195 + l * 65;
    float num = memory[mb + m];
    float den = memory[mb + 64];
    if (has) {
        num = num * decay + bf2f(msg_feat[(size_t)n * 192 + j]);
        den = den * decay + cnt3[(size_t)n * 3 + l];
    }
    node_emb[(size_t)n * 192 + j] = f2bf(num / fmaxf(den, 1e-6f));
}

// ---------------- vnode_emb = row-softmax(A_r) @ v_emb via MFMA (LDS-staged A) ----------------
__global__ __launch_bounds__(256, 4) void k_vnode_mfma(
        const unsigned short* __restrict__ Aexp_rm, const unsigned short* __restrict__ vembT,
        const float* __restrict__ rowsum, unsigned short* __restrict__ vnode_emb, int N) {
    __shared__ unsigned short As[64 * 232];
    __shared__ float sRS[64];
    int t = threadIdx.x, lane = t & 63, w = t >> 6;
    int lr = lane & 15, kg = lane >> 4;
    int row0 = blockIdx.x * 64;
    {
        int r = t >> 2, sg = t & 3;
        const uint4* src = (const uint4*)(Aexp_rm + (size_t)(row0 + r) * 224 + sg * 56);
        uint4* dst = (uint4*)(As + r * 232 + sg * 56);
        #pragma unroll
        for (int u = 0; u < 7; ++u) dst[u] = src[u];
    }
    if (t < 64) sRS[t] = rowsum[min(row0 + t, N - 1)];
    __syncthreads();
    int n0 = w * 48;                      // 192 cols / 4 waves
    f32x4 acc[4][3];
    #pragma unroll
    for (int m = 0; m < 4; ++m)
        #pragma unroll
        for (int nt = 0; nt < 3; ++nt) acc[m][nt] = (f32x4){0.f, 0.f, 0.f, 0.f};
    #pragma unroll
    for (int kk = 0; kk < 7; ++kk) {
        short8 bf[3];
        #pragma unroll
        for (int nt = 0; nt < 3; ++nt)
            bf[nt] = *(const short8*)(vembT + (size_t)(n0 + nt * 16 + lr) * 224 + kk * 32 + kg * 8);
        #pragma unroll
        for (int m = 0; m < 4; ++m) {
            short8 af = *(const short8*)(As + (m * 16 + lr) * 232 + kk * 32 + kg * 8);
            #pragma unroll
            for (int nt = 0; nt < 3; ++nt)
                acc[m][nt] = __builtin_amdgcn_mfma_f32_16x16x32_bf16(af, bf[nt], acc[m][nt], 0, 0, 0);
        }
    }
    #pragma unroll
    for (int m = 0; m < 4; ++m)
        #pragma unroll
        for (int j = 0; j < 4; ++j) {
            int row = row0 + m * 16 + kg * 4 + j;
            if (row < N) {
                float inv = 1.f / sRS[row - row0];
                #pragma unroll
                for (int nt = 0; nt < 3; ++nt)
                    vnode_emb[(size_t)row * 192 + n0 + nt * 16 + lr] = f2bf(acc[m][nt][j] * inv);
            }
        }
}

// ---------------- et + st + output blend via MFMA: 32 rows/block, LDS-staged ----------------
__global__ __launch_bounds__(256, 4) void k_et_st_mfma(
        const unsigned short* __restrict__ ne, const unsigned short* __restrict__ ve,
        const unsigned short* __restrict__ etWT, const float* __restrict__ etb,
        const unsigned short* __restrict__ stWT, const float* __restrict__ stb,
        const float* __restrict__ stat, const float* __restrict__ lamb,
        float* __restrict__ out, int N) {
    __shared__ unsigned short As[64 * 200];    // rows 0-31: node, 32-63: vnode
    __shared__ unsigned short Hs[32 * 136];    // st input [32 rows][128 cols]
    int t = threadIdx.x, lane = t & 63, w = t >> 6;
    int lr = lane & 15, kg = lane >> 4;
    int row0 = blockIdx.x * 32;
    {
        int r = t >> 3, s8 = t & 7;            // 8 threads/row, 48B each
        const uint4* sn = (const uint4*)(ne + (size_t)(row0 + r) * 192 + s8 * 24);
        const uint4* sv = (const uint4*)(ve + (size_t)(row0 + r) * 192 + s8 * 24);
        uint4* dn = (uint4*)(As + (size_t)r * 200 + s8 * 24);
        uint4* dv = (uint4*)(As + (size_t)(32 + r) * 200 + s8 * 24);
        #pragma unroll
        for (int u = 0; u < 3; ++u) { dn[u] = sn[u]; dv[u] = sv[u]; }
    }
    __syncthreads();
    // et layer: wave w -> cols [w*16, w*16+16), both halves; K=192
    int c0 = w * 16;
    f32x4 acc[2][2];
    #pragma unroll
    for (int h = 0; h < 2; ++h)
        #pragma unroll
        for (int m = 0; m < 2; ++m) acc[h][m] = (f32x4){0.f, 0.f, 0.f, 0.f};
    #pragma unroll
    for (int kk = 0; kk < 6; ++kk) {
        short8 bf = *(const short8*)(etWT + (size_t)(c0 + lr) * 192 + kk * 32 + kg * 8);
        #pragma unroll
        for (int h = 0; h < 2; ++h)
            #pragma unroll
            for (int m = 0; m < 2; ++m) {
                short8 af = *(const short8*)(As + (size_t)(h * 32 + m * 16 + lr) * 200 + kk * 32 + kg * 8);
                acc[h][m] = __builtin_amdgcn_mfma_f32_16x16x32_bf16(af, bf, acc[h][m], 0, 0, 0);
            }
    }
    float bb = etb[c0 + lr];
    #pragma unroll
    for (int h = 0; h < 2; ++h)
        #pragma unroll
        for (int m = 0; m < 2; ++m)
            #pragma unroll
            for (int j = 0; j < 4; ++j)
                Hs[(m * 16 + kg * 4 + j) * 136 + h * 64 + c0 + lr] = f2bf(lky(acc[h][m][j] + bb));
    __syncthreads();
    // st layer: wave w -> cols [w*32, w*32+32); K=128
    int c0s = w * 32;
    f32x4 a2[2][2];
    #pragma unroll
    for (int m = 0; m < 2; ++m) { a2[m][0] = (f32x4){0.f,0.f,0.f,0.f}; a2[m][1] = (f32x4){0.f,0.f,0.f,0.f}; }
    #pragma unroll
    for (int kk = 0; kk < 4; ++kk) {
        short8 bf0 = *(const short8*)(stWT + (size_t)(c0s + lr) * 128 + kk * 32 + kg * 8);
        short8 bf1 = *(const short8*)(stWT + (size_t)(c0s + 16 + lr) * 128 + kk * 32 + kg * 8);
        #pragma unroll
        for (int m = 0; m < 2; ++m) {
            short8 af = *(const short8*)(Hs + (m * 16 + lr) * 136 + kk * 32 + kg * 8);
            a2[m][0] = __builtin_amdgcn_mfma_f32_16x16x32_bf16(af, bf0, a2[m][0], 0, 0, 0);
            a2[m][1] = __builtin_amdgcn_mfma_f32_16x16x32_bf16(af, bf1, a2[m][1], 0, 0, 0);
        }
    }
    float lam = lamb[0];
    float sb0 = stb[c0s + lr], sb1 = stb[c0s + 16 + lr];
    #pragma unroll
    for (int m = 0; m < 2; ++m)
        #pragma unroll
        for (int j = 0; j < 4; ++j) {
            int n = row0 + m * 16 + kg * 4 + j;
            if (n < N) {
                int ca = c0s + lr, cb = c0s + 16 + lr;
                float va = lky(a2[m][0][j] + sb0);
                float vb = lky(a2[m][1][j] + sb1);
                out[(size_t)n * 128 + ca] = lam * stat[(size_t)n * 128 + ca] + (1.f - lam) * va;
                out[(size_t)n * 128 + cb] = lam * stat[(size_t)n * 128 + cb] + (1.f - lam) * vb;
            }
        }
}

extern "C" void kernel_launch(void* const* d_in, const int* in_sizes, int n_in,
                              void* d_out, int out_size, void* d_ws, size_t ws_size,
                              hipStream_t stream) {
    const int*   src        = (const int*)d_in[0];
    const int*   tgt        = (const int*)d_in[1];
    const float* ts         = (const float*)d_in[2];
    const float* now_time   = (const float*)d_in[3];
    const float* nodef      = (const float*)d_in[5];
    const float* memory     = (const float*)d_in[6];
    const float* last_upd   = (const float*)d_in[7];
    const float* vmem       = (const float*)d_in[8];
    const float* vlast      = (const float*)d_in[9];
    const float* A_r        = (const float*)d_in[10];
    const float* static_emb = (const float*)d_in[11];
    const float* lamb       = (const float*)d_in[12];
    const float* lambs      = (const float*)d_in[13];
    const float* mf_W1      = (const float*)d_in[14];
    const float* mf_b1      = (const float*)d_in[15];
    const float* mf_W2      = (const float*)d_in[16];
    const float* mf_b2      = (const float*)d_in[17];
    const float* ffr_W1     = (const float*)d_in[18];
    const float* ffr_b1     = (const float*)d_in[19];
    const float* ffr_W2     = (const float*)d_in[20];
    const float* ffr_b2     = (const float*)d_in[21];
    const float* et_W       = (const float*)d_in[22];
    const float* et_b       = (const float*)d_in[23];
    const float* st_W       = (const float*)d_in[24];
    const float* st_b       = (const float*)d_in[25];

    int E = in_sizes[0];
    int N = in_sizes[7];

    float* ws = (float*)d_ws;
    size_t off = 0;
    auto alloc = [&](size_t nf) { float* p = ws + off; off += (nf + 63) & ~(size_t)63; return p; };
    unsigned short* aggb  = (unsigned short*)alloc((size_t)SN * 384);     // SN*3 rows x 256 bf16
    unsigned short* msg_feat = (unsigned short*)alloc((size_t)N * 96);    // bf16
    unsigned short* AexpT   = (unsigned short*)alloc((size_t)224 * SN / 2);
    unsigned short* Aexp_rm = (unsigned short*)alloc((size_t)SN * 224 / 2);
    float* tv_union = alloc((size_t)VCM * 172032);      // temb (N*128) then vpart (VCM*172032)
    float* vmid     = alloc(224 * 768);
    unsigned short* vembT = (unsigned short*)alloc((size_t)192 * 224 / 2 + 64);
    float* t_max    = alloc(N);
    float* rowsum   = alloc(N);
    float* cnt3     = alloc((size_t)SN * 3);
    float* colsum   = alloc(256);
    unsigned short* W1T  = (unsigned short*)alloc(128 * 256 / 2);
    unsigned short* W2T  = (unsigned short*)alloc(64 * 128 / 2);
    unsigned short* etWT = (unsigned short*)alloc(64 * 192 / 2);
    unsigned short* stWT = (unsigned short*)alloc(128 * 128 / 2);
    int*   cnt      = (int*)alloc(NSCAN);               // padded+zeroed for int4 scan
    int*   offsets  = (int*)alloc(N + 1);
    int*   cursor   = (int*)alloc(N);
    int*   sorted   = (int*)alloc(E);
    int*   has_msg  = (int*)alloc(N);
    if (off * sizeof(float) > ws_size) return;   // workspace guard

    unsigned int* temb = (unsigned int*)tv_union;   // live: k_setup..k_agg
    float* vpart = tv_union;                        // live: k_vmid_mfma..k_vred
    // overlays: aggb region is dead after k_mf_mfma + k_vmid_mfma
    unsigned short* node_emb  = (unsigned short*)aggb;
    unsigned short* vnode_emb = node_emb + (size_t)N * 192;

    k_setup<<<SETUP_BLOCKS, 256, 0, stream>>>(t_max, cnt, cursor, colsum,
                                              mf_W1, W1T, mf_W2, W2T, et_W, etWT, st_W, stWT,
                                              memory, nodef, temb, N, NSCAN);
    k_tmax_cnt<<<(E + 255) / 256, 256, 0, stream>>>(src, ts, t_max, cnt, E);
    k_scan<<<1, 1024, 0, stream>>>(cnt, offsets, N);
    k_scatter<<<(E + 255) / 256, 256, 0, stream>>>(src, offsets, cursor, sorted, E);
    k_aexp<<<SN / 64, 256, 0, stream>>>(A_r, rowsum, colsum, AexpT, Aexp_rm, N);
    k_agg<<<AGG_BLOCKS, 256, 0, stream>>>(tgt, ts, sorted, offsets, t_max, temb,
                                          lambs, (unsigned int*)aggb, cnt3, has_msg, N);
    k_mf_mfma<<<SN * 3 / 64, 512, 0, stream>>>(aggb, W1T, mf_b1, W2T, mf_b2, msg_feat, N * 3);
    k_vmid_mfma<<<NWG_V, 256, 0, stream>>>(AexpT, aggb, cnt3, vpart);
    k_vred<<<(224 * 768 + 255) / 256, 256, 0, stream>>>(vpart, colsum, vmid);
    k_ffr<<<42, 256, 0, stream>>>(vmid, ffr_W1, ffr_b1, ffr_W2, ffr_b2, vmem, vlast,
                                  lambs, now_time, vembT);
    k_newmem<<<N, 192, 0, stream>>>(memory, msg_feat, cnt3, t_max, last_upd, has_msg,
                                    lambs, node_emb, N);
    k_vnode_mfma<<<SN / 64, 256, 0, stream>>>(Aexp_rm, vembT, rowsum, vnode_emb, N);
    k_et_st_mfma<<<SN / 32, 256, 0, stream>>>(node_emb, vnode_emb, etWT, et_b, stWT, st_b,
                                              static_emb, lamb, (float*)d_out, N);
}

// Round 16
// 346.870 us; speedup vs baseline: 1.1220x; 1.0272x over previous
//
#include <hip/hip_runtime.h>

static __device__ __forceinline__ float lky(float x) { return x > 0.f ? x : 0.01f * x; }

static __device__ __forceinline__ unsigned short f2bf(float x) {
    unsigned int u = __float_as_uint(x);
    unsigned int r = (u + 0x7FFFu + ((u >> 16) & 1u)) >> 16;
    return (unsigned short)r;
}
static __device__ __forceinline__ float bf2f(unsigned short x) {
    return __uint_as_float((unsigned int)x << 16);
}
static __device__ __forceinline__ unsigned int pack2bf(float lo, float hi) {
    return (unsigned int)f2bf(lo) | ((unsigned int)f2bf(hi) << 16);
}

typedef __attribute__((ext_vector_type(8))) short short8;
typedef __attribute__((ext_vector_type(4))) float f32x4;

constexpr int SN  = 50048;   // padded node count (multiple of 64)
constexpr int KLV = 608;     // K(nodes) per split-K chunk (multiple of 32)
constexpr int VCM = 83;      // ceil(SN/KLV)
constexpr int NSCAN = 53248; // 13 * 4096, scan padding
constexpr int NWG_V = 12 * VCM;      // 996
constexpr int NQ_V  = NWG_V / 8;     // 124
constexpr int NR_V  = NWG_V % 8;     // 4
constexpr int AGG_BLOCKS = 2048;     // persistent k_agg blocks
constexpr int AGG_WAVES  = AGG_BLOCKS * 4;
constexpr int SETUP_BLOCKS = 2048;
constexpr int SETUP_WAVES  = SETUP_BLOCKS * 4;

// ---------------- fused setup: init + 4 weight transposes + temb prep ----------------
__global__ __launch_bounds__(256) void k_setup(
        float* t_max, int* cnt, int* cursor, float* colsum,
        const float* __restrict__ mf_W1, unsigned short* __restrict__ W1T,
        const float* __restrict__ mf_W2, unsigned short* __restrict__ W2T,
        const float* __restrict__ et_W,  unsigned short* __restrict__ etWT,
        const float* __restrict__ st_W,  unsigned short* __restrict__ stWT,
        const float* __restrict__ memory, const float* __restrict__ nodef,
        unsigned int* __restrict__ temb, int N, int NP) {
    int gid = blockIdx.x * 256 + threadIdx.x;
    // init
    if (gid < N) { t_max[gid] = -1.0f; cursor[gid] = 0; }
    if (gid < NP) cnt[gid] = 0;
    if (gid < 224) colsum[gid] = 0.0f;
    // weight transposes (disjoint gid ranges; dst[c*K+k] = src[k*C+c])
    if (gid < 128 * 256) {                       // W1T: K=256, C=128
        int c = gid / 256, k = gid % 256;
        W1T[gid] = f2bf(mf_W1[k * 128 + c]);
    } else if (gid < 128 * 256 + 64 * 128) {     // W2T: K=128, C=64
        int i = gid - 128 * 256;
        int c = i / 128, k = i % 128;
        W2T[i] = f2bf(mf_W2[k * 64 + c]);
    } else if (gid < 128 * 256 + 64 * 128 + 64 * 192) {   // etWT: K=192, C=64
        int i = gid - (128 * 256 + 64 * 128);
        int c = i / 192, k = i % 192;
        etWT[i] = f2bf(et_W[k * 64 + c]);
    } else if (gid < 128 * 256 + 64 * 128 + 64 * 192 + 128 * 128) {  // stWT: K=128, C=128
        int i = gid - (128 * 256 + 64 * 128 + 64 * 192);
        int c = i / 128, k = i % 128;
        stWT[i] = f2bf(st_W[k * 128 + c]);
    }
    // temb prep: wave-stride over nodes
    int gw = blockIdx.x * 4 + (threadIdx.x >> 6);
    int lane = threadIdx.x & 63;
    for (int n = gw; n < N; n += SETUP_WAVES) {
        const float* mrow = memory + (size_t)n * 195;
        float d0 = mrow[64], d1 = mrow[129], d2 = mrow[194];
        int f = 2 * lane;
        float den = (f < 64) ? d0 : d1;
        int offA = (f < 64) ? f : f + 1;
        float va0 = mrow[offA] / den;
        float va1 = mrow[offA + 1] / den;
        float vb0, vb1;
        if (lane < 32) {
            vb0 = mrow[130 + 2 * lane] / d2;
            vb1 = mrow[131 + 2 * lane] / d2;
        } else {
            const float* nf = nodef + (size_t)n * 64 + 2 * (lane - 32);
            vb0 = nf[0]; vb1 = nf[1];
        }
        temb[(size_t)n * 128 + lane]      = pack2bf(va0, va1);
        temb[(size_t)n * 128 + 64 + lane] = pack2bf(vb0, vb1);
    }
}

// ---------------- per-edge t_max / counts ----------------
__global__ void k_tmax_cnt(const int* __restrict__ src, const float* __restrict__ ts,
                           float* t_max, int* cnt, int E) {
    int e = blockIdx.x * 256 + threadIdx.x;
    if (e >= E) return;
    int s = src[e];
    atomicMax((int*)(t_max + s), __float_as_int(ts[e]));   // ts >= 0, int-monotone
    atomicAdd(cnt + s, 1);
}

// ---------------- exclusive scan over counts (single block, 4096/iter) ----------------
__global__ __launch_bounds__(1024) void k_scan(const int* __restrict__ cnt,
                                               int* __restrict__ offsets, int N) {
    __shared__ int wsum[16];
    __shared__ int s_run;
    int t = threadIdx.x;
    int lane = t & 63, wid = t >> 6;
    if (t == 0) s_run = 0;
    __syncthreads();
    int nchunk = (N + 4095) >> 12;
    for (int c = 0; c < nchunk; ++c) {
        int i0 = (c << 12) + t * 4;
        int4 v = *(const int4*)(cnt + i0);     // cnt zero-padded to NSCAN
        int s = v.x + v.y + v.z + v.w;
        int x = s;
        #pragma unroll
        for (int d = 1; d < 64; d <<= 1) {
            int y = __shfl_up(x, d, 64);
            if (lane >= d) x += y;
        }
        if (lane == 63) wsum[wid] = x;
        __syncthreads();
        int wbase = 0;
        #pragma unroll
        for (int w = 0; w < 16; ++w) wbase += (w < wid) ? wsum[w] : 0;
        int run = s_run;
        int base = run + wbase + x - s;
        if (i0 + 3 < N) {
            int4 o;
            o.x = base; o.y = base + v.x; o.z = o.y + v.y; o.w = o.z + v.z;
            *(int4*)(offsets + i0) = o;
        } else {
            int o = base;
            if (i0 < N) offsets[i0] = o;
            o += v.x;
            if (i0 + 1 < N) offsets[i0 + 1] = o;
            o += v.y;
            if (i0 + 2 < N) offsets[i0 + 2] = o;
            o += v.z;
            if (i0 + 3 < N) offsets[i0 + 3] = o;
        }
        __syncthreads();
        if (t == 1023) s_run = run + wbase + x;
        __syncthreads();
    }
    if (t == 0) offsets[N] = s_run;
}

// ---------------- scatter edges: packed (tgt, ts) records ----------------
__global__ void k_scatter(const int* __restrict__ src, const int* __restrict__ tgt,
                          const float* __restrict__ ts, const int* __restrict__ offsets,
                          int* cursor, int2* __restrict__ edat, int E) {
    int e = blockIdx.x * 256 + threadIdx.x;
    if (e >= E) return;
    int s = src[e];
    int pos = offsets[s] + atomicAdd(cursor + s, 1);
    edat[pos] = make_int2(tgt[e], __float_as_int(ts[e]));
}

// ---------------- A_r pass: rowsum, colsum, bf16 Aexp_rm + AexpT (throughput form) ----------------
__global__ __launch_bounds__(256) void k_aexp(
        const float* __restrict__ A_r,
        float* __restrict__ rowsum, float* __restrict__ colsum,
        unsigned short* __restrict__ AexpT, unsigned short* __restrict__ Aexp_rm, int N) {
    __shared__ unsigned short sE[64][228];   // 456B row stride: 8B-aligned, ~2-way banks
    int t = threadIdx.x;
    int n0 = blockIdx.x * 64;
    int maxq = min(64, N - n0) * 56;
    const float4* src = (const float4*)(A_r + (size_t)n0 * 224);
    #pragma unroll
    for (int k = 0; k < 14; ++k) {
        int i = t + k * 256;
        float4 v = (i < maxq) ? src[i] : (float4){-1e30f, -1e30f, -1e30f, -1e30f};
        int row = i / 56, cq = i % 56;
        uint2 pk;
        pk.x = pack2bf(__expf(v.x), __expf(v.y));
        pk.y = pack2bf(__expf(v.z), __expf(v.w));
        *(uint2*)&sE[row][cq * 4] = pk;
    }
    __syncthreads();
    // rowsum: 4 threads per row, 2 shuffles
    {
        int row = t >> 2, q = t & 3;
        const uint2* p = (const uint2*)&sE[row][q * 56];
        float s = 0.f;
        #pragma unroll
        for (int c = 0; c < 7; ++c) {
            uint2 u = p[c];
            s += __uint_as_float(u.x << 16) + __uint_as_float(u.x & 0xffff0000u)
               + __uint_as_float(u.y << 16) + __uint_as_float(u.y & 0xffff0000u);
        }
        s += __shfl_xor(s, 1, 64);
        s += __shfl_xor(s, 2, 64);
        if (q == 0 && n0 + row < N) rowsum[n0 + row] = s;
    }
    // colsum partials
    if (t < 224) {
        float s = 0.f;
        #pragma unroll 8
        for (int r = 0; r < 64; ++r) s += bf2f(sE[r][t]);
        atomicAdd(colsum + t, s);
    }
    // row-major write, packed uints, coalesced
    {
        unsigned int* dst = (unsigned int*)Aexp_rm;
        for (int i = t; i < 64 * 112; i += 256) {
            int n = i / 112, cp = i % 112;
            dst[(size_t)(n0 + n) * 112 + cp] = *(const unsigned int*)&sE[n][2 * cp];
        }
    }
    // transposed write: wave-coalesced 128B runs per r-row
    {
        unsigned int* dst = (unsigned int*)AexpT;
        for (int u = t; u < 224 * 32; u += 256) {
            int r = u >> 5, np = u & 31;
            unsigned int lo = sE[2 * np][r];
            unsigned int hi = sE[2 * np + 1][r];
            dst[(size_t)r * (SN / 2) + (n0 >> 1) + np] = lo | (hi << 16);
        }
    }
}

// ---------------- per-node aggregation: persistent waves, packed edge records ----------------
__global__ __launch_bounds__(256) void k_agg(
        const int2* __restrict__ edat, const int* __restrict__ offsets,
        const float* __restrict__ t_max, const unsigned int* __restrict__ temb,
        const float* __restrict__ lambs,
        unsigned int* __restrict__ aggb, float* __restrict__ cnt3,
        int* __restrict__ has_msg, int N) {
    int gw = blockIdx.x * 4 + (threadIdx.x >> 6);   // global wave id
    int lane = threadIdx.x & 63;
    float lb0 = lambs[0], lb1 = lambs[1], lb2 = lambs[2];
    for (int n = gw; n < SN; n += AGG_WAVES) {
        size_t rb = (size_t)n * 3;
        if (n >= N) {                       // zero-fill padding rows
            #pragma unroll
            for (int l = 0; l < 3; ++l) {
                unsigned int* row = aggb + (rb + l) * 128;
                row[lane] = 0; row[64 + lane] = 0;
                if (lane == 0) cnt3[rb + l] = 0.f;
            }
            continue;
        }
        int beg = offsets[n], end = offsets[n + 1];
        float tm = t_max[n];
        float aa0[3], aa1[3], ab0[3], ab1[3], accc[3];
        #pragma unroll
        for (int l = 0; l < 3; ++l) { aa0[l] = aa1[l] = ab0[l] = ab1[l] = accc[l] = 0.f; }
        for (int idx = beg; idx < end; ++idx) {
            int2 ed = edat[idx];
            int tt = ed.x;
            float d = tm - __int_as_float(ed.y);
            unsigned int ua = temb[(size_t)tt * 128 + lane];
            unsigned int ub = temb[(size_t)tt * 128 + 64 + lane];
            float a0 = __uint_as_float(ua << 16);
            float a1 = __uint_as_float(ua & 0xffff0000u);
            float b0 = __uint_as_float(ub << 16);
            float b1 = __uint_as_float(ub & 0xffff0000u);
            float w0 = __expf(-lb0 * d), w1 = __expf(-lb1 * d), w2 = __expf(-lb2 * d);
            aa0[0] += w0 * a0; aa1[0] += w0 * a1; ab0[0] += w0 * b0; ab1[0] += w0 * b1; accc[0] += w0;
            aa0[1] += w1 * a0; aa1[1] += w1 * a1; ab0[1] += w1 * b0; ab1[1] += w1 * b1; accc[1] += w1;
            aa0[2] += w2 * a0; aa1[2] += w2 * a1; ab0[2] += w2 * b0; ab1[2] += w2 * b1; accc[2] += w2;
        }
        #pragma unroll
        for (int l = 0; l < 3; ++l) {
            unsigned int* row = aggb + (rb + l) * 128;
            row[lane]      = pack2bf(aa0[l], aa1[l]);
            row[64 + lane] = pack2bf(ab0[l], ab1[l]);
            if (lane == 0) cnt3[rb + l] = accc[l];
        }
        if (lane == 0) has_msg[n] = (end > beg) ? 1 : 0;
    }
}

// ---------------- mf MLP via MFMA: 512 threads (8 waves), 64 rows/block, W-prefetch ----------------
__global__ __launch_bounds__(512, 3) void k_mf_mfma(
        const unsigned short* __restrict__ aggb,
        const unsigned short* __restrict__ W1T, const float* __restrict__ b1,
        const unsigned short* __restrict__ W2T, const float* __restrict__ b2,
        unsigned short* __restrict__ msg_feat, int NROWS) {
    __shared__ unsigned short As[64 * 264];
    __shared__ unsigned short Hs[64 * 136];
    int t = threadIdx.x, lane = t & 63, w = t >> 6;   // w in 0..7
    int lr = lane & 15, kg = lane >> 4;
    int row0 = blockIdx.x * 64;
    {   // stage A: 64 rows x 256 bf16, 8 threads/row (32 shorts each)
        int r = t >> 3, s8 = t & 7;
        const uint4* src = (const uint4*)(aggb + (size_t)(row0 + r) * 256 + s8 * 32);
        uint4* dst = (uint4*)(As + r * 264 + s8 * 32);
        #pragma unroll
        for (int u = 0; u < 4; ++u) dst[u] = src[u];
    }
    __syncthreads();
    // layer 1: wave w -> cols [w*16, w*16+16); 64 rows
    int n0 = w * 16;
    f32x4 acc[4];
    #pragma unroll
    for (int m = 0; m < 4; ++m) acc[m] = (f32x4){0.f, 0.f, 0.f, 0.f};
    short8 bfc = *(const short8*)(W1T + (size_t)(n0 + lr) * 256 + kg * 8);
    #pragma unroll
    for (int kk = 0; kk < 8; ++kk) {
        short8 bfn;
        if (kk < 7)
            bfn = *(const short8*)(W1T + (size_t)(n0 + lr) * 256 + (kk + 1) * 32 + kg * 8);
        #pragma unroll
        for (int m = 0; m < 4; ++m) {
            short8 af = *(const short8*)(As + (m * 16 + lr) * 264 + kk * 32 + kg * 8);
            acc[m] = __builtin_amdgcn_mfma_f32_16x16x32_bf16(af, bfc, acc[m], 0, 0, 0);
        }
        bfc = bfn;
    }
    float bb0 = b1[n0 + lr];
    #pragma unroll
    for (int m = 0; m < 4; ++m)
        #pragma unroll
        for (int j = 0; j < 4; ++j) {
            int row = m * 16 + kg * 4 + j;
            Hs[row * 136 + n0 + lr] = f2bf(fmaxf(acc[m][j] + bb0, 0.f));
        }
    __syncthreads();
    // layer 2: wave w -> rows [(w>>2)*32, +32), cols [(w&3)*16, +16); K=128
    int rh = (w >> 2) * 32;
    int c0 = (w & 3) * 16;
    f32x4 a2[2];
    a2[0] = (f32x4){0.f, 0.f, 0.f, 0.f};
    a2[1] = (f32x4){0.f, 0.f, 0.f, 0.f};
    short8 b2c = *(const short8*)(W2T + (size_t)(c0 + lr) * 128 + kg * 8);
    #pragma unroll
    for (int kk = 0; kk < 4; ++kk) {
        short8 b2n;
        if (kk < 3)
            b2n = *(const short8*)(W2T + (size_t)(c0 + lr) * 128 + (kk + 1) * 32 + kg * 8);
        #pragma unroll
        for (int m = 0; m < 2; ++m) {
            short8 af = *(const short8*)(Hs + (rh + m * 16 + lr) * 136 + kk * 32 + kg * 8);
            a2[m] = __builtin_amdgcn_mfma_f32_16x16x32_bf16(af, b2c, a2[m], 0, 0, 0);
        }
        b2c = b2n;
    }
    float b2v = b2[c0 + lr];
    #pragma unroll
    for (int m = 0; m < 2; ++m)
        #pragma unroll
        for (int j = 0; j < 4; ++j) {
            int row = row0 + rh + m * 16 + kg * 4 + j;
            if (row < NROWS)
                msg_feat[(size_t)row * 64 + c0 + lr] = f2bf(fmaxf(a2[m][j] + b2v, 0.f));
        }
}

// ---------------- vmid via bf16 MFMA, split-K; XCD-swizzled, B LDS-staged ----------------
__global__ __launch_bounds__(256, 4) void k_vmid_mfma(
        const unsigned short* __restrict__ AexpT, const unsigned short* __restrict__ aggb,
        const float* __restrict__ cnt3, float* __restrict__ vpart) {
    __shared__ unsigned short As[112 * 40];   // 112 rows x 32 shorts (stride 40 = 80B)
    __shared__ unsigned int BsT[128 * 20];    // [col][np-uint] stride 20; np ^= ((col>>3)&3)<<2
    // bijective XCD swizzle: co-locate the 12 tiles of each chunk on one XCD
    int bx = blockIdx.x;
    int xcd = bx & 7, bidx = bx >> 3;
    int virt = (xcd < NR_V) ? xcd * (NQ_V + 1) + bidx
                            : NR_V * (NQ_V + 1) + (xcd - NR_V) * NQ_V + bidx;
    int chunk = virt / 12, tile = virt % 12;
    int r0 = (tile & 1) * 112;
    int ft = tile >> 1;                 // 0..5
    int l = ft >> 1, fo = (ft & 1) * 128;
    int t = threadIdx.x, lane = t & 63, w = t >> 6;
    int lr = lane & 15, kg = lane >> 4;
    int np = t >> 4, sg = t & 15;       // B staging: node-pair, col-segment(8 cols)
    f32x4 acc[7][2];
    #pragma unroll
    for (int q = 0; q < 7; ++q) {
        acc[q][0] = (f32x4){0.f, 0.f, 0.f, 0.f};
        acc[q][1] = (f32x4){0.f, 0.f, 0.f, 0.f};
    }
    int nbeg = chunk * KLV;
    int nsteps = min(KLV, SN - nbeg) >> 5;
    int c0 = w * 32 + lr, c1 = c0 + 16;
    int rb0 = c0 * 20 + (kg ^ ((c0 >> 3) & 3)) * 4;
    int rb1 = c1 * 20 + (kg ^ ((c1 >> 3) & 3)) * 4;
    int swz = np ^ ((sg & 3) << 2);
    for (int s = 0; s < nsteps; ++s) {
        int n0 = nbeg + s * 32;
        if (t < 224) {                   // stage A: 2 threads/row, 32 shorts/row
            int srow = t >> 1, sseg = t & 1;
            const uint4* ap = (const uint4*)(AexpT + (size_t)(r0 + srow) * SN + n0) + sseg * 2;
            uint4 v0 = ap[0];
            uint4 v1 = ap[1];
            *(uint4*)&As[srow * 40 + sseg * 16]     = v0;
            *(uint4*)&As[srow * 40 + sseg * 16 + 8] = v1;
        }
        {   // stage B: nodes (2np, 2np+1) x cols [sg*8, sg*8+8), scaled by 1/den, k-pair packed
            int na = n0 + 2 * np;
            size_t ra = ((size_t)na * 3 + l) * 256 + fo + sg * 8;
            uint4 va = *(const uint4*)(aggb + ra);
            uint4 vb = *(const uint4*)(aggb + ra + 768);
            float da = 1.f / fmaxf(cnt3[(size_t)na * 3 + l], 1e-6f);
            float db = 1.f / fmaxf(cnt3[(size_t)na * 3 + l + 3], 1e-6f);
            const unsigned short* pa = (const unsigned short*)&va;
            const unsigned short* pb = (const unsigned short*)&vb;
            unsigned int* dst = BsT + sg * 160 + swz;
            #pragma unroll
            for (int j = 0; j < 8; ++j)
                dst[j * 20] = pack2bf(bf2f(pa[j]) * da, bf2f(pb[j]) * db);
        }
        __syncthreads();
        short8 b0 = *(const short8*)((const unsigned short*)(BsT + rb0));
        short8 b1 = *(const short8*)((const unsigned short*)(BsT + rb1));
        #pragma unroll
        for (int q = 0; q < 7; ++q) {
            short8 af = *(const short8*)&As[(q * 16 + lr) * 40 + kg * 8];
            acc[q][0] = __builtin_amdgcn_mfma_f32_16x16x32_bf16(af, b0, acc[q][0], 0, 0, 0);
            acc[q][1] = __builtin_amdgcn_mfma_f32_16x16x32_bf16(af, b1, acc[q][1], 0, 0, 0);
        }
        __syncthreads();
    }
    float* outp = vpart + (size_t)chunk * 172032;
    #pragma unroll
    for (int q = 0; q < 7; ++q) {
        int row = r0 + q * 16 + kg * 4;
        #pragma unroll
        for (int p = 0; p < 2; ++p) {
            int col = l * 256 + fo + w * 32 + p * 16 + lr;
            #pragma unroll
            for (int j = 0; j < 4; ++j)
                outp[(size_t)(row + j) * 768 + col] = acc[q][p][j];
        }
    }
}

// ---------------- reduce vpart over chunks, divide by colsum ----------------
__global__ void k_vred(const float* __restrict__ vpart, const float* __restrict__ colsum,
                       float* __restrict__ vmid) {
    int idx = blockIdx.x * 256 + threadIdx.x;
    if (idx >= 224 * 768) return;
    float s = 0.f;
    for (int c = 0; c < VCM; ++c) s += vpart[(long)c * (224 * 768) + idx];
    vmid[idx] = s / colsum[idx / 768];
}

// ---------------- ffr MLP (672 rows) + virtual-memory decay -> vembT (bf16) ----------------
__global__ __launch_bounds__(256) void k_ffr(
        const float* __restrict__ vmid, const float* __restrict__ W1, const float* __restrict__ b1,
        const float* __restrict__ W2, const float* __restrict__ b2,
        const float* __restrict__ vmem, const float* __restrict__ vlast,
        const float* __restrict__ lambs, const float* __restrict__ now_time,
        unsigned short* __restrict__ vembT) {
    __shared__ float sin_[16][260];
    __shared__ float svh[16][260];
    int row0 = blockIdx.x * 16;
    int t = threadIdx.x;
    #pragma unroll
    for (int k = 0; k < 16; ++k) {
        int idx = t + k * 256;
        int r = idx >> 8, f = idx & 255;
        sin_[r][f] = vmid[(long)(row0 + r) * 256 + f];
    }
    __syncthreads();
    {   // layer 1: 16 x 256, 4r x 4c
        int cg = t & 63, rg = t >> 6;
        int c0 = cg * 4, r0 = rg * 4;
        float acc[4][4];
        #pragma unroll
        for (int i = 0; i < 4; ++i)
            #pragma unroll
            for (int j = 0; j < 4; ++j) acc[i][j] = 0.f;
        for (int f0 = 0; f0 < 256; f0 += 4) {
            float4 a[4];
            #pragma unroll
            for (int i = 0; i < 4; ++i) a[i] = *(const float4*)&sin_[r0 + i][f0];
            #pragma unroll
            for (int ff = 0; ff < 4; ++ff) {
                float4 w = *(const float4*)&W1[(long)(f0 + ff) * 256 + c0];
                #pragma unroll
                for (int i = 0; i < 4; ++i) {
                    float av = (&a[i].x)[ff];
                    acc[i][0] += av * w.x; acc[i][1] += av * w.y;
                    acc[i][2] += av * w.z; acc[i][3] += av * w.w;
                }
            }
        }
        #pragma unroll
        for (int i = 0; i < 4; ++i)
            #pragma unroll
            for (int j = 0; j < 4; ++j)
                svh[r0 + i][c0 + j] = lky(acc[i][j] + b1[c0 + j]);
    }
    __syncthreads();
    {   // layer 2: 16 x 64, 2r x 2c + decay epilogue
        int cg = t & 31, rg = t >> 5;
        int c0 = cg * 2, r0 = rg * 2;
        float acc[2][2];
        acc[0][0] = acc[0][1] = acc[1][0] = acc[1][1] = 0.f;
        for (int f0 = 0; f0 < 256; f0 += 4) {
            float4 a[2];
            #pragma unroll
            for (int i = 0; i < 2; ++i) a[i] = *(const float4*)&svh[r0 + i][f0];
            #pragma unroll
            for (int ff = 0; ff < 4; ++ff) {
                float2 w = *(const float2*)&W2[(long)(f0 + ff) * 64 + c0];
                #pragma unroll
                for (int i = 0; i < 2; ++i) {
                    float av = (&a[i].x)[ff];
                    acc[i][0] += av * w.x; acc[i][1] += av * w.y;
                }
            }
        }
        float nowv = now_time[0];
        #pragma unroll
        for (int i = 0; i < 2; ++i) {
            int row = row0 + r0 + i;           // row = rr*3 + l
            int rr = row / 3, l = row % 3;
            float vd = __expf(-lambs[l] * (nowv - vlast[rr]));
            #pragma unroll
            for (int j = 0; j < 2; ++j) {
                float v = lky(acc[i][j] + b2[c0 + j]);
                int m = c0 + j;
                vembT[(size_t)(l * 64 + m) * 224 + rr] =
                    f2bf(vmem[(long)rr * 192 + l * 64 + m] * vd + v);
            }
        }
    }
}

// ---------------- new_mem -> node_emb (bf16) ----------------
__global__ void k_newmem(const float* __restrict__ memory,
        const unsigned short* __restrict__ msg_feat,
        const float* __restrict__ cnt3, const float* __restrict__ t_max,
        const float* __restrict__ last_update, const int* __restrict__ has_msg,
        const float* __restrict__ lambs, unsigned short* __restrict__ node_emb, int N) {
    int n = blockIdx.x;
    int j = threadIdx.x;                 // 0..191
    int l = j >> 6, m = j & 63;
    int has = has_msg[n];
    float dt = has ? (t_max[n] - last_update[n]) : 0.f;
    float decay = __expf(-lambs[l] * dt);
    long mb = (long)n * 195 + l * 65;
    float num = memory[mb + m];
    float den = memory[mb + 64];
    if (has) {
        num = num * decay + bf2f(msg_feat[(size_t)n * 192 + j]);
        den = den * decay + cnt3[(size_t)n * 3 + l];
    }
    node_emb[(size_t)n * 192 + j] = f2bf(num / fmaxf(den, 1e-6f));
}

// ---------------- vnode_emb = row-softmax(A_r) @ v_emb via MFMA (LDS-staged A) ----------------
__global__ __launch_bounds__(256, 4) void k_vnode_mfma(
        const unsigned short* __restrict__ Aexp_rm, const unsigned short* __restrict__ vembT,
        const float* __restrict__ rowsum, unsigned short* __restrict__ vnode_emb, int N) {
    __shared__ unsigned short As[64 * 232];
    __shared__ float sRS[64];
    int t = threadIdx.x, lane = t & 63, w = t >> 6;
    int lr = lane & 15, kg = lane >> 4;
    int row0 = blockIdx.x * 64;
    {
        int r = t >> 2, sg = t & 3;
        const uint4* src = (const uint4*)(Aexp_rm + (size_t)(row0 + r) * 224 + sg * 56);
        uint4* dst = (uint4*)(As + r * 232 + sg * 56);
        #pragma unroll
        for (int u = 0; u < 7; ++u) dst[u] = src[u];
    }
    if (t < 64) sRS[t] = rowsum[min(row0 + t, N - 1)];
    __syncthreads();
    int n0 = w * 48;                      // 192 cols / 4 waves
    f32x4 acc[4][3];
    #pragma unroll
    for (int m = 0; m < 4; ++m)
        #pragma unroll
        for (int nt = 0; nt < 3; ++nt) acc[m][nt] = (f32x4){0.f, 0.f, 0.f, 0.f};
    #pragma unroll
    for (int kk = 0; kk < 7; ++kk) {
        short8 bf[3];
        #pragma unroll
        for (int nt = 0; nt < 3; ++nt)
            bf[nt] = *(const short8*)(vembT + (size_t)(n0 + nt * 16 + lr) * 224 + kk * 32 + kg * 8);
        #pragma unroll
        for (int m = 0; m < 4; ++m) {
            short8 af = *(const short8*)(As + (m * 16 + lr) * 232 + kk * 32 + kg * 8);
            #pragma unroll
            for (int nt = 0; nt < 3; ++nt)
                acc[m][nt] = __builtin_amdgcn_mfma_f32_16x16x32_bf16(af, bf[nt], acc[m][nt], 0, 0, 0);
        }
    }
    #pragma unroll
    for (int m = 0; m < 4; ++m)
        #pragma unroll
        for (int j = 0; j < 4; ++j) {
            int row = row0 + m * 16 + kg * 4 + j;
            if (row < N) {
                float inv = 1.f / sRS[row - row0];
                #pragma unroll
                for (int nt = 0; nt < 3; ++nt)
                    vnode_emb[(size_t)row * 192 + n0 + nt * 16 + lr] = f2bf(acc[m][nt][j] * inv);
            }
        }
}

// ---------------- et + st + output blend via MFMA: 32 rows/block, LDS-staged ----------------
__global__ __launch_bounds__(256, 4) void k_et_st_mfma(
        const unsigned short* __restrict__ ne, const unsigned short* __restrict__ ve,
        const unsigned short* __restrict__ etWT, const float* __restrict__ etb,
        const unsigned short* __restrict__ stWT, const float* __restrict__ stb,
        const float* __restrict__ stat, const float* __restrict__ lamb,
        float* __restrict__ out, int N) {
    __shared__ unsigned short As[64 * 200];    // rows 0-31: node, 32-63: vnode
    __shared__ unsigned short Hs[32 * 136];    // st input [32 rows][128 cols]
    int t = threadIdx.x, lane = t & 63, w = t >> 6;
    int lr = lane & 15, kg = lane >> 4;
    int row0 = blockIdx.x * 32;
    {
        int r = t >> 3, s8 = t & 7;            // 8 threads/row, 48B each
        const uint4* sn = (const uint4*)(ne + (size_t)(row0 + r) * 192 + s8 * 24);
        const uint4* sv = (const uint4*)(ve + (size_t)(row0 + r) * 192 + s8 * 24);
        uint4* dn = (uint4*)(As + (size_t)r * 200 + s8 * 24);
        uint4* dv = (uint4*)(As + (size_t)(32 + r) * 200 + s8 * 24);
        #pragma unroll
        for (int u = 0; u < 3; ++u) { dn[u] = sn[u]; dv[u] = sv[u]; }
    }
    __syncthreads();
    // et layer: wave w -> cols [w*16, w*16+16), both halves; K=192
    int c0 = w * 16;
    f32x4 acc[2][2];
    #pragma unroll
    for (int h = 0; h < 2; ++h)
        #pragma unroll
        for (int m = 0; m < 2; ++m) acc[h][m] = (f32x4){0.f, 0.f, 0.f, 0.f};
    #pragma unroll
    for (int kk = 0; kk < 6; ++kk) {
        short8 bf = *(const short8*)(etWT + (size_t)(c0 + lr) * 192 + kk * 32 + kg * 8);
        #pragma unroll
        for (int h = 0; h < 2; ++h)
            #pragma unroll
            for (int m = 0; m < 2; ++m) {
                short8 af = *(const short8*)(As + (size_t)(h * 32 + m * 16 + lr) * 200 + kk * 32 + kg * 8);
                acc[h][m] = __builtin_amdgcn_mfma_f32_16x16x32_bf16(af, bf, acc[h][m], 0, 0, 0);
            }
    }
    float bb = etb[c0 + lr];
    #pragma unroll
    for (int h = 0; h < 2; ++h)
        #pragma unroll
        for (int m = 0; m < 2; ++m)
            #pragma unroll
            for (int j = 0; j < 4; ++j)
                Hs[(m * 16 + kg * 4 + j) * 136 + h * 64 + c0 + lr] = f2bf(lky(acc[h][m][j] + bb));
    __syncthreads();
    // st layer: wave w -> cols [w*32, w*32+32); K=128
    int c0s = w * 32;
    f32x4 a2[2][2];
    #pragma unroll
    for (int m = 0; m < 2; ++m) { a2[m][0] = (f32x4){0.f,0.f,0.f,0.f}; a2[m][1] = (f32x4){0.f,0.f,0.f,0.f}; }
    #pragma unroll
    for (int kk = 0; kk < 4; ++kk) {
        short8 bf0 = *(const short8*)(stWT + (size_t)(c0s + lr) * 128 + kk * 32 + kg * 8);
        short8 bf1 = *(const short8*)(stWT + (size_t)(c0s + 16 + lr) * 128 + kk * 32 + kg * 8);
        #pragma unroll
        for (int m = 0; m < 2; ++m) {
            short8 af = *(const short8*)(Hs + (m * 16 + lr) * 136 + kk * 32 + kg * 8);
            a2[m][0] = __builtin_amdgcn_mfma_f32_16x16x32_bf16(af, bf0, a2[m][0], 0, 0, 0);
            a2[m][1] = __builtin_amdgcn_mfma_f32_16x16x32_bf16(af, bf1, a2[m][1], 0, 0, 0);
        }
    }
    float lam = lamb[0];
    float sb0 = stb[c0s + lr], sb1 = stb[c0s + 16 + lr];
    #pragma unroll
    for (int m = 0; m < 2; ++m)
        #pragma unroll
        for (int j = 0; j < 4; ++j) {
            int n = row0 + m * 16 + kg * 4 + j;
            if (n < N) {
                int ca = c0s + lr, cb = c0s + 16 + lr;
                float va = lky(a2[m][0][j] + sb0);
                float vb = lky(a2[m][1][j] + sb1);
                out[(size_t)n * 128 + ca] = lam * stat[(size_t)n * 128 + ca] + (1.f - lam) * va;
                out[(size_t)n * 128 + cb] = lam * stat[(size_t)n * 128 + cb] + (1.f - lam) * vb;
            }
        }
}

extern "C" void kernel_launch(void* const* d_in, const int* in_sizes, int n_in,
                              void* d_out, int out_size, void* d_ws, size_t ws_size,
                              hipStream_t stream) {
    const int*   src        = (const int*)d_in[0];
    const int*   tgt        = (const int*)d_in[1];
    const float* ts         = (const float*)d_in[2];
    const float* now_time   = (const float*)d_in[3];
    const float* nodef      = (const float*)d_in[5];
    const float* memory     = (const float*)d_in[6];
    const float* last_upd   = (const float*)d_in[7];
    const float* vmem       = (const float*)d_in[8];
    const float* vlast      = (const float*)d_in[9];
    const float* A_r        = (const float*)d_in[10];
    const float* static_emb = (const float*)d_in[11];
    const float* lamb       = (const float*)d_in[12];
    const float* lambs      = (const float*)d_in[13];
    const float* mf_W1      = (const float*)d_in[14];
    const float* mf_b1      = (const float*)d_in[15];
    const float* mf_W2      = (const float*)d_in[16];
    const float* mf_b2      = (const float*)d_in[17];
    const float* ffr_W1     = (const float*)d_in[18];
    const float* ffr_b1     = (const float*)d_in[19];
    const float* ffr_W2     = (const float*)d_in[20];
    const float* ffr_b2     = (const float*)d_in[21];
    const float* et_W       = (const float*)d_in[22];
    const float* et_b       = (const float*)d_in[23];
    const float* st_W       = (const float*)d_in[24];
    const float* st_b       = (const float*)d_in[25];

    int E = in_sizes[0];
    int N = in_sizes[7];

    float* ws = (float*)d_ws;
    size_t off = 0;
    auto alloc = [&](size_t nf) { float* p = ws + off; off += (nf + 63) & ~(size_t)63; return p; };
    unsigned short* aggb  = (unsigned short*)alloc((size_t)SN * 384);     // SN*3 rows x 256 bf16
    unsigned short* msg_feat = (unsigned short*)alloc((size_t)N * 96);    // bf16
    unsigned short* AexpT   = (unsigned short*)alloc((size_t)224 * SN / 2);
    unsigned short* Aexp_rm = (unsigned short*)alloc((size_t)SN * 224 / 2);
    float* tv_union = alloc((size_t)VCM * 172032);      // temb (N*128) then vpart (VCM*172032)
    float* vmid     = alloc(224 * 768);
    unsigned short* vembT = (unsigned short*)alloc((size_t)192 * 224 / 2 + 64);
    float* t_max    = alloc(N);
    float* rowsum   = alloc(N);
    float* cnt3     = alloc((size_t)SN * 3);
    float* colsum   = alloc(256);
    unsigned short* W1T  = (unsigned short*)alloc(128 * 256 / 2);
    unsigned short* W2T  = (unsigned short*)alloc(64 * 128 / 2);
    unsigned short* etWT = (unsigned short*)alloc(64 * 192 / 2);
    unsigned short* stWT = (unsigned short*)alloc(128 * 128 / 2);
    int*   cnt      = (int*)alloc(NSCAN);               // padded+zeroed for int4 scan
    int*   offsets  = (int*)alloc(N + 1);
    int*   cursor   = (int*)alloc(N);
    int2*  edat     = (int2*)alloc((size_t)E * 2);      // packed (tgt, ts) per sorted edge
    int*   has_msg  = (int*)alloc(N);
    if (off * sizeof(float) > ws_size) return;   // workspace guard

    unsigned int* temb = (unsigned int*)tv_union;   // live: k_setup..k_agg
    float* vpart = tv_union;                        // live: k_vmid_mfma..k_vred
    // overlays: aggb region is dead after k_mf_mfma + k_vmid_mfma
    unsigned short* node_emb  = (unsigned short*)aggb;
    unsigned short* vnode_emb = node_emb + (size_t)N * 192;

    k_setup<<<SETUP_BLOCKS, 256, 0, stream>>>(t_max, cnt, cursor, colsum,
                                              mf_W1, W1T, mf_W2, W2T, et_W, etWT, st_W, stWT,
                                              memory, nodef, temb, N, NSCAN);
    k_tmax_cnt<<<(E + 255) / 256, 256, 0, stream>>>(src, ts, t_max, cnt, E);
    k_scan<<<1, 1024, 0, stream>>>(cnt, offsets, N);
    k_scatter<<<(E + 255) / 256, 256, 0, stream>>>(src, tgt, ts, offsets, cursor, edat, E);
    k_aexp<<<SN / 64, 256, 0, stream>>>(A_r, rowsum, colsum, AexpT, Aexp_rm, N);
    k_agg<<<AGG_BLOCKS, 256, 0, stream>>>(edat, offsets, t_max, temb,
                                          lambs, (unsigned int*)aggb, cnt3, has_msg, N);
    k_mf_mfma<<<SN * 3 / 64, 512, 0, stream>>>(aggb, W1T, mf_b1, W2T, mf_b2, msg_feat, N * 3);
    k_vmid_mfma<<<NWG_V, 256, 0, stream>>>(AexpT, aggb, cnt3, vpart);
    k_vred<<<(224 * 768 + 255) / 256, 256, 0, stream>>>(vpart, colsum, vmid);
    k_ffr<<<42, 256, 0, stream>>>(vmid, ffr_W1, ffr_b1, ffr_W2, ffr_b2, vmem, vlast,
                                  lambs, now_time, vembT);
    k_newmem<<<N, 192, 0, stream>>>(memory, msg_feat, cnt3, t_max, last_upd, has_msg,
                                    lambs, node_emb, N);
    k_vnode_mfma<<<SN / 64, 256, 0, stream>>>(Aexp_rm, vembT, rowsum, vnode_emb, N);
    k_et_st_mfma<<<SN / 32, 256, 0, stream>>>(node_emb, vnode_emb, etWT, et_b, stWT, st_b,
                                              static_emb, lamb, (float*)d_out, N);
}